// Round 1
// baseline (779.614 us; speedup 1.0000x reference)
//
#include <hip/hip_runtime.h>

typedef __attribute__((ext_vector_type(8))) short short8;
typedef __attribute__((ext_vector_type(4))) float floatx4;
typedef __attribute__((ext_vector_type(4))) unsigned short ushort4v;
typedef unsigned short u16;

__device__ __forceinline__ u16 f2bf(float f) {
  unsigned u = __float_as_uint(f);
  u += 0x7fffu + ((u >> 16) & 1u);
  return (u16)(u >> 16);
}

__device__ __forceinline__ void gl_lds16(const void* g, void* l) {
  __builtin_amdgcn_global_load_lds((const __attribute__((address_space(1))) void*)g,
                                   (__attribute__((address_space(3))) void*)l, 16, 0, 0);
}

// ---------------- converts ----------------

__global__ void k_cvt_x(const float* __restrict__ x, u16* __restrict__ o, long n) {
  long i = ((long)blockIdx.x * blockDim.x + threadIdx.x) * 8;
  long stride = (long)gridDim.x * blockDim.x * 8;
  for (; i < n; i += stride) {
    float4 a = *(const float4*)(x + i);
    float4 b = *(const float4*)(x + i + 4);
    ushort4v r0 = { f2bf(a.x), f2bf(a.y), f2bf(a.z), f2bf(a.w) };
    ushort4v r1 = { f2bf(b.x), f2bf(b.y), f2bf(b.z), f2bf(b.w) };
    *(ushort4v*)(o + i) = r0;
    *(ushort4v*)(o + i + 4) = r1;
  }
}

// wqkv: [n=(t*1024+h*256+e)][k=d] bf16 ; wo: [n=d][k=h*256+e] bf16
__global__ void k_cvt_w(const float* __restrict__ WQ, const float* __restrict__ WK,
                        const float* __restrict__ WV, const float* __restrict__ WO,
                        u16* __restrict__ wqkv, u16* __restrict__ wo) {
  int idx = blockIdx.x * blockDim.x + threadIdx.x;
  const int NW = 3072 * 1024;
  if (idx < NW) {
    int n = idx >> 10, k = idx & 1023;
    int t = n >> 10, h = (n >> 8) & 3, e = n & 255;
    const float* W = (t == 0) ? WQ : (t == 1) ? WK : WV;
    wqkv[idx] = f2bf(W[((h * 1024) + k) * 256 + e]);
  } else if (idx < NW + 1024 * 1024) {
    int j = idx - NW;
    int d = j >> 10, k = j & 1023;
    wo[j] = f2bf(WO[(long)k * 1024 + d]);
  }
}

// ---------------- GEMM: C[M,*] = A[M,1024] * Bt[N,1024]^T ----------------
// EPI 0: QKV projection epilogue (route to Q,K,Vt + bias)
// EPI 1: output projection epilogue (fp32 out + b_O)
template<int EPI>
__global__ __launch_bounds__(256, 2) void k_gemm(
    const u16* __restrict__ A, const u16* __restrict__ Bt,
    u16* __restrict__ Qo, u16* __restrict__ Ko, u16* __restrict__ Vt,
    const float* __restrict__ bQ, const float* __restrict__ bK, const float* __restrict__ bV,
    float* __restrict__ out, const float* __restrict__ bO) {
  __shared__ u16 sA[128 * 64];
  __shared__ u16 sB[128 * 64];
  const int tid = threadIdx.x;
  const int lane = tid & 63, w = tid >> 6;
  const int wr = w >> 1, wc = w & 1;
  const int cI = lane & 15, rI = lane >> 4;
  const long am0 = (long)blockIdx.y * 128;
  const long bn0 = (long)blockIdx.x * 128;
  floatx4 acc[4][4] = {};

  for (int kt = 0; kt < 1024; kt += 64) {
#pragma unroll
    for (int j = 0; j < 4; ++j) {
      int o = j * 4096 + w * 1024 + lane * 16;
      int row = o >> 7, c = (o & 127) >> 1;
      gl_lds16(A + (am0 + row) * 1024 + kt + c, (char*)sA + o);
      gl_lds16(Bt + (bn0 + row) * 1024 + kt + c, (char*)sB + o);
    }
    __syncthreads();
#pragma unroll
    for (int kk = 0; kk < 2; ++kk) {
      short8 af[4], bf[4];
      const int ko = kk * 64 + rI * 16;  // byte offset of k within 128B row
#pragma unroll
      for (int i = 0; i < 4; ++i) {
        af[i] = *(const short8*)((const char*)sA + (wr * 64 + i * 16 + cI) * 128 + ko);
        bf[i] = *(const short8*)((const char*)sB + (wc * 64 + i * 16 + cI) * 128 + ko);
      }
#pragma unroll
      for (int i = 0; i < 4; ++i)
#pragma unroll
        for (int jn = 0; jn < 4; ++jn)
          acc[i][jn] = __builtin_amdgcn_mfma_f32_16x16x32_bf16(af[i], bf[jn], acc[i][jn], 0, 0, 0);
    }
    __syncthreads();
  }

  if (EPI == 0) {
    const int t = (int)(bn0 >> 10);
    const float* bias = (t == 0) ? bQ : (t == 1) ? bK : bV;
#pragma unroll
    for (int i = 0; i < 4; ++i) {
      int m = (int)am0 + wr * 64 + i * 16 + rI * 4;
      int b = m >> 11, s = m & 2047;
#pragma unroll
      for (int jn = 0; jn < 4; ++jn) {
        int n = (int)bn0 + wc * 64 + jn * 16 + cI;
        int h = (n >> 8) & 3, e = n & 255;
        float bb = bias[n & 1023];
        floatx4 c = acc[i][jn];
        if (t < 2) {
          u16* dst = (t == 0) ? Qo : Ko;
          long base = ((long)(b * 4 + h) * 2048 + s) * 256 + e;
          dst[base]       = f2bf(c[0] + bb);
          dst[base + 256] = f2bf(c[1] + bb);
          dst[base + 512] = f2bf(c[2] + bb);
          dst[base + 768] = f2bf(c[3] + bb);
        } else {
          long base = ((long)(b * 4 + h) * 256 + e) * 2048 + s;
          ushort4v v = { f2bf(c[0] + bb), f2bf(c[1] + bb), f2bf(c[2] + bb), f2bf(c[3] + bb) };
          *(ushort4v*)(Vt + base) = v;
        }
      }
    }
  } else {
#pragma unroll
    for (int i = 0; i < 4; ++i) {
      int m = (int)am0 + wr * 64 + i * 16 + rI * 4;
#pragma unroll
      for (int jn = 0; jn < 4; ++jn) {
        int n = (int)bn0 + wc * 64 + jn * 16 + cI;
        float bb = bO[n];
        floatx4 c = acc[i][jn];
        out[(long)m * 1024 + n]       = c[0] + bb;
        out[(long)(m + 1) * 1024 + n] = c[1] + bb;
        out[(long)(m + 2) * 1024 + n] = c[2] + bb;
        out[(long)(m + 3) * 1024 + n] = c[3] + bb;
      }
    }
  }
}

// ---------------- flash attention ----------------
// grid (32 qtiles, 4 h, 8 b), 256 thr. wave w owns 16 q-rows. KVBLK=32.
__global__ __launch_bounds__(256, 2) void k_attn(
    const u16* __restrict__ Q, const u16* __restrict__ K,
    const u16* __restrict__ Vt, u16* __restrict__ Z) {
  __shared__ u16 sK[32 * 256];
  __shared__ u16 sV[256 * 32];
  __shared__ u16 sP[4][16 * 32];
  const int tid = threadIdx.x, lane = tid & 63, w = tid >> 6;
  const int cI = lane & 15, rI = lane >> 4;
  const int h = blockIdx.y, b = blockIdx.z;
  const int bh = b * 4 + h;
  const long base = (long)bh * 2048 * 256;
  const int q0 = blockIdx.x * 64 + w * 16;

  short8 qf[8];
#pragma unroll
  for (int ef = 0; ef < 8; ++ef)
    qf[ef] = *(const short8*)(Q + base + (long)(q0 + cI) * 256 + ef * 32 + rI * 8);

  floatx4 accz[16] = {};
  float mr[4] = {-1e30f, -1e30f, -1e30f, -1e30f};
  float lr[4] = {0.f, 0.f, 0.f, 0.f};
  const float scale = 0.0625f;
  const u16* Vg = Vt + base;  // [256][2048]

  for (int kt = 0; kt < 64; ++kt) {
    const int k0 = kt * 32;
    const u16* Kg = K + base + (long)k0 * 256;  // contiguous 16KB tile
#pragma unroll
    for (int j = 0; j < 4; ++j) {
      int o = j * 4096 + w * 1024 + lane * 16;
      gl_lds16(Kg + (o >> 1), (char*)sK + o);
      int row = o >> 6, c = (o & 63) >> 1;
      gl_lds16(Vg + (long)row * 2048 + k0 + c, (char*)sV + o);
    }
    __syncthreads();

    floatx4 accs[2] = {};
#pragma unroll
    for (int nf = 0; nf < 2; ++nf)
#pragma unroll
      for (int kk = 0; kk < 8; ++kk) {
        short8 kf = *(const short8*)(sK + (nf * 16 + cI) * 256 + kk * 32 + rI * 8);
        accs[nf] = __builtin_amdgcn_mfma_f32_16x16x32_bf16(qf[kk], kf, accs[nf], 0, 0, 0);
      }

    float esc[4];
#pragma unroll
    for (int r = 0; r < 4; ++r) {
      float mx = fmaxf(accs[0][r], accs[1][r]) * scale;
      mx = fmaxf(mx, __shfl_xor(mx, 1, 16));
      mx = fmaxf(mx, __shfl_xor(mx, 2, 16));
      mx = fmaxf(mx, __shfl_xor(mx, 4, 16));
      mx = fmaxf(mx, __shfl_xor(mx, 8, 16));
      float mn = fmaxf(mr[r], mx);
      esc[r] = __expf(mr[r] - mn);
      float p0 = __expf(accs[0][r] * scale - mn);
      float p1 = __expf(accs[1][r] * scale - mn);
      accs[0][r] = p0; accs[1][r] = p1;
      float rs = p0 + p1;
      rs += __shfl_xor(rs, 1, 16);
      rs += __shfl_xor(rs, 2, 16);
      rs += __shfl_xor(rs, 4, 16);
      rs += __shfl_xor(rs, 8, 16);
      lr[r] = lr[r] * esc[r] + rs;
      mr[r] = mn;
    }
#pragma unroll
    for (int f = 0; f < 16; ++f) {
      accz[f][0] *= esc[0]; accz[f][1] *= esc[1];
      accz[f][2] *= esc[2]; accz[f][3] *= esc[3];
    }
#pragma unroll
    for (int nf = 0; nf < 2; ++nf)
#pragma unroll
      for (int r = 0; r < 4; ++r)
        sP[w][(rI * 4 + r) * 32 + nf * 16 + cI] = f2bf(accs[nf][r]);
    asm volatile("s_waitcnt lgkmcnt(0)" ::: "memory");
    short8 pf = *(const short8*)(&sP[w][cI * 32 + rI * 8]);
#pragma unroll
    for (int f = 0; f < 16; ++f) {
      short8 vf = *(const short8*)(sV + (f * 16 + cI) * 32 + rI * 8);
      accz[f] = __builtin_amdgcn_mfma_f32_16x16x32_bf16(pf, vf, accz[f], 0, 0, 0);
    }
    __syncthreads();
  }

  const long zb = ((long)b * 2048) * 1024 + h * 256;
#pragma unroll
  for (int r = 0; r < 4; ++r) {
    float inv = 1.f / lr[r];
    long rb = zb + (long)(q0 + rI * 4 + r) * 1024;
#pragma unroll
    for (int f = 0; f < 16; ++f)
      Z[rb + f * 16 + cI] = f2bf(accz[f][r] * inv);
  }
}

// ---------------- launch ----------------

extern "C" void kernel_launch(void* const* d_in, const int* in_sizes, int n_in,
                              void* d_out, int out_size, void* d_ws, size_t ws_size,
                              hipStream_t stream) {
  const float* x  = (const float*)d_in[0];
  const float* WQ = (const float*)d_in[1];
  const float* bQ = (const float*)d_in[2];
  const float* WK = (const float*)d_in[3];
  const float* bK = (const float*)d_in[4];
  const float* WV = (const float*)d_in[5];
  const float* bV = (const float*)d_in[6];
  const float* WO = (const float*)d_in[7];
  const float* bO = (const float*)d_in[8];
  float* out = (float*)d_out;

  char* p = (char*)d_ws;
  u16* xb   = (u16*)p; p += (size_t)16384 * 1024 * 2;  // x bf16; reused later as Z
  u16* wqkv = (u16*)p; p += (size_t)3072 * 1024 * 2;
  u16* wo   = (u16*)p; p += (size_t)1024 * 1024 * 2;
  u16* Qb   = (u16*)p; p += (size_t)32 * 2048 * 256 * 2;
  u16* Kb   = (u16*)p; p += (size_t)32 * 2048 * 256 * 2;
  u16* Vtb  = (u16*)p; p += (size_t)32 * 256 * 2048 * 2;
  u16* Zb   = xb;  // alias: xb dead after k_gemm<0>

  k_cvt_x<<<dim3(4096), dim3(256), 0, stream>>>(x, xb, (long)16384 * 1024);
  k_cvt_w<<<dim3(16384), dim3(256), 0, stream>>>(WQ, WK, WV, WO, wqkv, wo);
  k_gemm<0><<<dim3(24, 128), dim3(256), 0, stream>>>(xb, wqkv, Qb, Kb, Vtb, bQ, bK, bV,
                                                     (float*)nullptr, (const float*)nullptr);
  k_attn<<<dim3(32, 4, 8), dim3(256), 0, stream>>>(Qb, Kb, Vtb, Zb);
  k_gemm<1><<<dim3(8, 128), dim3(256), 0, stream>>>(Zb, wo,
                                                    (u16*)nullptr, (u16*)nullptr, (u16*)nullptr,
                                                    (const float*)nullptr, (const float*)nullptr, (const float*)nullptr,
                                                    out, bO);
}

// Round 2
// 555.741 us; speedup vs baseline: 1.4028x; 1.4028x over previous
//
#include <hip/hip_runtime.h>

typedef __attribute__((ext_vector_type(8))) short short8;
typedef __attribute__((ext_vector_type(4))) float floatx4;
typedef __attribute__((ext_vector_type(4))) unsigned short ushort4v;
typedef unsigned short u16;

__device__ __forceinline__ u16 f2bf(float f) {
  unsigned u = __float_as_uint(f);
  u += 0x7fffu + ((u >> 16) & 1u);
  return (u16)(u >> 16);
}

__device__ __forceinline__ void gl_lds16(const void* g, void* l) {
  __builtin_amdgcn_global_load_lds((const __attribute__((address_space(1))) void*)g,
                                   (__attribute__((address_space(3))) void*)l, 16, 0, 0);
}

// ---------------- converts ----------------

__global__ void k_cvt_x(const float* __restrict__ x, u16* __restrict__ o, long n) {
  long i = ((long)blockIdx.x * blockDim.x + threadIdx.x) * 8;
  long stride = (long)gridDim.x * blockDim.x * 8;
  for (; i < n; i += stride) {
    float4 a = *(const float4*)(x + i);
    float4 b = *(const float4*)(x + i + 4);
    ushort4v r0 = { f2bf(a.x), f2bf(a.y), f2bf(a.z), f2bf(a.w) };
    ushort4v r1 = { f2bf(b.x), f2bf(b.y), f2bf(b.z), f2bf(b.w) };
    *(ushort4v*)(o + i) = r0;
    *(ushort4v*)(o + i + 4) = r1;
  }
}

// wqkv: [n=(t*1024+h*256+e)][k=d] bf16 ; wo: [n=d][k=h*256+e] bf16
__global__ void k_cvt_w(const float* __restrict__ WQ, const float* __restrict__ WK,
                        const float* __restrict__ WV, const float* __restrict__ WO,
                        u16* __restrict__ wqkv, u16* __restrict__ wo) {
  int idx = blockIdx.x * blockDim.x + threadIdx.x;
  const int NW = 3072 * 1024;
  if (idx < NW) {
    int n = idx >> 10, k = idx & 1023;
    int t = n >> 10, h = (n >> 8) & 3, e = n & 255;
    const float* W = (t == 0) ? WQ : (t == 1) ? WK : WV;
    wqkv[idx] = f2bf(W[((h * 1024) + k) * 256 + e]);
  } else if (idx < NW + 1024 * 1024) {
    int j = idx - NW;
    int d = j >> 10, k = j & 1023;
    wo[j] = f2bf(WO[(long)k * 1024 + d]);
  }
}

// ---------------- GEMM: C[M,*] = A[M,1024] * Bt[N,1024]^T ----------------
template<int EPI>
__global__ __launch_bounds__(256, 2) void k_gemm(
    const u16* __restrict__ A, const u16* __restrict__ Bt,
    u16* __restrict__ Qo, u16* __restrict__ Ko, u16* __restrict__ Vt,
    const float* __restrict__ bQ, const float* __restrict__ bK, const float* __restrict__ bV,
    float* __restrict__ out, const float* __restrict__ bO) {
  __shared__ u16 sA[128 * 64];
  __shared__ u16 sB[128 * 64];
  const int tid = threadIdx.x;
  const int lane = tid & 63, w = tid >> 6;
  const int wr = w >> 1, wc = w & 1;
  const int cI = lane & 15, rI = lane >> 4;
  const long am0 = (long)blockIdx.y * 128;
  const long bn0 = (long)blockIdx.x * 128;
  floatx4 acc[4][4] = {};

  for (int kt = 0; kt < 1024; kt += 64) {
#pragma unroll
    for (int j = 0; j < 4; ++j) {
      int o = j * 4096 + w * 1024 + lane * 16;
      int row = o >> 7, c = (o & 127) >> 1;
      gl_lds16(A + (am0 + row) * 1024 + kt + c, (char*)sA + o);
      gl_lds16(Bt + (bn0 + row) * 1024 + kt + c, (char*)sB + o);
    }
    __syncthreads();
#pragma unroll
    for (int kk = 0; kk < 2; ++kk) {
      short8 af[4], bf[4];
      const int ko = kk * 64 + rI * 16;
#pragma unroll
      for (int i = 0; i < 4; ++i) {
        af[i] = *(const short8*)((const char*)sA + (wr * 64 + i * 16 + cI) * 128 + ko);
        bf[i] = *(const short8*)((const char*)sB + (wc * 64 + i * 16 + cI) * 128 + ko);
      }
#pragma unroll
      for (int i = 0; i < 4; ++i)
#pragma unroll
        for (int jn = 0; jn < 4; ++jn)
          acc[i][jn] = __builtin_amdgcn_mfma_f32_16x16x32_bf16(af[i], bf[jn], acc[i][jn], 0, 0, 0);
    }
    __syncthreads();
  }

  if (EPI == 0) {
    const int t = (int)(bn0 >> 10);
    const float* bias = (t == 0) ? bQ : (t == 1) ? bK : bV;
    const float sc = (t == 0) ? 0.0625f : 1.0f;  // fold 1/sqrt(256) into Q
#pragma unroll
    for (int i = 0; i < 4; ++i) {
      int m = (int)am0 + wr * 64 + i * 16 + rI * 4;
      int b = m >> 11, s = m & 2047;
#pragma unroll
      for (int jn = 0; jn < 4; ++jn) {
        int n = (int)bn0 + wc * 64 + jn * 16 + cI;
        int h = (n >> 8) & 3, e = n & 255;
        float bb = bias[n & 1023];
        floatx4 c = acc[i][jn];
        if (t < 2) {
          u16* dst = (t == 0) ? Qo : Ko;
          long base = ((long)(b * 4 + h) * 2048 + s) * 256 + e;
          dst[base]       = f2bf((c[0] + bb) * sc);
          dst[base + 256] = f2bf((c[1] + bb) * sc);
          dst[base + 512] = f2bf((c[2] + bb) * sc);
          dst[base + 768] = f2bf((c[3] + bb) * sc);
        } else {
          long base = ((long)(b * 4 + h) * 256 + e) * 2048 + s;
          ushort4v v = { f2bf(c[0] + bb), f2bf(c[1] + bb), f2bf(c[2] + bb), f2bf(c[3] + bb) };
          *(ushort4v*)(Vt + base) = v;
        }
      }
    }
  } else {
#pragma unroll
    for (int i = 0; i < 4; ++i) {
      int m = (int)am0 + wr * 64 + i * 16 + rI * 4;
#pragma unroll
      for (int jn = 0; jn < 4; ++jn) {
        int n = (int)bn0 + wc * 64 + jn * 16 + cI;
        float bb = bO[n];
        floatx4 c = acc[i][jn];
        out[(long)m * 1024 + n]       = c[0] + bb;
        out[(long)(m + 1) * 1024 + n] = c[1] + bb;
        out[(long)(m + 2) * 1024 + n] = c[2] + bb;
        out[(long)(m + 3) * 1024 + n] = c[3] + bb;
      }
    }
  }
}

// ---------------- flash attention v2 ----------------
// 1024 blocks (XCD-grouped), 256 thr (4 waves x 16 q-rows), KVBLK=32.
// K+V double-buffered via global_load_lds, 1 barrier per k-tile.
// sK XOR-swizzled via pre-permuted global source (linear LDS dest).
__global__ __launch_bounds__(256, 2) void k_attn(
    const u16* __restrict__ Q, const u16* __restrict__ K,
    const u16* __restrict__ Vt, u16* __restrict__ Z) {
  extern __shared__ u16 smem[];
  u16* sK = smem;            // 2 x [32][256], 16B-chunk swizzled (chunk ^ (row&7))
  u16* sV = smem + 16384;    // 2 x [256][32], linear
  u16* sP = smem + 32768;    // [4][16*32] per-wave
  const int tid = threadIdx.x, lane = tid & 63, w = tid >> 6;
  const int cI = lane & 15, rI = lane >> 4;
  const int role = (blockIdx.x & 7) * 128 + (blockIdx.x >> 3);  // XCD-grouped, bijective
  const int bh = role >> 5, qt = role & 31;
  const int b = bh >> 2, h = bh & 3;
  const long base = (long)bh * 2048 * 256;
  const int q0 = qt * 64 + w * 16;

  // per-lane staging offsets
  int koff_ds[4], koff_src[4], voff_src[4];
#pragma unroll
  for (int j = 0; j < 4; ++j) {
    int o = j * 4096 + w * 1024 + lane * 16;  // byte offset within 16KB tile
    koff_ds[j] = o;
    int krow = o >> 9, ks = (o >> 4) & 31;
    koff_src[j] = krow * 256 + ((ks ^ (krow & 7)) << 3);  // u16 units, inverse-swizzled source
    int vrow = o >> 6, vs = (o >> 4) & 3;
    voff_src[j] = vrow * 2048 + (vs << 3);                // u16 units (+ k0 at use)
  }
  const u16* Kg0 = K + base;
  const u16* Vg  = Vt + base;  // [256][2048]

  // Q fragments (pre-scaled by 1/16 in projection)
  short8 qf[8];
#pragma unroll
  for (int ef = 0; ef < 8; ++ef)
    qf[ef] = *(const short8*)(Q + base + (long)(q0 + cI) * 256 + ef * 32 + rI * 8);

#define STAGE(kt_, buf_) do { \
    const u16* Kg_ = Kg0 + (kt_) * 8192; \
    u16* dK_ = sK + (buf_) * 8192; \
    u16* dV_ = sV + (buf_) * 8192; \
    const int k0_ = (kt_) * 32; \
    _Pragma("unroll") \
    for (int j = 0; j < 4; ++j) gl_lds16(Kg_ + koff_src[j], (char*)dK_ + koff_ds[j]); \
    _Pragma("unroll") \
    for (int j = 0; j < 4; ++j) gl_lds16(Vg + k0_ + voff_src[j], (char*)dV_ + koff_ds[j]); \
  } while (0)

  STAGE(0, 0);

  floatx4 accz[16] = {};
  float mr[4] = {-1e30f, -1e30f, -1e30f, -1e30f};
  float lr[4] = {0.f, 0.f, 0.f, 0.f};

  __syncthreads();  // drain prologue stage

  for (int kt = 0; kt < 64; ++kt) {
    const int cur = kt & 1;
    if (kt < 63) STAGE(kt + 1, cur ^ 1);  // issue early; drained by end-of-iter barrier
    const u16* bK = sK + cur * 8192;
    const u16* bV = sV + cur * 8192;

    // QK^T : S[16q][32k]
    floatx4 accs[2] = {};
#pragma unroll
    for (int nf = 0; nf < 2; ++nf) {
      const int row = nf * 16 + cI;
      const u16* kr = bK + row * 256;
      const int sw = row & 7;
#pragma unroll
      for (int kk = 0; kk < 8; ++kk) {
        short8 kf = *(const short8*)(kr + (((kk * 4 + rI) ^ sw) << 3));
        accs[nf] = __builtin_amdgcn_mfma_f32_16x16x32_bf16(qf[kk], kf, accs[nf], 0, 0, 0);
      }
    }

    // online softmax (scale already folded into Q)
    float esc[4];
#pragma unroll
    for (int r = 0; r < 4; ++r) {
      float mx = fmaxf(accs[0][r], accs[1][r]);
      mx = fmaxf(mx, __shfl_xor(mx, 1, 16));
      mx = fmaxf(mx, __shfl_xor(mx, 2, 16));
      mx = fmaxf(mx, __shfl_xor(mx, 4, 16));
      mx = fmaxf(mx, __shfl_xor(mx, 8, 16));
      float mn = fmaxf(mr[r], mx);
      esc[r] = __expf(mr[r] - mn);
      float p0 = __expf(accs[0][r] - mn);
      float p1 = __expf(accs[1][r] - mn);
      accs[0][r] = p0; accs[1][r] = p1;
      float rs = p0 + p1;
      rs += __shfl_xor(rs, 1, 16);
      rs += __shfl_xor(rs, 2, 16);
      rs += __shfl_xor(rs, 4, 16);
      rs += __shfl_xor(rs, 8, 16);
      lr[r] = lr[r] * esc[r] + rs;
      mr[r] = mn;
    }
#pragma unroll
    for (int f = 0; f < 16; ++f) {
      accz[f][0] *= esc[0]; accz[f][1] *= esc[1];
      accz[f][2] *= esc[2]; accz[f][3] *= esc[3];
    }

    // P transpose through per-wave LDS
    u16* pw = sP + w * 512;
#pragma unroll
    for (int nf = 0; nf < 2; ++nf)
#pragma unroll
      for (int r = 0; r < 4; ++r)
        pw[(rI * 4 + r) * 32 + nf * 16 + cI] = f2bf(accs[nf][r]);
    asm volatile("s_waitcnt lgkmcnt(0)" ::: "memory");
    short8 pf = *(const short8*)(pw + cI * 32 + rI * 8);

    // PV : accz += P @ V
#pragma unroll
    for (int f = 0; f < 16; ++f) {
      short8 vf = *(const short8*)(bV + (f * 16 + cI) * 32 + rI * 8);
      accz[f] = __builtin_amdgcn_mfma_f32_16x16x32_bf16(pf, vf, accz[f], 0, 0, 0);
    }
    __syncthreads();  // drains next-tile loads + guards buffer swap
  }

  const long zb = ((long)b * 2048) * 1024 + h * 256;
#pragma unroll
  for (int r = 0; r < 4; ++r) {
    float inv = 1.f / lr[r];
    long rb = zb + (long)(q0 + rI * 4 + r) * 1024;
#pragma unroll
    for (int f = 0; f < 16; ++f)
      Z[rb + f * 16 + cI] = f2bf(accz[f][r] * inv);
  }
#undef STAGE
}

// ---------------- launch ----------------

extern "C" void kernel_launch(void* const* d_in, const int* in_sizes, int n_in,
                              void* d_out, int out_size, void* d_ws, size_t ws_size,
                              hipStream_t stream) {
  const float* x  = (const float*)d_in[0];
  const float* WQ = (const float*)d_in[1];
  const float* bQ = (const float*)d_in[2];
  const float* WK = (const float*)d_in[3];
  const float* bK = (const float*)d_in[4];
  const float* WV = (const float*)d_in[5];
  const float* bV = (const float*)d_in[6];
  const float* WO = (const float*)d_in[7];
  const float* bO = (const float*)d_in[8];
  float* out = (float*)d_out;

  char* p = (char*)d_ws;
  u16* xb   = (u16*)p; p += (size_t)16384 * 1024 * 2;  // x bf16; reused later as Z
  u16* wqkv = (u16*)p; p += (size_t)3072 * 1024 * 2;
  u16* wo   = (u16*)p; p += (size_t)1024 * 1024 * 2;
  u16* Qb   = (u16*)p; p += (size_t)32 * 2048 * 256 * 2;
  u16* Kb   = (u16*)p; p += (size_t)32 * 2048 * 256 * 2;
  u16* Vtb  = (u16*)p; p += (size_t)32 * 256 * 2048 * 2;
  u16* Zb   = xb;  // alias: xb dead after k_gemm<0>

  const int attn_lds = 69632;  // 2*16KB K + 2*16KB V + 4KB P
  (void)hipFuncSetAttribute((const void*)k_attn,
                            hipFuncAttributeMaxDynamicSharedMemorySize, attn_lds);

  k_cvt_x<<<dim3(4096), dim3(256), 0, stream>>>(x, xb, (long)16384 * 1024);
  k_cvt_w<<<dim3(16384), dim3(256), 0, stream>>>(WQ, WK, WV, WO, wqkv, wo);
  k_gemm<0><<<dim3(24, 128), dim3(256), 0, stream>>>(xb, wqkv, Qb, Kb, Vtb, bQ, bK, bV,
                                                     (float*)nullptr, (const float*)nullptr);
  k_attn<<<dim3(1024), dim3(256), attn_lds, stream>>>(Qb, Kb, Vtb, Zb);
  k_gemm<1><<<dim3(8, 128), dim3(256), 0, stream>>>(Zb, wo,
                                                    (u16*)nullptr, (u16*)nullptr, (u16*)nullptr,
                                                    (const float*)nullptr, (const float*)nullptr, (const float*)nullptr,
                                                    out, bO);
}

// Round 3
// 421.543 us; speedup vs baseline: 1.8494x; 1.3184x over previous
//
#include <hip/hip_runtime.h>

typedef __attribute__((ext_vector_type(8))) short short8;
typedef __attribute__((ext_vector_type(4))) float floatx4;
typedef __attribute__((ext_vector_type(16))) float floatx16;
typedef __attribute__((ext_vector_type(4))) unsigned short ushort4v;
typedef unsigned short u16;

__device__ __forceinline__ u16 f2bf(float f) {
  unsigned u = __float_as_uint(f);
  u += 0x7fffu + ((u >> 16) & 1u);
  return (u16)(u >> 16);
}

__device__ __forceinline__ void gl_lds16(const void* g, void* l) {
  __builtin_amdgcn_global_load_lds((const __attribute__((address_space(1))) void*)g,
                                   (__attribute__((address_space(3))) void*)l, 16, 0, 0);
}

__device__ __forceinline__ float bpermf(float v, int srclane) {
  return __int_as_float(__builtin_amdgcn_ds_bpermute(srclane << 2, __float_as_int(v)));
}

// ---------------- converts ----------------

__global__ void k_cvt_x(const float* __restrict__ x, u16* __restrict__ o, long n) {
  long i = ((long)blockIdx.x * blockDim.x + threadIdx.x) * 8;
  long stride = (long)gridDim.x * blockDim.x * 8;
  for (; i < n; i += stride) {
    float4 a = *(const float4*)(x + i);
    float4 b = *(const float4*)(x + i + 4);
    ushort4v r0 = { f2bf(a.x), f2bf(a.y), f2bf(a.z), f2bf(a.w) };
    ushort4v r1 = { f2bf(b.x), f2bf(b.y), f2bf(b.z), f2bf(b.w) };
    *(ushort4v*)(o + i) = r0;
    *(ushort4v*)(o + i + 4) = r1;
  }
}

// wqkv: [n=(t*1024+h*256+e)][k=d] bf16 ; wo: [n=d][k=h*256+e] bf16
__global__ void k_cvt_w(const float* __restrict__ WQ, const float* __restrict__ WK,
                        const float* __restrict__ WV, const float* __restrict__ WO,
                        u16* __restrict__ wqkv, u16* __restrict__ wo) {
  int idx = blockIdx.x * blockDim.x + threadIdx.x;
  const int NW = 3072 * 1024;
  if (idx < NW) {
    int n = idx >> 10, k = idx & 1023;
    int t = n >> 10, h = (n >> 8) & 3, e = n & 255;
    const float* W = (t == 0) ? WQ : (t == 1) ? WK : WV;
    wqkv[idx] = f2bf(W[((h * 1024) + k) * 256 + e]);
  } else if (idx < NW + 1024 * 1024) {
    int j = idx - NW;
    int d = j >> 10, k = j & 1023;
    wo[j] = f2bf(WO[(long)k * 1024 + d]);
  }
}

// ---------------- GEMM: C[M,*] = A[M,1024] * Bt[N,1024]^T ----------------
template<int EPI>
__global__ __launch_bounds__(256, 2) void k_gemm(
    const u16* __restrict__ A, const u16* __restrict__ Bt,
    u16* __restrict__ Qo, u16* __restrict__ Ko, u16* __restrict__ Vt,
    const float* __restrict__ bQ, const float* __restrict__ bK, const float* __restrict__ bV,
    float* __restrict__ out, const float* __restrict__ bO) {
  __shared__ u16 sA[128 * 64];
  __shared__ u16 sB[128 * 64];
  const int tid = threadIdx.x;
  const int lane = tid & 63, w = tid >> 6;
  const int wr = w >> 1, wc = w & 1;
  const int cI = lane & 15, rI = lane >> 4;
  const long am0 = (long)blockIdx.y * 128;
  const long bn0 = (long)blockIdx.x * 128;
  floatx4 acc[4][4] = {};

  for (int kt = 0; kt < 1024; kt += 64) {
#pragma unroll
    for (int j = 0; j < 4; ++j) {
      int o = j * 4096 + w * 1024 + lane * 16;
      int row = o >> 7, c = (o & 127) >> 1;
      gl_lds16(A + (am0 + row) * 1024 + kt + c, (char*)sA + o);
      gl_lds16(Bt + (bn0 + row) * 1024 + kt + c, (char*)sB + o);
    }
    __syncthreads();
#pragma unroll
    for (int kk = 0; kk < 2; ++kk) {
      short8 af[4], bf[4];
      const int ko = kk * 64 + rI * 16;
#pragma unroll
      for (int i = 0; i < 4; ++i) {
        af[i] = *(const short8*)((const char*)sA + (wr * 64 + i * 16 + cI) * 128 + ko);
        bf[i] = *(const short8*)((const char*)sB + (wc * 64 + i * 16 + cI) * 128 + ko);
      }
#pragma unroll
      for (int i = 0; i < 4; ++i)
#pragma unroll
        for (int jn = 0; jn < 4; ++jn)
          acc[i][jn] = __builtin_amdgcn_mfma_f32_16x16x32_bf16(af[i], bf[jn], acc[i][jn], 0, 0, 0);
    }
    __syncthreads();
  }

  if (EPI == 0) {
    const int t = (int)(bn0 >> 10);
    const float* bias = (t == 0) ? bQ : (t == 1) ? bK : bV;
    // fold attn scale AND log2(e) into Q so softmax uses exp2 directly
    const float sc = (t == 0) ? 0.0625f * 1.44269504088896f : 1.0f;
#pragma unroll
    for (int i = 0; i < 4; ++i) {
      int m = (int)am0 + wr * 64 + i * 16 + rI * 4;
      int b = m >> 11, s = m & 2047;
#pragma unroll
      for (int jn = 0; jn < 4; ++jn) {
        int n = (int)bn0 + wc * 64 + jn * 16 + cI;
        int h = (n >> 8) & 3, e = n & 255;
        float bb = bias[n & 1023];
        floatx4 c = acc[i][jn];
        if (t < 2) {
          u16* dst = (t == 0) ? Qo : Ko;
          long base = ((long)(b * 4 + h) * 2048 + s) * 256 + e;
          dst[base]       = f2bf((c[0] + bb) * sc);
          dst[base + 256] = f2bf((c[1] + bb) * sc);
          dst[base + 512] = f2bf((c[2] + bb) * sc);
          dst[base + 768] = f2bf((c[3] + bb) * sc);
        } else {
          long base = ((long)(b * 4 + h) * 256 + e) * 2048 + s;
          ushort4v v = { f2bf(c[0] + bb), f2bf(c[1] + bb), f2bf(c[2] + bb), f2bf(c[3] + bb) };
          *(ushort4v*)(Vt + base) = v;
        }
      }
    }
  } else {
#pragma unroll
    for (int i = 0; i < 4; ++i) {
      int m = (int)am0 + wr * 64 + i * 16 + rI * 4;
#pragma unroll
      for (int jn = 0; jn < 4; ++jn) {
        int n = (int)bn0 + wc * 64 + jn * 16 + cI;
        float bb = bO[n];
        floatx4 c = acc[i][jn];
        out[(long)m * 1024 + n]       = c[0] + bb;
        out[(long)(m + 1) * 1024 + n] = c[1] + bb;
        out[(long)(m + 2) * 1024 + n] = c[2] + bb;
        out[(long)(m + 3) * 1024 + n] = c[3] + bb;
      }
    }
  }
}

// ---------------- flash attention v3: swapped QK^T, 32x32 MFMA ----------------
// 512 blocks (XCD-grouped), 256 thr = 4 waves x 32 q-rows, KVBLK=32.
// Lane holds S[k][q=lane&31] -> softmax fully in-register (1 shfl per reduce).
// P->bf16 via v_cvt_pk + shfl_xor(32) exchange. Defer-max THR=8 (log2 domain).
__global__ __launch_bounds__(256, 2) void k_attn(
    const u16* __restrict__ Q, const u16* __restrict__ K,
    const u16* __restrict__ Vt, u16* __restrict__ Z) {
  extern __shared__ u16 smem[];
  u16* sK = smem;          // 2 x [32 k][256 e], 16B-chunk swizzled: C = g ^ (krow&7)
  u16* sV = smem + 16384;  // 2 x [256 e][32 k], 16B-chunk swizzled: C = g ^ ((e>>1)&3)
  const int tid = threadIdx.x, lane = tid & 63, w = tid >> 6;
  const int q = lane & 31, hi = lane >> 5;
  const int role = (blockIdx.x & 7) * 64 + (blockIdx.x >> 3);  // XCD-grouped, bijective
  const int bh = role >> 4, qt = role & 15;
  const long base = (long)bh * 2048 * 256;
  const int q0 = qt * 128 + w * 32;

  // staging offsets (gl_lds: linear LDS dest, inverse-swizzled global src)
  int off_ds[4], ksrc[4], vsrc[4];
#pragma unroll
  for (int j = 0; j < 4; ++j) {
    int o = j * 4096 + tid * 16;  // byte offset within 16KB tile
    off_ds[j] = o;
    int krow = o >> 9, kch = (o >> 4) & 31;
    ksrc[j] = krow * 256 + ((kch ^ (krow & 7)) << 3);   // u16 units
    int e = o >> 6, cr = (o >> 4) & 3;
    vsrc[j] = e * 2048 + ((cr ^ ((e >> 1) & 3)) << 3);  // u16 units (+ k0 at use)
  }
  const u16* Kg0 = K + base;
  const u16* Vg  = Vt + base;  // [256][2048]

  // Q fragments (scale*log2e pre-folded): lane holds Q[q0+q][e=ec*16+hi*8+j]
  short8 qf[16];
#pragma unroll
  for (int ec = 0; ec < 16; ++ec)
    qf[ec] = *(const short8*)(Q + base + (long)(q0 + q) * 256 + ec * 16 + hi * 8);

#define STAGE(kt_, buf_) do { \
    const u16* Kg_ = Kg0 + (kt_) * 8192; \
    const u16* Vg_ = Vg + (kt_) * 32; \
    u16* dK_ = sK + (buf_) * 8192; \
    u16* dV_ = sV + (buf_) * 8192; \
    _Pragma("unroll") \
    for (int j = 0; j < 4; ++j) gl_lds16(Kg_ + ksrc[j], (char*)dK_ + off_ds[j]); \
    _Pragma("unroll") \
    for (int j = 0; j < 4; ++j) gl_lds16(Vg_ + vsrc[j], (char*)dV_ + off_ds[j]); \
  } while (0)

  STAGE(0, 0);

  floatx16 z[8] = {};  // Z[q'][e=et*32+q], q' = (r&3)+8*(r>>2)+4*hi
  float m_run = -1e30f, l = 0.f;
  const int ksw = q & 7, vsw = (q >> 1) & 3;

  __syncthreads();

  for (int kt = 0; kt < 64; ++kt) {
    const int cur = kt & 1;
    if (kt < 63) STAGE(kt + 1, cur ^ 1);
    const char* bKp = (const char*)(sK + cur * 8192);
    const char* bVp = (const char*)(sV + cur * 8192);

    // QK^T swapped: S = K(32k x e) * Q^T -> lane holds S[k'][q], k'=(r&3)+8*(r>>2)+4*hi
    floatx16 s = {};
    __builtin_amdgcn_s_setprio(1);
#pragma unroll
    for (int ec = 0; ec < 16; ++ec) {
      short8 kf = *(const short8*)(bKp + (q << 9) + ((((ec << 1) | hi) ^ ksw) << 4));
      s = __builtin_amdgcn_mfma_f32_32x32x16_bf16(kf, qf[ec], s, 0, 0, 0);
    }
    __builtin_amdgcn_s_setprio(0);

    // row max (in-register) + cross-half
    float pm = s[0];
#pragma unroll
    for (int r = 1; r < 16; ++r) pm = fmaxf(pm, s[r]);
    pm = fmaxf(pm, __shfl_xor(pm, 32));

    if (!__all(pm <= m_run + 8.f)) {  // defer-max: rescale only on real growth
      float mn = fmaxf(m_run, pm);
      float esc = exp2f(m_run - mn);
      l *= esc;
      m_run = mn;
      float escv[16];
#pragma unroll
      for (int r = 0; r < 16; ++r)
        escv[r] = bpermf(esc, ((r & 3) + 8 * (r >> 2) + 4 * hi) + 32 * hi);
#pragma unroll
      for (int et = 0; et < 8; ++et)
#pragma unroll
        for (int r = 0; r < 16; ++r) z[et][r] *= escv[r];
    }

    float p[16], rs = 0.f;
#pragma unroll
    for (int r = 0; r < 16; ++r) { p[r] = exp2f(s[r] - m_run); rs += p[r]; }
    l += rs + __shfl_xor(rs, 32);

    // pack P to bf16 pairs, then cross-half exchange to build PV A-frags
    unsigned wpk[8];
#pragma unroll
    for (int m = 0; m < 8; ++m)
      asm("v_cvt_pk_bf16_f32 %0, %1, %2" : "=v"(wpk[m]) : "v"(p[2 * m]), "v"(p[2 * m + 1]));

    short8 pa[2];
#pragma unroll
    for (int c = 0; c < 2; ++c) {
      unsigned x0 = (unsigned)__shfl_xor((int)wpk[4 * c],     32);
      unsigned x1 = (unsigned)__shfl_xor((int)wpk[4 * c + 1], 32);
      unsigned x2 = (unsigned)__shfl_xor((int)wpk[4 * c + 2], 32);
      unsigned x3 = (unsigned)__shfl_xor((int)wpk[4 * c + 3], 32);
      int4 t;
      t.x = hi ? (int)x2 : (int)wpk[4 * c];        // w[4c+2hi]@hi0
      t.y = hi ? (int)x3 : (int)wpk[4 * c + 1];    // w[4c+2hi+1]@hi0
      t.z = hi ? (int)wpk[4 * c + 2] : (int)x0;    // w[4c+2hi]@hi1
      t.w = hi ? (int)wpk[4 * c + 3] : (int)x1;    // w[4c+2hi+1]@hi1
      pa[c] = *(short8*)&t;
    }

    // PV: Z[q'][e] += P[q'][k] V[k][e]
    __builtin_amdgcn_s_setprio(1);
#pragma unroll
    for (int et = 0; et < 8; ++et)
#pragma unroll
      for (int c = 0; c < 2; ++c) {
        short8 vf = *(const short8*)(bVp + ((et * 32 + q) << 6) + ((((c << 1) | hi) ^ vsw) << 4));
        z[et] = __builtin_amdgcn_mfma_f32_32x32x16_bf16(pa[c], vf, z[et], 0, 0, 0);
      }
    __builtin_amdgcn_s_setprio(0);

    __syncthreads();  // drains next-tile gl_lds + guards buffer swap
  }

  // epilogue: per-q 1/l broadcast, normalize, write
  float linv = 1.f / l;
  float invv[16];
#pragma unroll
  for (int r = 0; r < 16; ++r)
    invv[r] = bpermf(linv, ((r & 3) + 8 * (r >> 2) + 4 * hi) + 32 * hi);

  const int b = bh >> 2, hh = bh & 3;
  const long zb = (long)b * 2048 * 1024 + hh * 256;
#pragma unroll
  for (int r = 0; r < 16; ++r) {
    const int qr = (r & 3) + 8 * (r >> 2) + 4 * hi;
    long rb = zb + (long)(q0 + qr) * 1024;
#pragma unroll
    for (int et = 0; et < 8; ++et)
      Z[rb + et * 32 + q] = f2bf(z[et][r] * invv[r]);
  }
#undef STAGE
}

// ---------------- launch ----------------

extern "C" void kernel_launch(void* const* d_in, const int* in_sizes, int n_in,
                              void* d_out, int out_size, void* d_ws, size_t ws_size,
                              hipStream_t stream) {
  const float* x  = (const float*)d_in[0];
  const float* WQ = (const float*)d_in[1];
  const float* bQ = (const float*)d_in[2];
  const float* WK = (const float*)d_in[3];
  const float* bK = (const float*)d_in[4];
  const float* WV = (const float*)d_in[5];
  const float* bV = (const float*)d_in[6];
  const float* WO = (const float*)d_in[7];
  const float* bO = (const float*)d_in[8];
  float* out = (float*)d_out;

  char* p = (char*)d_ws;
  u16* xb   = (u16*)p; p += (size_t)16384 * 1024 * 2;  // x bf16; reused later as Z
  u16* wqkv = (u16*)p; p += (size_t)3072 * 1024 * 2;
  u16* wo   = (u16*)p; p += (size_t)1024 * 1024 * 2;
  u16* Qb   = (u16*)p; p += (size_t)32 * 2048 * 256 * 2;
  u16* Kb   = (u16*)p; p += (size_t)32 * 2048 * 256 * 2;
  u16* Vtb  = (u16*)p; p += (size_t)32 * 256 * 2048 * 2;
  u16* Zb   = xb;  // alias: xb dead after k_gemm<0>

  const int attn_lds = 65536;  // 2*16KB K + 2*16KB V
  (void)hipFuncSetAttribute((const void*)k_attn,
                            hipFuncAttributeMaxDynamicSharedMemorySize, attn_lds);

  k_cvt_x<<<dim3(4096), dim3(256), 0, stream>>>(x, xb, (long)16384 * 1024);
  k_cvt_w<<<dim3(16384), dim3(256), 0, stream>>>(WQ, WK, WV, WO, wqkv, wo);
  k_gemm<0><<<dim3(24, 128), dim3(256), 0, stream>>>(xb, wqkv, Qb, Kb, Vtb, bQ, bK, bV,
                                                     (float*)nullptr, (const float*)nullptr);
  k_attn<<<dim3(512), dim3(256), attn_lds, stream>>>(Qb, Kb, Vtb, Zb);
  k_gemm<1><<<dim3(8, 128), dim3(256), 0, stream>>>(Zb, wo,
                                                    (u16*)nullptr, (u16*)nullptr, (u16*)nullptr,
                                                    (const float*)nullptr, (const float*)nullptr, (const float*)nullptr,
                                                    out, bO);
}

// Round 4
// 421.249 us; speedup vs baseline: 1.8507x; 1.0007x over previous
//
#include <hip/hip_runtime.h>

typedef __attribute__((ext_vector_type(8))) short short8;
typedef __attribute__((ext_vector_type(4))) float floatx4;
typedef __attribute__((ext_vector_type(16))) float floatx16;
typedef __attribute__((ext_vector_type(4))) unsigned short ushort4v;
typedef __attribute__((ext_vector_type(2))) unsigned int uint2v;
typedef unsigned short u16;

__device__ __forceinline__ u16 f2bf(float f) {
  unsigned u = __float_as_uint(f);
  u += 0x7fffu + ((u >> 16) & 1u);
  return (u16)(u >> 16);
}

__device__ __forceinline__ void gl_lds16(const void* g, void* l) {
  __builtin_amdgcn_global_load_lds((const __attribute__((address_space(1))) void*)g,
                                   (__attribute__((address_space(3))) void*)l, 16, 0, 0);
}

__device__ __forceinline__ float bpermf(float v, int srclane) {
  return __int_as_float(__builtin_amdgcn_ds_bpermute(srclane << 2, __float_as_int(v)));
}

// ---------------- converts ----------------

__global__ void k_cvt_x(const float* __restrict__ x, u16* __restrict__ o, long n) {
  long i = ((long)blockIdx.x * blockDim.x + threadIdx.x) * 8;
  long stride = (long)gridDim.x * blockDim.x * 8;
  for (; i < n; i += stride) {
    float4 a = *(const float4*)(x + i);
    float4 b = *(const float4*)(x + i + 4);
    ushort4v r0 = { f2bf(a.x), f2bf(a.y), f2bf(a.z), f2bf(a.w) };
    ushort4v r1 = { f2bf(b.x), f2bf(b.y), f2bf(b.z), f2bf(b.w) };
    *(ushort4v*)(o + i) = r0;
    *(ushort4v*)(o + i + 4) = r1;
  }
}

// Tiled transpose (coalesced read + write):
//  blocks 0..767 : wqkv[(t*1024+h*256+e)][k=d] <- W_t[h][d][e]  (12 x [1024][256] transposes)
//  blocks 768..1023 : wo[d][c=h*256+e] <- WO[c][d]               (1024x1024 transpose)
__global__ __launch_bounds__(256) void k_cvt_w(
    const float* __restrict__ WQ, const float* __restrict__ WK,
    const float* __restrict__ WV, const float* __restrict__ WO,
    u16* __restrict__ wqkv, u16* __restrict__ wo) {
  __shared__ float tile[64][65];
  const int bid = blockIdx.x;
  const float* src;
  u16* dst;
  int C, R, r0, c0;
  if (bid < 768) {
    int th = bid >> 6;          // 0..11
    int tid6 = bid & 63;        // 16 k-tiles x 4 e-tiles
    int t = th >> 2, h = th & 3;
    src = ((t == 0) ? WQ : (t == 1) ? WK : WV) + h * 1024 * 256;
    dst = wqkv + (size_t)(t * 1024 + h * 256) * 1024;
    R = 1024; C = 256;
    r0 = (tid6 & 15) * 64;
    c0 = (tid6 >> 4) * 64;
  } else {
    int tid6 = bid - 768;       // 16 x 16
    src = WO; dst = wo;
    R = 1024; C = 1024;
    r0 = (tid6 & 15) * 64;
    c0 = (tid6 >> 4) * 64;
  }
  const int tx = threadIdx.x & 15, ty = threadIdx.x >> 4;
#pragma unroll
  for (int i = 0; i < 4; ++i) {
    int r = ty + 16 * i;
    float4 v = *(const float4*)(src + (long)(r0 + r) * C + c0 + tx * 4);
    tile[r][tx * 4 + 0] = v.x;
    tile[r][tx * 4 + 1] = v.y;
    tile[r][tx * 4 + 2] = v.z;
    tile[r][tx * 4 + 3] = v.w;
  }
  __syncthreads();
#pragma unroll
  for (int i = 0; i < 4; ++i) {
    int c = ty + 16 * i;
    ushort4v o = { f2bf(tile[tx * 4 + 0][c]), f2bf(tile[tx * 4 + 1][c]),
                   f2bf(tile[tx * 4 + 2][c]), f2bf(tile[tx * 4 + 3][c]) };
    *(ushort4v*)(dst + (long)(c0 + c) * R + r0 + tx * 4) = o;
  }
}

// ---------------- GEMM: C[M,*] = A[M,1024] * Bt[N,1024]^T ----------------
template<int EPI>
__global__ __launch_bounds__(256, 2) void k_gemm(
    const u16* __restrict__ A, const u16* __restrict__ Bt,
    u16* __restrict__ Qo, u16* __restrict__ Ko, u16* __restrict__ Vt,
    const float* __restrict__ bQ, const float* __restrict__ bK, const float* __restrict__ bV,
    float* __restrict__ out, const float* __restrict__ bO) {
  __shared__ u16 sA[128 * 64];
  __shared__ u16 sB[128 * 64];
  const int tid = threadIdx.x;
  const int lane = tid & 63, w = tid >> 6;
  const int wr = w >> 1, wc = w & 1;
  const int cI = lane & 15, rI = lane >> 4;
  const long am0 = (long)blockIdx.y * 128;
  const long bn0 = (long)blockIdx.x * 128;
  floatx4 acc[4][4] = {};

  for (int kt = 0; kt < 1024; kt += 64) {
#pragma unroll
    for (int j = 0; j < 4; ++j) {
      int o = j * 4096 + w * 1024 + lane * 16;
      int row = o >> 7, c = (o & 127) >> 1;
      gl_lds16(A + (am0 + row) * 1024 + kt + c, (char*)sA + o);
      gl_lds16(Bt + (bn0 + row) * 1024 + kt + c, (char*)sB + o);
    }
    __syncthreads();
#pragma unroll
    for (int kk = 0; kk < 2; ++kk) {
      short8 af[4], bf[4];
      const int ko = kk * 64 + rI * 16;
#pragma unroll
      for (int i = 0; i < 4; ++i) {
        af[i] = *(const short8*)((const char*)sA + (wr * 64 + i * 16 + cI) * 128 + ko);
        bf[i] = *(const short8*)((const char*)sB + (wc * 64 + i * 16 + cI) * 128 + ko);
      }
#pragma unroll
      for (int i = 0; i < 4; ++i)
#pragma unroll
        for (int jn = 0; jn < 4; ++jn)
          acc[i][jn] = __builtin_amdgcn_mfma_f32_16x16x32_bf16(af[i], bf[jn], acc[i][jn], 0, 0, 0);
    }
    __syncthreads();
  }

  if (EPI == 0) {
    const int t = (int)(bn0 >> 10);
    const float* bias = (t == 0) ? bQ : (t == 1) ? bK : bV;
    // fold attn scale AND log2(e) into Q so softmax uses exp2 directly
    const float sc = (t == 0) ? 0.0625f * 1.44269504088896f : 1.0f;
#pragma unroll
    for (int i = 0; i < 4; ++i) {
      int m = (int)am0 + wr * 64 + i * 16 + rI * 4;
      int b = m >> 11, s = m & 2047;
#pragma unroll
      for (int jn = 0; jn < 4; ++jn) {
        int n = (int)bn0 + wc * 64 + jn * 16 + cI;
        int h = (n >> 8) & 3, e = n & 255;
        float bb = bias[n & 1023];
        floatx4 c = acc[i][jn];
        if (t < 2) {
          u16* dst = (t == 0) ? Qo : Ko;
          long base = ((long)(b * 4 + h) * 2048 + s) * 256 + e;
          dst[base]       = f2bf((c[0] + bb) * sc);
          dst[base + 256] = f2bf((c[1] + bb) * sc);
          dst[base + 512] = f2bf((c[2] + bb) * sc);
          dst[base + 768] = f2bf((c[3] + bb) * sc);
        } else {
          long base = ((long)(b * 4 + h) * 256 + e) * 2048 + s;
          ushort4v v = { f2bf(c[0] + bb), f2bf(c[1] + bb), f2bf(c[2] + bb), f2bf(c[3] + bb) };
          *(ushort4v*)(Vt + base) = v;
        }
      }
    }
  } else {
#pragma unroll
    for (int i = 0; i < 4; ++i) {
      int m = (int)am0 + wr * 64 + i * 16 + rI * 4;
#pragma unroll
      for (int jn = 0; jn < 4; ++jn) {
        int n = (int)bn0 + wc * 64 + jn * 16 + cI;
        float bb = bO[n];
        floatx4 c = acc[i][jn];
        out[(long)m * 1024 + n]       = c[0] + bb;
        out[(long)(m + 1) * 1024 + n] = c[1] + bb;
        out[(long)(m + 2) * 1024 + n] = c[2] + bb;
        out[(long)(m + 3) * 1024 + n] = c[3] + bb;
      }
    }
  }
}

// ---------------- flash attention v4 ----------------
// v3 + softmax split around PV(c=0), permlane32_swap exchanges, tree max.
__global__ __launch_bounds__(256, 2) void k_attn(
    const u16* __restrict__ Q, const u16* __restrict__ K,
    const u16* __restrict__ Vt, u16* __restrict__ Z) {
  extern __shared__ u16 smem[];
  u16* sK = smem;          // 2 x [32 k][256 e], 16B-chunk swizzled: C = g ^ (krow&7)
  u16* sV = smem + 16384;  // 2 x [256 e][32 k], 16B-chunk swizzled: C = g ^ ((e>>1)&3)
  const int tid = threadIdx.x, lane = tid & 63, w = tid >> 6;
  const int q = lane & 31, hi = lane >> 5;
  const int role = (blockIdx.x & 7) * 64 + (blockIdx.x >> 3);  // XCD-grouped, bijective
  const int bh = role >> 4, qt = role & 15;
  const long base = (long)bh * 2048 * 256;
  const int q0 = qt * 128 + w * 32;

  // staging offsets (gl_lds: linear LDS dest, inverse-swizzled global src)
  int off_ds[4], ksrc[4], vsrc[4];
#pragma unroll
  for (int j = 0; j < 4; ++j) {
    int o = j * 4096 + tid * 16;  // byte offset within 16KB tile
    off_ds[j] = o;
    int krow = o >> 9, kch = (o >> 4) & 31;
    ksrc[j] = krow * 256 + ((kch ^ (krow & 7)) << 3);   // u16 units
    int e = o >> 6, cr = (o >> 4) & 3;
    vsrc[j] = e * 2048 + ((cr ^ ((e >> 1) & 3)) << 3);  // u16 units (+ k0 at use)
  }
  const u16* Kg0 = K + base;
  const u16* Vg  = Vt + base;  // [256][2048]

  // Q fragments (scale*log2e pre-folded): lane holds Q[q0+q][e=ec*16+hi*8+j]
  short8 qf[16];
#pragma unroll
  for (int ec = 0; ec < 16; ++ec)
    qf[ec] = *(const short8*)(Q + base + (long)(q0 + q) * 256 + ec * 16 + hi * 8);

#define STAGE(kt_, buf_) do { \
    const u16* Kg_ = Kg0 + (kt_) * 8192; \
    const u16* Vg_ = Vg + (kt_) * 32; \
    u16* dK_ = sK + (buf_) * 8192; \
    u16* dV_ = sV + (buf_) * 8192; \
    _Pragma("unroll") \
    for (int j = 0; j < 4; ++j) gl_lds16(Kg_ + ksrc[j], (char*)dK_ + off_ds[j]); \
    _Pragma("unroll") \
    for (int j = 0; j < 4; ++j) gl_lds16(Vg_ + vsrc[j], (char*)dV_ + off_ds[j]); \
  } while (0)

  STAGE(0, 0);

  floatx16 z[8] = {};  // Z[q'][e=et*32+q], q' = (r&3)+8*(r>>2)+4*hi
  float m_run = -1e30f, l = 0.f;
  const int ksw = q & 7, vsw = (q >> 1) & 3;

  __syncthreads();

  for (int kt = 0; kt < 64; ++kt) {
    const int cur = kt & 1;
    if (kt < 63) STAGE(kt + 1, cur ^ 1);
    const char* bKp = (const char*)(sK + cur * 8192);
    const char* bVp = (const char*)(sV + cur * 8192);

    // QK^T swapped: lane holds S[k'][q], k' = (r&3)+8*(r>>2)+4*hi
    floatx16 s = {};
    __builtin_amdgcn_s_setprio(1);
#pragma unroll
    for (int ec = 0; ec < 16; ++ec) {
      short8 kf = *(const short8*)(bKp + (q << 9) + ((((ec << 1) | hi) ^ ksw) << 4));
      s = __builtin_amdgcn_mfma_f32_32x32x16_bf16(kf, qf[ec], s, 0, 0, 0);
    }
    __builtin_amdgcn_s_setprio(0);

    // tree max + cross-half via permlane32_swap (pure VALU)
    float m0 = fmaxf(s[0], s[1]),  m1 = fmaxf(s[2], s[3]);
    float m2 = fmaxf(s[4], s[5]),  m3 = fmaxf(s[6], s[7]);
    float m4 = fmaxf(s[8], s[9]),  m5 = fmaxf(s[10], s[11]);
    float m6 = fmaxf(s[12], s[13]), m7 = fmaxf(s[14], s[15]);
    m0 = fmaxf(m0, m1); m2 = fmaxf(m2, m3); m4 = fmaxf(m4, m5); m6 = fmaxf(m6, m7);
    m0 = fmaxf(m0, m2); m4 = fmaxf(m4, m6);
    float pm = fmaxf(m0, m4);
    {
      uint2v sw = __builtin_amdgcn_permlane32_swap(__float_as_uint(pm), __float_as_uint(pm), false, false);
      pm = fmaxf(__uint_as_float(sw[0]), __uint_as_float(sw[1]));
    }

    if (!__all(pm <= m_run + 8.f)) {  // defer-max: rescale only on real growth
      float mn = fmaxf(m_run, pm);
      float esc = exp2f(m_run - mn);
      l *= esc;
      m_run = mn;
      float escv[16];
#pragma unroll
      for (int r = 0; r < 16; ++r)
        escv[r] = bpermf(esc, ((r & 3) + 8 * (r >> 2) + 4 * hi) + 32 * hi);
#pragma unroll
      for (int et = 0; et < 8; ++et)
#pragma unroll
        for (int r = 0; r < 16; ++r) z[et][r] *= escv[r];
    }

    // ---- phase A: p[0..7] -> pa0 -> PV c=0 ----
    float rs = 0.f;
    float pA[8];
#pragma unroll
    for (int r = 0; r < 8; ++r) { pA[r] = exp2f(s[r] - m_run); rs += pA[r]; }
    unsigned w0, w1, w2, w3;
    asm("v_cvt_pk_bf16_f32 %0, %1, %2" : "=v"(w0) : "v"(pA[0]), "v"(pA[1]));
    asm("v_cvt_pk_bf16_f32 %0, %1, %2" : "=v"(w1) : "v"(pA[2]), "v"(pA[3]));
    asm("v_cvt_pk_bf16_f32 %0, %1, %2" : "=v"(w2) : "v"(pA[4]), "v"(pA[5]));
    asm("v_cvt_pk_bf16_f32 %0, %1, %2" : "=v"(w3) : "v"(pA[6]), "v"(pA[7]));
    uint2v e02 = __builtin_amdgcn_permlane32_swap(w0, w2, false, false);
    uint2v e13 = __builtin_amdgcn_permlane32_swap(w1, w3, false, false);
    int4 t0i = { (int)e02[0], (int)e13[0], (int)e02[1], (int)e13[1] };
    short8 pa0 = *(short8*)&t0i;

    __builtin_amdgcn_s_setprio(1);
#pragma unroll
    for (int et = 0; et < 8; ++et) {
      short8 vf = *(const short8*)(bVp + ((et * 32 + q) << 6) + (((hi ^ vsw) & 3) << 4));
      z[et] = __builtin_amdgcn_mfma_f32_32x32x16_bf16(pa0, vf, z[et], 0, 0, 0);
    }
    __builtin_amdgcn_s_setprio(0);

    // ---- phase B: p[8..15] -> pa1 -> PV c=1 (VALU overlaps c=0 MFMAs) ----
    float pB[8];
#pragma unroll
    for (int r = 0; r < 8; ++r) { pB[r] = exp2f(s[r + 8] - m_run); rs += pB[r]; }
    unsigned w4, w5, w6, w7;
    asm("v_cvt_pk_bf16_f32 %0, %1, %2" : "=v"(w4) : "v"(pB[0]), "v"(pB[1]));
    asm("v_cvt_pk_bf16_f32 %0, %1, %2" : "=v"(w5) : "v"(pB[2]), "v"(pB[3]));
    asm("v_cvt_pk_bf16_f32 %0, %1, %2" : "=v"(w6) : "v"(pB[4]), "v"(pB[5]));
    asm("v_cvt_pk_bf16_f32 %0, %1, %2" : "=v"(w7) : "v"(pB[6]), "v"(pB[7]));
    uint2v e46 = __builtin_amdgcn_permlane32_swap(w4, w6, false, false);
    uint2v e57 = __builtin_amdgcn_permlane32_swap(w5, w7, false, false);
    int4 t1i = { (int)e46[0], (int)e57[0], (int)e46[1], (int)e57[1] };
    short8 pa1 = *(short8*)&t1i;

    {
      uint2v sw = __builtin_amdgcn_permlane32_swap(__float_as_uint(rs), __float_as_uint(rs), false, false);
      l += __uint_as_float(sw[0]) + __uint_as_float(sw[1]);
    }

    __builtin_amdgcn_s_setprio(1);
#pragma unroll
    for (int et = 0; et < 8; ++et) {
      short8 vf = *(const short8*)(bVp + ((et * 32 + q) << 6) + ((((2 | hi) ^ vsw) & 3) << 4));
      z[et] = __builtin_amdgcn_mfma_f32_32x32x16_bf16(pa1, vf, z[et], 0, 0, 0);
    }
    __builtin_amdgcn_s_setprio(0);

    __syncthreads();  // drains next-tile gl_lds + guards buffer swap
  }

  // epilogue: per-q 1/l broadcast, normalize, write
  float linv = 1.f / l;
  float invv[16];
#pragma unroll
  for (int r = 0; r < 16; ++r)
    invv[r] = bpermf(linv, ((r & 3) + 8 * (r >> 2) + 4 * hi) + 32 * hi);

  const int b = bh >> 2, hh = bh & 3;
  const long zb = (long)b * 2048 * 1024 + hh * 256;
#pragma unroll
  for (int r = 0; r < 16; ++r) {
    const int qr = (r & 3) + 8 * (r >> 2) + 4 * hi;
    long rb = zb + (long)(q0 + qr) * 1024;
#pragma unroll
    for (int et = 0; et < 8; ++et)
      Z[rb + et * 32 + q] = f2bf(z[et][r] * invv[r]);
  }
#undef STAGE
}

// ---------------- launch ----------------

extern "C" void kernel_launch(void* const* d_in, const int* in_sizes, int n_in,
                              void* d_out, int out_size, void* d_ws, size_t ws_size,
                              hipStream_t stream) {
  const float* x  = (const float*)d_in[0];
  const float* WQ = (const float*)d_in[1];
  const float* bQ = (const float*)d_in[2];
  const float* WK = (const float*)d_in[3];
  const float* bK = (const float*)d_in[4];
  const float* WV = (const float*)d_in[5];
  const float* bV = (const float*)d_in[6];
  const float* WO = (const float*)d_in[7];
  const float* bO = (const float*)d_in[8];
  float* out = (float*)d_out;

  char* p = (char*)d_ws;
  u16* xb   = (u16*)p; p += (size_t)16384 * 1024 * 2;  // x bf16; reused later as Z
  u16* wqkv = (u16*)p; p += (size_t)3072 * 1024 * 2;
  u16* wo   = (u16*)p; p += (size_t)1024 * 1024 * 2;
  u16* Qb   = (u16*)p; p += (size_t)32 * 2048 * 256 * 2;
  u16* Kb   = (u16*)p; p += (size_t)32 * 2048 * 256 * 2;
  u16* Vtb  = (u16*)p; p += (size_t)32 * 256 * 2048 * 2;
  u16* Zb   = xb;  // alias: xb dead after k_gemm<0>

  const int attn_lds = 65536;  // 2*16KB K + 2*16KB V
  (void)hipFuncSetAttribute((const void*)k_attn,
                            hipFuncAttributeMaxDynamicSharedMemorySize, attn_lds);

  k_cvt_x<<<dim3(4096), dim3(256), 0, stream>>>(x, xb, (long)16384 * 1024);
  k_cvt_w<<<dim3(1024), dim3(256), 0, stream>>>(WQ, WK, WV, WO, wqkv, wo);
  k_gemm<0><<<dim3(24, 128), dim3(256), 0, stream>>>(xb, wqkv, Qb, Kb, Vtb, bQ, bK, bV,
                                                     (float*)nullptr, (const float*)nullptr);
  k_attn<<<dim3(512), dim3(256), attn_lds, stream>>>(Qb, Kb, Vtb, Zb);
  k_gemm<1><<<dim3(8, 128), dim3(256), 0, stream>>>(Zb, wo,
                                                    (u16*)nullptr, (u16*)nullptr, (u16*)nullptr,
                                                    (const float*)nullptr, (const float*)nullptr, (const float*)nullptr,
                                                    out, bO);
}

// Round 5
// 391.881 us; speedup vs baseline: 1.9894x; 1.0749x over previous
//
#include <hip/hip_runtime.h>

typedef __attribute__((ext_vector_type(8))) short short8;
typedef __attribute__((ext_vector_type(4))) float floatx4;
typedef __attribute__((ext_vector_type(16))) float floatx16;
typedef __attribute__((ext_vector_type(4))) unsigned short ushort4v;
typedef __attribute__((ext_vector_type(2))) unsigned int uint2v;
typedef unsigned short u16;

__device__ __forceinline__ u16 f2bf(float f) {
  unsigned u = __float_as_uint(f);
  u += 0x7fffu + ((u >> 16) & 1u);
  return (u16)(u >> 16);
}

__device__ __forceinline__ void gl_lds16(const void* g, void* l) {
  __builtin_amdgcn_global_load_lds((const __attribute__((address_space(1))) void*)g,
                                   (__attribute__((address_space(3))) void*)l, 16, 0, 0);
}

__device__ __forceinline__ float bpermf(float v, int srclane) {
  return __int_as_float(__builtin_amdgcn_ds_bpermute(srclane << 2, __float_as_int(v)));
}

// ---------------- converts ----------------

__global__ void k_cvt_x(const float* __restrict__ x, u16* __restrict__ o, long n) {
  long i = ((long)blockIdx.x * blockDim.x + threadIdx.x) * 8;
  long stride = (long)gridDim.x * blockDim.x * 8;
  for (; i < n; i += stride) {
    float4 a = *(const float4*)(x + i);
    float4 b = *(const float4*)(x + i + 4);
    ushort4v r0 = { f2bf(a.x), f2bf(a.y), f2bf(a.z), f2bf(a.w) };
    ushort4v r1 = { f2bf(b.x), f2bf(b.y), f2bf(b.z), f2bf(b.w) };
    *(ushort4v*)(o + i) = r0;
    *(ushort4v*)(o + i + 4) = r1;
  }
}

// Tiled transpose (coalesced read + write)
__global__ __launch_bounds__(256) void k_cvt_w(
    const float* __restrict__ WQ, const float* __restrict__ WK,
    const float* __restrict__ WV, const float* __restrict__ WO,
    u16* __restrict__ wqkv, u16* __restrict__ wo) {
  __shared__ float tile[64][65];
  const int bid = blockIdx.x;
  const float* src;
  u16* dst;
  int C, R, r0, c0;
  if (bid < 768) {
    int th = bid >> 6;
    int tid6 = bid & 63;
    int t = th >> 2, h = th & 3;
    src = ((t == 0) ? WQ : (t == 1) ? WK : WV) + h * 1024 * 256;
    dst = wqkv + (size_t)(t * 1024 + h * 256) * 1024;
    R = 1024; C = 256;
    r0 = (tid6 & 15) * 64;
    c0 = (tid6 >> 4) * 64;
  } else {
    int tid6 = bid - 768;
    src = WO; dst = wo;
    R = 1024; C = 1024;
    r0 = (tid6 & 15) * 64;
    c0 = (tid6 >> 4) * 64;
  }
  const int tx = threadIdx.x & 15, ty = threadIdx.x >> 4;
#pragma unroll
  for (int i = 0; i < 4; ++i) {
    int r = ty + 16 * i;
    float4 v = *(const float4*)(src + (long)(r0 + r) * C + c0 + tx * 4);
    tile[r][tx * 4 + 0] = v.x;
    tile[r][tx * 4 + 1] = v.y;
    tile[r][tx * 4 + 2] = v.z;
    tile[r][tx * 4 + 3] = v.w;
  }
  __syncthreads();
#pragma unroll
  for (int i = 0; i < 4; ++i) {
    int c = ty + 16 * i;
    ushort4v o = { f2bf(tile[tx * 4 + 0][c]), f2bf(tile[tx * 4 + 1][c]),
                   f2bf(tile[tx * 4 + 2][c]), f2bf(tile[tx * 4 + 3][c]) };
    *(ushort4v*)(dst + (long)(c0 + c) * R + r0 + tx * 4) = o;
  }
}

// ---------------- GEMM: C[M,*] = A[M,1024] * Bt[N,1024]^T ----------------
template<int EPI>
__global__ __launch_bounds__(256, 2) void k_gemm(
    const u16* __restrict__ A, const u16* __restrict__ Bt,
    u16* __restrict__ Qo, u16* __restrict__ Ko, u16* __restrict__ Vt,
    const float* __restrict__ bQ, const float* __restrict__ bK, const float* __restrict__ bV,
    float* __restrict__ out, const float* __restrict__ bO) {
  __shared__ u16 sA[128 * 64];
  __shared__ u16 sB[128 * 64];
  const int tid = threadIdx.x;
  const int lane = tid & 63, w = tid >> 6;
  const int wr = w >> 1, wc = w & 1;
  const int cI = lane & 15, rI = lane >> 4;
  const long am0 = (long)blockIdx.y * 128;
  const long bn0 = (long)blockIdx.x * 128;
  floatx4 acc[4][4] = {};

  for (int kt = 0; kt < 1024; kt += 64) {
#pragma unroll
    for (int j = 0; j < 4; ++j) {
      int o = j * 4096 + w * 1024 + lane * 16;
      int row = o >> 7, c = (o & 127) >> 1;
      gl_lds16(A + (am0 + row) * 1024 + kt + c, (char*)sA + o);
      gl_lds16(Bt + (bn0 + row) * 1024 + kt + c, (char*)sB + o);
    }
    __syncthreads();
#pragma unroll
    for (int kk = 0; kk < 2; ++kk) {
      short8 af[4], bf[4];
      const int ko = kk * 64 + rI * 16;
#pragma unroll
      for (int i = 0; i < 4; ++i) {
        af[i] = *(const short8*)((const char*)sA + (wr * 64 + i * 16 + cI) * 128 + ko);
        bf[i] = *(const short8*)((const char*)sB + (wc * 64 + i * 16 + cI) * 128 + ko);
      }
#pragma unroll
      for (int i = 0; i < 4; ++i)
#pragma unroll
        for (int jn = 0; jn < 4; ++jn)
          acc[i][jn] = __builtin_amdgcn_mfma_f32_16x16x32_bf16(af[i], bf[jn], acc[i][jn], 0, 0, 0);
    }
    __syncthreads();
  }

  if (EPI == 0) {
    const int t = (int)(bn0 >> 10);
    const float* bias = (t == 0) ? bQ : (t == 1) ? bK : bV;
    const float sc = (t == 0) ? 0.0625f * 1.44269504088896f : 1.0f;
#pragma unroll
    for (int i = 0; i < 4; ++i) {
      int m = (int)am0 + wr * 64 + i * 16 + rI * 4;
      int b = m >> 11, s = m & 2047;
#pragma unroll
      for (int jn = 0; jn < 4; ++jn) {
        int n = (int)bn0 + wc * 64 + jn * 16 + cI;
        int h = (n >> 8) & 3, e = n & 255;
        float bb = bias[n & 1023];
        floatx4 c = acc[i][jn];
        if (t < 2) {
          u16* dst = (t == 0) ? Qo : Ko;
          long base = ((long)(b * 4 + h) * 2048 + s) * 256 + e;
          dst[base]       = f2bf((c[0] + bb) * sc);
          dst[base + 256] = f2bf((c[1] + bb) * sc);
          dst[base + 512] = f2bf((c[2] + bb) * sc);
          dst[base + 768] = f2bf((c[3] + bb) * sc);
        } else {
          long base = ((long)(b * 4 + h) * 256 + e) * 2048 + s;
          ushort4v v = { f2bf(c[0] + bb), f2bf(c[1] + bb), f2bf(c[2] + bb), f2bf(c[3] + bb) };
          *(ushort4v*)(Vt + base) = v;
        }
      }
    }
  } else {
#pragma unroll
    for (int i = 0; i < 4; ++i) {
      int m = (int)am0 + wr * 64 + i * 16 + rI * 4;
#pragma unroll
      for (int jn = 0; jn < 4; ++jn) {
        int n = (int)bn0 + wc * 64 + jn * 16 + cI;
        float bb = bO[n];
        floatx4 c = acc[i][jn];
        out[(long)m * 1024 + n]       = c[0] + bb;
        out[(long)(m + 1) * 1024 + n] = c[1] + bb;
        out[(long)(m + 2) * 1024 + n] = c[2] + bb;
        out[(long)(m + 3) * 1024 + n] = c[3] + bb;
      }
    }
  }
}

// ---------------- flash attention v5: PV lagged one tile ----------------
// Iter t: interleave QK(t) serial chain with PV(t-1) independent chains;
// softmax(t) off critical path (consumed next iter). V staged one tile
// behind K; single barrier per iter guards all buffer hazards.
__global__ __launch_bounds__(256, 2) void k_attn(
    const u16* __restrict__ Q, const u16* __restrict__ K,
    const u16* __restrict__ Vt, u16* __restrict__ Z) {
  extern __shared__ u16 smem[];
  u16* sK = smem;          // 2 x [32 k][256 e], 16B-chunk swizzled: C = g ^ (krow&7)
  u16* sV = smem + 16384;  // 2 x [256 e][32 k], 16B-chunk swizzled: C = g ^ ((e>>1)&3)
  const int tid = threadIdx.x, lane = tid & 63, w = tid >> 6;
  const int q = lane & 31, hi = lane >> 5;
  const int role = (blockIdx.x & 7) * 64 + (blockIdx.x >> 3);  // XCD-grouped, bijective
  const int bh = role >> 4, qt = role & 15;
  const long base = (long)bh * 2048 * 256;
  const int q0 = qt * 128 + w * 32;

  int off_ds[4], ksrc[4], vsrc[4];
#pragma unroll
  for (int j = 0; j < 4; ++j) {
    int o = j * 4096 + tid * 16;
    off_ds[j] = o;
    int krow = o >> 9, kch = (o >> 4) & 31;
    ksrc[j] = krow * 256 + ((kch ^ (krow & 7)) << 3);
    int e = o >> 6, cr = (o >> 4) & 3;
    vsrc[j] = e * 2048 + ((cr ^ ((e >> 1) & 3)) << 3);
  }
  const u16* Kg0 = K + base;
  const u16* Vg  = Vt + base;  // [256][2048]

  short8 qf[16];
#pragma unroll
  for (int ec = 0; ec < 16; ++ec)
    qf[ec] = *(const short8*)(Q + base + (long)(q0 + q) * 256 + ec * 16 + hi * 8);

#define STAGE_K(kt_, buf_) do { \
    const u16* Kg_ = Kg0 + (kt_) * 8192; \
    u16* dK_ = sK + (buf_) * 8192; \
    _Pragma("unroll") \
    for (int j = 0; j < 4; ++j) gl_lds16(Kg_ + ksrc[j], (char*)dK_ + off_ds[j]); \
  } while (0)
#define STAGE_V(kt_, buf_) do { \
    const u16* Vg_ = Vg + (kt_) * 32; \
    u16* dV_ = sV + (buf_) * 8192; \
    _Pragma("unroll") \
    for (int j = 0; j < 4; ++j) gl_lds16(Vg_ + vsrc[j], (char*)dV_ + off_ds[j]); \
  } while (0)

  STAGE_K(0, 0);

  floatx16 z[8] = {};  // Z[q'][e=et*32+q], q' = (r&3)+8*(r>>2)+4*hi
  float m_run = -1e30f, l = 0.f;
  const int ksw = q & 7, vsw = (q >> 1) & 3;
  short8 pa0 = {}, pa1 = {};  // packed P of tile t-1

  __syncthreads();  // K(0) ready

  for (int t = 0; t < 64; ++t) {
    const int cb = t & 1;
    if (t < 63) STAGE_K(t + 1, cb ^ 1);
    STAGE_V(t, cb);
    const char* pK = (const char*)(sK + cb * 8192);        // K(t)
    const char* pV = (const char*)(sV + (cb ^ 1) * 8192);  // V(t-1)

    // QK(t) serial chain hand-interleaved with PV(t-1) independent chains
    floatx16 s = {};
    __builtin_amdgcn_s_setprio(1);
    if (t > 0) {
#pragma unroll
      for (int u = 0; u < 8; ++u) {
        short8 kf0 = *(const short8*)(pK + (q << 9) + ((((4 * u) | hi) ^ ksw) << 4));
        s = __builtin_amdgcn_mfma_f32_32x32x16_bf16(kf0, qf[2 * u], s, 0, 0, 0);
        short8 vf0 = *(const short8*)(pV + ((u * 32 + q) << 6) + (((hi ^ vsw) & 3) << 4));
        z[u] = __builtin_amdgcn_mfma_f32_32x32x16_bf16(pa0, vf0, z[u], 0, 0, 0);
        short8 kf1 = *(const short8*)(pK + (q << 9) + ((((4 * u + 2) | hi) ^ ksw) << 4));
        s = __builtin_amdgcn_mfma_f32_32x32x16_bf16(kf1, qf[2 * u + 1], s, 0, 0, 0);
        short8 vf1 = *(const short8*)(pV + ((u * 32 + q) << 6) + ((((2 | hi) ^ vsw) & 3) << 4));
        z[u] = __builtin_amdgcn_mfma_f32_32x32x16_bf16(pa1, vf1, z[u], 0, 0, 0);
      }
    } else {
#pragma unroll
      for (int ec = 0; ec < 16; ++ec) {
        short8 kf = *(const short8*)(pK + (q << 9) + ((((2 * ec) | hi) ^ ksw) << 4));
        s = __builtin_amdgcn_mfma_f32_32x32x16_bf16(kf, qf[ec], s, 0, 0, 0);
      }
    }
    __builtin_amdgcn_s_setprio(0);

    // softmax(t): tree max + cross-half (permlane, pure VALU)
    float m0 = fmaxf(s[0], s[1]),  m1 = fmaxf(s[2], s[3]);
    float m2 = fmaxf(s[4], s[5]),  m3 = fmaxf(s[6], s[7]);
    float m4 = fmaxf(s[8], s[9]),  m5 = fmaxf(s[10], s[11]);
    float m6 = fmaxf(s[12], s[13]), m7 = fmaxf(s[14], s[15]);
    m0 = fmaxf(m0, m1); m2 = fmaxf(m2, m3); m4 = fmaxf(m4, m5); m6 = fmaxf(m6, m7);
    m0 = fmaxf(m0, m2); m4 = fmaxf(m4, m6);
    float pm = fmaxf(m0, m4);
    {
      uint2v sw = __builtin_amdgcn_permlane32_swap(__float_as_uint(pm), __float_as_uint(pm), false, false);
      pm = fmaxf(__uint_as_float(sw[0]), __uint_as_float(sw[1]));
    }

    if (!__all(pm <= m_run + 8.f)) {  // defer-max; z-mult ordered after PV(t-1) via reg deps
      float mn = fmaxf(m_run, pm);
      float esc = exp2f(m_run - mn);
      l *= esc;
      m_run = mn;
      float escv[16];
#pragma unroll
      for (int r = 0; r < 16; ++r)
        escv[r] = bpermf(esc, ((r & 3) + 8 * (r >> 2) + 4 * hi) + 32 * hi);
#pragma unroll
      for (int et = 0; et < 8; ++et)
#pragma unroll
        for (int r = 0; r < 16; ++r) z[et][r] *= escv[r];
    }

    float p[16], rs = 0.f;
#pragma unroll
    for (int r = 0; r < 16; ++r) { p[r] = exp2f(s[r] - m_run); rs += p[r]; }
    {
      uint2v sw = __builtin_amdgcn_permlane32_swap(__float_as_uint(rs), __float_as_uint(rs), false, false);
      l += __uint_as_float(sw[0]) + __uint_as_float(sw[1]);
    }

    // pack P(t) -> pa0/pa1 (read next iter / epilogue)
    unsigned w0, w1, w2, w3, w4, w5, w6, w7;
    asm("v_cvt_pk_bf16_f32 %0, %1, %2" : "=v"(w0) : "v"(p[0]), "v"(p[1]));
    asm("v_cvt_pk_bf16_f32 %0, %1, %2" : "=v"(w1) : "v"(p[2]), "v"(p[3]));
    asm("v_cvt_pk_bf16_f32 %0, %1, %2" : "=v"(w2) : "v"(p[4]), "v"(p[5]));
    asm("v_cvt_pk_bf16_f32 %0, %1, %2" : "=v"(w3) : "v"(p[6]), "v"(p[7]));
    asm("v_cvt_pk_bf16_f32 %0, %1, %2" : "=v"(w4) : "v"(p[8]), "v"(p[9]));
    asm("v_cvt_pk_bf16_f32 %0, %1, %2" : "=v"(w5) : "v"(p[10]), "v"(p[11]));
    asm("v_cvt_pk_bf16_f32 %0, %1, %2" : "=v"(w6) : "v"(p[12]), "v"(p[13]));
    asm("v_cvt_pk_bf16_f32 %0, %1, %2" : "=v"(w7) : "v"(p[14]), "v"(p[15]));
    uint2v e02 = __builtin_amdgcn_permlane32_swap(w0, w2, false, false);
    uint2v e13 = __builtin_amdgcn_permlane32_swap(w1, w3, false, false);
    uint2v e46 = __builtin_amdgcn_permlane32_swap(w4, w6, false, false);
    uint2v e57 = __builtin_amdgcn_permlane32_swap(w5, w7, false, false);
    int4 t0i = { (int)e02[0], (int)e13[0], (int)e02[1], (int)e13[1] };
    int4 t1i = { (int)e46[0], (int)e57[0], (int)e46[1], (int)e57[1] };
    pa0 = *(short8*)&t0i;
    pa1 = *(short8*)&t1i;

    __syncthreads();  // drains staged loads + guards buffer swap
  }

  // epilogue: PV(63) from bufV[1]
  {
    const char* pV = (const char*)(sV + 8192);
#pragma unroll
    for (int u = 0; u < 8; ++u) {
      short8 vf0 = *(const short8*)(pV + ((u * 32 + q) << 6) + (((hi ^ vsw) & 3) << 4));
      z[u] = __builtin_amdgcn_mfma_f32_32x32x16_bf16(pa0, vf0, z[u], 0, 0, 0);
      short8 vf1 = *(const short8*)(pV + ((u * 32 + q) << 6) + ((((2 | hi) ^ vsw) & 3) << 4));
      z[u] = __builtin_amdgcn_mfma_f32_32x32x16_bf16(pa1, vf1, z[u], 0, 0, 0);
    }
  }

  float linv = 1.f / l;
  float invv[16];
#pragma unroll
  for (int r = 0; r < 16; ++r)
    invv[r] = bpermf(linv, ((r & 3) + 8 * (r >> 2) + 4 * hi) + 32 * hi);

  const int b = bh >> 2, hh = bh & 3;
  const long zb = (long)b * 2048 * 1024 + hh * 256;
#pragma unroll
  for (int r = 0; r < 16; ++r) {
    const int qr = (r & 3) + 8 * (r >> 2) + 4 * hi;
    long rb = zb + (long)(q0 + qr) * 1024;
#pragma unroll
    for (int et = 0; et < 8; ++et)
      Z[rb + et * 32 + q] = f2bf(z[et][r] * invv[r]);
  }
#undef STAGE_K
#undef STAGE_V
}

// ---------------- launch ----------------

extern "C" void kernel_launch(void* const* d_in, const int* in_sizes, int n_in,
                              void* d_out, int out_size, void* d_ws, size_t ws_size,
                              hipStream_t stream) {
  const float* x  = (const float*)d_in[0];
  const float* WQ = (const float*)d_in[1];
  const float* bQ = (const float*)d_in[2];
  const float* WK = (const float*)d_in[3];
  const float* bK = (const float*)d_in[4];
  const float* WV = (const float*)d_in[5];
  const float* bV = (const float*)d_in[6];
  const float* WO = (const float*)d_in[7];
  const float* bO = (const float*)d_in[8];
  float* out = (float*)d_out;

  char* p = (char*)d_ws;
  u16* xb   = (u16*)p; p += (size_t)16384 * 1024 * 2;  // x bf16; reused later as Z
  u16* wqkv = (u16*)p; p += (size_t)3072 * 1024 * 2;
  u16* wo   = (u16*)p; p += (size_t)1024 * 1024 * 2;
  u16* Qb   = (u16*)p; p += (size_t)32 * 2048 * 256 * 2;
  u16* Kb   = (u16*)p; p += (size_t)32 * 2048 * 256 * 2;
  u16* Vtb  = (u16*)p; p += (size_t)32 * 256 * 2048 * 2;
  u16* Zb   = xb;  // alias: xb dead after k_gemm<0>

  const int attn_lds = 65536;  // 2*16KB K + 2*16KB V
  (void)hipFuncSetAttribute((const void*)k_attn,
                            hipFuncAttributeMaxDynamicSharedMemorySize, attn_lds);

  k_cvt_x<<<dim3(4096), dim3(256), 0, stream>>>(x, xb, (long)16384 * 1024);
  k_cvt_w<<<dim3(1024), dim3(256), 0, stream>>>(WQ, WK, WV, WO, wqkv, wo);
  k_gemm<0><<<dim3(24, 128), dim3(256), 0, stream>>>(xb, wqkv, Qb, Kb, Vtb, bQ, bK, bV,
                                                     (float*)nullptr, (const float*)nullptr);
  k_attn<<<dim3(512), dim3(256), attn_lds, stream>>>(Qb, Kb, Vtb, Zb);
  k_gemm<1><<<dim3(8, 128), dim3(256), 0, stream>>>(Zb, wo,
                                                    (u16*)nullptr, (u16*)nullptr, (u16*)nullptr,
                                                    (const float*)nullptr, (const float*)nullptr, (const float*)nullptr,
                                                    out, bO);
}

// Round 7
// 360.047 us; speedup vs baseline: 2.1653x; 1.0884x over previous
//
#include <hip/hip_runtime.h>

typedef __attribute__((ext_vector_type(8))) short short8;
typedef __attribute__((ext_vector_type(4))) float floatx4;
typedef __attribute__((ext_vector_type(16))) float floatx16;
typedef __attribute__((ext_vector_type(4))) unsigned short ushort4v;
typedef __attribute__((ext_vector_type(2))) unsigned int uint2v;
typedef unsigned short u16;

__device__ __forceinline__ u16 f2bf(float f) {
  unsigned u = __float_as_uint(f);
  u += 0x7fffu + ((u >> 16) & 1u);
  return (u16)(u >> 16);
}

__device__ __forceinline__ void gl_lds16(const void* g, void* l) {
  __builtin_amdgcn_global_load_lds((const __attribute__((address_space(1))) void*)g,
                                   (__attribute__((address_space(3))) void*)l, 16, 0, 0);
}

__device__ __forceinline__ float bpermf(float v, int srclane) {
  return __int_as_float(__builtin_amdgcn_ds_bpermute(srclane << 2, __float_as_int(v)));
}

#define BARRIER() do { asm volatile("" ::: "memory"); __builtin_amdgcn_s_barrier(); asm volatile("" ::: "memory"); } while (0)

// ---------------- converts ----------------

__global__ void k_cvt_x(const float* __restrict__ x, u16* __restrict__ o, long n) {
  long i = ((long)blockIdx.x * blockDim.x + threadIdx.x) * 8;
  long stride = (long)gridDim.x * blockDim.x * 8;
  for (; i < n; i += stride) {
    float4 a = *(const float4*)(x + i);
    float4 b = *(const float4*)(x + i + 4);
    ushort4v r0 = { f2bf(a.x), f2bf(a.y), f2bf(a.z), f2bf(a.w) };
    ushort4v r1 = { f2bf(b.x), f2bf(b.y), f2bf(b.z), f2bf(b.w) };
    *(ushort4v*)(o + i) = r0;
    *(ushort4v*)(o + i + 4) = r1;
  }
}

// Tiled transpose (coalesced read + write)
__global__ __launch_bounds__(256) void k_cvt_w(
    const float* __restrict__ WQ, const float* __restrict__ WK,
    const float* __restrict__ WV, const float* __restrict__ WO,
    u16* __restrict__ wqkv, u16* __restrict__ wo) {
  __shared__ float tile[64][65];
  const int bid = blockIdx.x;
  const float* src;
  u16* dst;
  int C, R, r0, c0;
  if (bid < 768) {
    int th = bid >> 6;
    int tid6 = bid & 63;
    int t = th >> 2, h = th & 3;
    src = ((t == 0) ? WQ : (t == 1) ? WK : WV) + h * 1024 * 256;
    dst = wqkv + (size_t)(t * 1024 + h * 256) * 1024;
    R = 1024; C = 256;
    r0 = (tid6 & 15) * 64;
    c0 = (tid6 >> 4) * 64;
  } else {
    int tid6 = bid - 768;
    src = WO; dst = wo;
    R = 1024; C = 1024;
    r0 = (tid6 & 15) * 64;
    c0 = (tid6 >> 4) * 64;
  }
  const int tx = threadIdx.x & 15, ty = threadIdx.x >> 4;
#pragma unroll
  for (int i = 0; i < 4; ++i) {
    int r = ty + 16 * i;
    float4 v = *(const float4*)(src + (long)(r0 + r) * C + c0 + tx * 4);
    tile[r][tx * 4 + 0] = v.x;
    tile[r][tx * 4 + 1] = v.y;
    tile[r][tx * 4 + 2] = v.z;
    tile[r][tx * 4 + 3] = v.w;
  }
  __syncthreads();
#pragma unroll
  for (int i = 0; i < 4; ++i) {
    int c = ty + 16 * i;
    ushort4v o = { f2bf(tile[tx * 4 + 0][c]), f2bf(tile[tx * 4 + 1][c]),
                   f2bf(tile[tx * 4 + 2][c]), f2bf(tile[tx * 4 + 3][c]) };
    *(ushort4v*)(dst + (long)(c0 + c) * R + r0 + tx * 4) = o;
  }
}

// ---------------- 8-phase 256x256 GEMM: C[M,*] = A[M,1024] * Bt[N,1024]^T ----
// 512 thr = 8 waves (2 wm x 4 wn). Quadrant mapping: C row = MH*128+wm*64+mi*16,
// col = NH*128+wn*32+ni*16, so phase (MH,NH) reads EXACTLY one A half-tile and
// one B half-tile. Half-tile liveness (slot0 tile u, slot1 tile u+1):
//   A-lo0 dies ph2, B-lo0 ph3, A-hi0/B-hi0 ph4, A-lo1 ph6, B-lo1 ph7, A-hi1/B-hi1 ph8.
// Stage schedule (each 1 phase after old content dies):
//   ph1:A-hi(u+1)@slot1  ph2:B-hi(u+1)@slot1  ph3:A-lo(u+2)@slot0  ph4:B-lo(u+2)@slot0
//   ph5:A-hi(u+2)@slot0  ph6:B-hi(u+2)@slot0  ph7:A-lo(u+3)@slot1  ph8:B-lo(u+3)@slot1
// vmcnt(4) at ph4 (retires ...,ph1,ph2 -> tile u+1 complete before ph5) and at
// ph8 (retires ph3..ph6 -> tile u+2 complete before next ph1). Last iter: ph4
// uses vmcnt(0) (its ph3/4 stages skipped, must drain ph1/2).
template<int EPI>
__global__ __launch_bounds__(512, 2) void k_gemm8(
    const u16* __restrict__ A, const u16* __restrict__ Bt,
    u16* __restrict__ Qo, u16* __restrict__ Ko, u16* __restrict__ Vt,
    const float* __restrict__ bQ, const float* __restrict__ bK, const float* __restrict__ bV,
    float* __restrict__ out, const float* __restrict__ bO, int gridNx) {
  extern __shared__ char lds[];
  const int tid = threadIdx.x, lane = tid & 63, w = tid >> 6;
  const int wm = w >> 2, wn = w & 3;
  const int cI = lane & 15, rI = lane >> 4;
  const int nwg = gridDim.x;
  const int bid = blockIdx.x;
  const int swz = (bid & 7) * (nwg >> 3) + (bid >> 3);  // XCD-grouped (nwg%8==0)
  const int by = swz / gridNx, bx = swz % gridNx;
  const long am0 = (long)by * 256, bn0 = (long)bx * 256;

  // staging offsets: LDS linear dest, inverse-swizzled global source
  // LDS[r][c16] = G[r][c16 ^ (r&7)]  (c16 = 16B chunk, r = row within 128-row half)
  int so_ds[2], so_src[2];
#pragma unroll
  for (int jj = 0; jj < 2; ++jj) {
    int o = jj * 8192 + tid * 16;
    int row = o >> 7;
    so_ds[jj] = o;
    so_src[jj] = row * 1024 + ((((o >> 4) & 7) ^ (row & 7)) << 3);  // u16 units
  }
  const u16* gAlo = A + am0 * 1024;
  const u16* gAhi = gAlo + 128 * 1024;
  const u16* gBlo = Bt + bn0 * 1024;
  const u16* gBhi = gBlo + 128 * 1024;

  // LDS half-tile bases (bytes):
  //   A slot0: lo 0      hi 16384 | A slot1: lo 32768 hi 49152
  //   B slot0: lo 65536  hi 81920 | B slot1: lo 98304 hi 114688
#define STG(gp, kt, ldsbyte) do { \
    gl_lds16((gp) + (kt) * 64 + so_src[0], lds + (ldsbyte) + so_ds[0]); \
    gl_lds16((gp) + (kt) * 64 + so_src[1], lds + (ldsbyte) + so_ds[1]); \
  } while (0)

  floatx4 acc[8][4] = {};

  // prologue: tile0 complete + tile1 lo halves  (12 ops)
  STG(gAlo, 0, 0);
  STG(gBlo, 0, 65536);
  STG(gAhi, 0, 16384);
  STG(gBhi, 0, 81920);
  STG(gAlo, 1, 32768);
  STG(gBlo, 1, 98304);
  asm volatile("s_waitcnt vmcnt(4)" ::: "memory");  // tile0 landed; t1 lo in flight
  BARRIER();

#define PHASE(AB, BB, MH, NH, STAGE_STMT, VMSTMT) do { \
    short8 af[4][2], bf[2][2]; \
    _Pragma("unroll") \
    for (int mi2 = 0; mi2 < 4; ++mi2) { \
      int row = wm * 64 + mi2 * 16 + cI; \
      const char* rp = lds + (AB) + (MH) * 16384 + row * 128; \
      int sw = row & 7; \
      _Pragma("unroll") \
      for (int kk = 0; kk < 2; ++kk) \
        af[mi2][kk] = *(const short8*)(rp + (((kk * 4 + rI) ^ sw) << 4)); \
    } \
    _Pragma("unroll") \
    for (int ni2 = 0; ni2 < 2; ++ni2) { \
      int row = wn * 32 + ni2 * 16 + cI; \
      const char* rp = lds + (BB) + (NH) * 16384 + row * 128; \
      int sw = row & 7; \
      _Pragma("unroll") \
      for (int kk = 0; kk < 2; ++kk) \
        bf[ni2][kk] = *(const short8*)(rp + (((kk * 4 + rI) ^ sw) << 4)); \
    } \
    STAGE_STMT; \
    VMSTMT; \
    BARRIER(); \
    __builtin_amdgcn_s_setprio(1); \
    _Pragma("unroll") \
    for (int mi2 = 0; mi2 < 4; ++mi2) \
      _Pragma("unroll") \
      for (int ni2 = 0; ni2 < 2; ++ni2) \
        _Pragma("unroll") \
        for (int kk = 0; kk < 2; ++kk) \
          acc[(MH) * 4 + mi2][(NH) * 2 + ni2] = __builtin_amdgcn_mfma_f32_16x16x32_bf16( \
              af[mi2][kk], bf[ni2][kk], acc[(MH) * 4 + mi2][(NH) * 2 + ni2], 0, 0, 0); \
    __builtin_amdgcn_s_setprio(0); \
    BARRIER(); \
  } while (0)

  for (int it = 0; it < 8; ++it) {
    const int u = 2 * it;
    const bool s2 = (u + 2 < 16), s3 = (u + 3 < 16);
    // phases 1-4: K-tile u (slot0: A@0, B@65536)
    PHASE(0, 65536, 0, 0, STG(gAhi, u + 1, 49152), );
    PHASE(0, 65536, 0, 1, STG(gBhi, u + 1, 114688), );
    PHASE(0, 65536, 1, 0, if (s2) STG(gAlo, u + 2, 0), );
    PHASE(0, 65536, 1, 1, if (s2) STG(gBlo, u + 2, 65536),
          if (s2) { asm volatile("s_waitcnt vmcnt(4)" ::: "memory"); }
          else    { asm volatile("s_waitcnt vmcnt(0)" ::: "memory"); });
    // phases 5-8: K-tile u+1 (slot1: A@32768, B@98304)
    PHASE(32768, 98304, 0, 0, if (s2) STG(gAhi, u + 2, 16384), );
    PHASE(32768, 98304, 0, 1, if (s2) STG(gBhi, u + 2, 81920), );
    PHASE(32768, 98304, 1, 0, if (s3) STG(gAlo, u + 3, 32768), );
    PHASE(32768, 98304, 1, 1, if (s3) STG(gBlo, u + 3, 98304),
          asm volatile("s_waitcnt vmcnt(4)" ::: "memory"));
  }

  // ---------------- epilogue ----------------
  if (EPI == 0) {
    const int t = (int)(bn0 >> 10);
    const int h = (int)(bn0 >> 8) & 3;
    const float* bias = (t == 0) ? bQ : (t == 1) ? bK : bV;
    const float sc = (t == 0) ? 0.0625f * 1.44269504088896f : 1.0f;
#pragma unroll
    for (int MH = 0; MH < 2; ++MH)
#pragma unroll
    for (int mi = 0; mi < 4; ++mi) {
      int m = (int)am0 + MH * 128 + wm * 64 + mi * 16 + rI * 4;
      int b = m >> 11, s = m & 2047;
#pragma unroll
      for (int NH = 0; NH < 2; ++NH)
#pragma unroll
      for (int ni = 0; ni < 2; ++ni) {
        int e = NH * 128 + wn * 32 + ni * 16 + cI;
        float bb = bias[h * 256 + e];
        floatx4 c = acc[MH * 4 + mi][NH * 2 + ni];
        if (t < 2) {
          u16* dst = (t == 0) ? Qo : Ko;
          long base = ((long)(b * 4 + h) * 2048 + s) * 256 + e;
          dst[base]       = f2bf((c[0] + bb) * sc);
          dst[base + 256] = f2bf((c[1] + bb) * sc);
          dst[base + 512] = f2bf((c[2] + bb) * sc);
          dst[base + 768] = f2bf((c[3] + bb) * sc);
        } else {
          long base = ((long)(b * 4 + h) * 256 + e) * 2048 + s;
          ushort4v v = { f2bf(c[0] + bb), f2bf(c[1] + bb), f2bf(c[2] + bb), f2bf(c[3] + bb) };
          *(ushort4v*)(Vt + base) = v;
        }
      }
    }
  } else {
#pragma unroll
    for (int MH = 0; MH < 2; ++MH)
#pragma unroll
    for (int mi = 0; mi < 4; ++mi) {
      int m = (int)am0 + MH * 128 + wm * 64 + mi * 16 + rI * 4;
#pragma unroll
      for (int NH = 0; NH < 2; ++NH)
#pragma unroll
      for (int ni = 0; ni < 2; ++ni) {
        int n = (int)bn0 + NH * 128 + wn * 32 + ni * 16 + cI;
        float bb = bO[n];
        floatx4 c = acc[MH * 4 + mi][NH * 2 + ni];
        out[(long)m * 1024 + n]       = c[0] + bb;
        out[(long)(m + 1) * 1024 + n] = c[1] + bb;
        out[(long)(m + 2) * 1024 + n] = c[2] + bb;
        out[(long)(m + 3) * 1024 + n] = c[3] + bb;
      }
    }
  }
#undef PHASE
#undef STG
}

// ---------------- flash attention v5: PV lagged one tile (unchanged) --------
__global__ __launch_bounds__(256, 2) void k_attn(
    const u16* __restrict__ Q, const u16* __restrict__ K,
    const u16* __restrict__ Vt, u16* __restrict__ Z) {
  extern __shared__ u16 smem[];
  u16* sK = smem;          // 2 x [32 k][256 e], 16B-chunk swizzled: C = g ^ (krow&7)
  u16* sV = smem + 16384;  // 2 x [256 e][32 k], 16B-chunk swizzled: C = g ^ ((e>>1)&3)
  const int tid = threadIdx.x, lane = tid & 63, w = tid >> 6;
  const int q = lane & 31, hi = lane >> 5;
  const int role = (blockIdx.x & 7) * 64 + (blockIdx.x >> 3);
  const int bh = role >> 4, qt = role & 15;
  const long base = (long)bh * 2048 * 256;
  const int q0 = qt * 128 + w * 32;

  int off_ds[4], ksrc[4], vsrc[4];
#pragma unroll
  for (int j = 0; j < 4; ++j) {
    int o = j * 4096 + tid * 16;
    off_ds[j] = o;
    int krow = o >> 9, kch = (o >> 4) & 31;
    ksrc[j] = krow * 256 + ((kch ^ (krow & 7)) << 3);
    int e = o >> 6, cr = (o >> 4) & 3;
    vsrc[j] = e * 2048 + ((cr ^ ((e >> 1) & 3)) << 3);
  }
  const u16* Kg0 = K + base;
  const u16* Vg  = Vt + base;  // [256][2048]

  short8 qf[16];
#pragma unroll
  for (int ec = 0; ec < 16; ++ec)
    qf[ec] = *(const short8*)(Q + base + (long)(q0 + q) * 256 + ec * 16 + hi * 8);

#define STAGE_K(kt_, buf_) do { \
    const u16* Kg_ = Kg0 + (kt_) * 8192; \
    u16* dK_ = sK + (buf_) * 8192; \
    _Pragma("unroll") \
    for (int j = 0; j < 4; ++j) gl_lds16(Kg_ + ksrc[j], (char*)dK_ + off_ds[j]); \
  } while (0)
#define STAGE_V(kt_, buf_) do { \
    const u16* Vg_ = Vg + (kt_) * 32; \
    u16* dV_ = sV + (buf_) * 8192; \
    _Pragma("unroll") \
    for (int j = 0; j < 4; ++j) gl_lds16(Vg_ + vsrc[j], (char*)dV_ + off_ds[j]); \
  } while (0)

  STAGE_K(0, 0);

  floatx16 z[8] = {};
  float m_run = -1e30f, l = 0.f;
  const int ksw = q & 7, vsw = (q >> 1) & 3;
  short8 pa0 = {}, pa1 = {};

  __syncthreads();

  for (int t = 0; t < 64; ++t) {
    const int cb = t & 1;
    if (t < 63) STAGE_K(t + 1, cb ^ 1);
    STAGE_V(t, cb);
    const char* pK = (const char*)(sK + cb * 8192);
    const char* pV = (const char*)(sV + (cb ^ 1) * 8192);

    floatx16 s = {};
    __builtin_amdgcn_s_setprio(1);
    if (t > 0) {
#pragma unroll
      for (int u = 0; u < 8; ++u) {
        short8 kf0 = *(const short8*)(pK + (q << 9) + ((((4 * u) | hi) ^ ksw) << 4));
        s = __builtin_amdgcn_mfma_f32_32x32x16_bf16(kf0, qf[2 * u], s, 0, 0, 0);
        short8 vf0 = *(const short8*)(pV + ((u * 32 + q) << 6) + (((hi ^ vsw) & 3) << 4));
        z[u] = __builtin_amdgcn_mfma_f32_32x32x16_bf16(pa0, vf0, z[u], 0, 0, 0);
        short8 kf1 = *(const short8*)(pK + (q << 9) + ((((4 * u + 2) | hi) ^ ksw) << 4));
        s = __builtin_amdgcn_mfma_f32_32x32x16_bf16(kf1, qf[2 * u + 1], s, 0, 0, 0);
        short8 vf1 = *(const short8*)(pV + ((u * 32 + q) << 6) + ((((2 | hi) ^ vsw) & 3) << 4));
        z[u] = __builtin_amdgcn_mfma_f32_32x32x16_bf16(pa1, vf1, z[u], 0, 0, 0);
      }
    } else {
#pragma unroll
      for (int ec = 0; ec < 16; ++ec) {
        short8 kf = *(const short8*)(pK + (q << 9) + ((((2 * ec) | hi) ^ ksw) << 4));
        s = __builtin_amdgcn_mfma_f32_32x32x16_bf16(kf, qf[ec], s, 0, 0, 0);
      }
    }
    __builtin_amdgcn_s_setprio(0);

    float m0 = fmaxf(s[0], s[1]),  m1 = fmaxf(s[2], s[3]);
    float m2 = fmaxf(s[4], s[5]),  m3 = fmaxf(s[6], s[7]);
    float m4 = fmaxf(s[8], s[9]),  m5 = fmaxf(s[10], s[11]);
    float m6 = fmaxf(s[12], s[13]), m7 = fmaxf(s[14], s[15]);
    m0 = fmaxf(m0, m1); m2 = fmaxf(m2, m3); m4 = fmaxf(m4, m5); m6 = fmaxf(m6, m7);
    m0 = fmaxf(m0, m2); m4 = fmaxf(m4, m6);
    float pm = fmaxf(m0, m4);
    {
      uint2v sw = __builtin_amdgcn_permlane32_swap(__float_as_uint(pm), __float_as_uint(pm), false, false);
      pm = fmaxf(__uint_as_float(sw[0]), __uint_as_float(sw[1]));
    }

    if (!__all(pm <= m_run + 8.f)) {
      float mn = fmaxf(m_run, pm);
      float esc = exp2f(m_run - mn);
      l *= esc;
      m_run = mn;
      float escv[16];
#pragma unroll
      for (int r = 0; r < 16; ++r)
        escv[r] = bpermf(esc, ((r & 3) + 8 * (r >> 2) + 4 * hi) + 32 * hi);
#pragma unroll
      for (int et = 0; et < 8; ++et)
#pragma unroll
        for (int r = 0; r < 16; ++r) z[et][r] *= escv[r];
    }

    float p[16], rs = 0.f;
#pragma unroll
    for (int r = 0; r < 16; ++r) { p[r] = exp2f(s[r] - m_run); rs += p[r]; }
    {
      uint2v sw = __builtin_amdgcn_permlane32_swap(__float_as_uint(rs), __float_as_uint(rs), false, false);
      l += __uint_as_float(sw[0]) + __uint_as_float(sw[1]);
    }

    unsigned w0, w1, w2, w3, w4, w5, w6, w7;
    asm("v_cvt_pk_bf16_f32 %0, %1, %2" : "=v"(w0) : "v"(p[0]), "v"(p[1]));
    asm("v_cvt_pk_bf16_f32 %0, %1, %2" : "=v"(w1) : "v"(p[2]), "v"(p[3]));
    asm("v_cvt_pk_bf16_f32 %0, %1, %2" : "=v"(w2) : "v"(p[4]), "v"(p[5]));
    asm("v_cvt_pk_bf16_f32 %0, %1, %2" : "=v"(w3) : "v"(p[6]), "v"(p[7]));
    asm("v_cvt_pk_bf16_f32 %0, %1, %2" : "=v"(w4) : "v"(p[8]), "v"(p[9]));
    asm("v_cvt_pk_bf16_f32 %0, %1, %2" : "=v"(w5) : "v"(p[10]), "v"(p[11]));
    asm("v_cvt_pk_bf16_f32 %0, %1, %2" : "=v"(w6) : "v"(p[12]), "v"(p[13]));
    asm("v_cvt_pk_bf16_f32 %0, %1, %2" : "=v"(w7) : "v"(p[14]), "v"(p[15]));
    uint2v e02 = __builtin_amdgcn_permlane32_swap(w0, w2, false, false);
    uint2v e13 = __builtin_amdgcn_permlane32_swap(w1, w3, false, false);
    uint2v e46 = __builtin_amdgcn_permlane32_swap(w4, w6, false, false);
    uint2v e57 = __builtin_amdgcn_permlane32_swap(w5, w7, false, false);
    int4 t0i = { (int)e02[0], (int)e13[0], (int)e02[1], (int)e13[1] };
    int4 t1i = { (int)e46[0], (int)e57[0], (int)e46[1], (int)e57[1] };
    pa0 = *(short8*)&t0i;
    pa1 = *(short8*)&t1i;

    __syncthreads();
  }

  {
    const char* pV = (const char*)(sV + 8192);
#pragma unroll
    for (int u = 0; u < 8; ++u) {
      short8 vf0 = *(const short8*)(pV + ((u * 32 + q) << 6) + (((hi ^ vsw) & 3) << 4));
      z[u] = __builtin_amdgcn_mfma_f32_32x32x16_bf16(pa0, vf0, z[u], 0, 0, 0);
      short8 vf1 = *(const short8*)(pV + ((u * 32 + q) << 6) + ((((2 | hi) ^ vsw) & 3) << 4));
      z[u] = __builtin_amdgcn_mfma_f32_32x32x16_bf16(pa1, vf1, z[u], 0, 0, 0);
    }
  }

  float linv = 1.f / l;
  float invv[16];
#pragma unroll
  for (int r = 0; r < 16; ++r)
    invv[r] = bpermf(linv, ((r & 3) + 8 * (r >> 2) + 4 * hi) + 32 * hi);

  const int b = bh >> 2, hh = bh & 3;
  const long zb = (long)b * 2048 * 1024 + hh * 256;
#pragma unroll
  for (int r = 0; r < 16; ++r) {
    const int qr = (r & 3) + 8 * (r >> 2) + 4 * hi;
    long rb = zb + (long)(q0 + qr) * 1024;
#pragma unroll
    for (int et = 0; et < 8; ++et)
      Z[rb + et * 32 + q] = f2bf(z[et][r] * invv[r]);
  }
#undef STAGE_K
#undef STAGE_V
}

// ---------------- launch ----------------

extern "C" void kernel_launch(void* const* d_in, const int* in_sizes, int n_in,
                              void* d_out, int out_size, void* d_ws, size_t ws_size,
                              hipStream_t stream) {
  const float* x  = (const float*)d_in[0];
  const float* WQ = (const float*)d_in[1];
  const float* bQ = (const float*)d_in[2];
  const float* WK = (const float*)d_in[3];
  const float* bK = (const float*)d_in[4];
  const float* WV = (const float*)d_in[5];
  const float* bV = (const float*)d_in[6];
  const float* WO = (const float*)d_in[7];
  const float* bO = (const float*)d_in[8];
  float* out = (float*)d_out;

  char* p = (char*)d_ws;
  u16* xb   = (u16*)p; p += (size_t)16384 * 1024 * 2;  // x bf16; reused later as Z
  u16* wqkv = (u16*)p; p += (size_t)3072 * 1024 * 2;
  u16* wo   = (u16*)p; p += (size_t)1024 * 1024 * 2;
  u16* Qb   = (u16*)p; p += (size_t)32 * 2048 * 256 * 2;
  u16* Kb   = (u16*)p; p += (size_t)32 * 2048 * 256 * 2;
  u16* Vtb  = (u16*)p; p += (size_t)32 * 256 * 2048 * 2;
  u16* Zb   = xb;  // alias: xb dead after k_gemm8<0>

  const int attn_lds = 65536;
  (void)hipFuncSetAttribute((const void*)k_attn,
                            hipFuncAttributeMaxDynamicSharedMemorySize, attn_lds);
  const int gemm_lds = 131072;
  (void)hipFuncSetAttribute((const void*)k_gemm8<0>,
                            hipFuncAttributeMaxDynamicSharedMemorySize, gemm_lds);
  (void)hipFuncSetAttribute((const void*)k_gemm8<1>,
                            hipFuncAttributeMaxDynamicSharedMemorySize, gemm_lds);

  k_cvt_x<<<dim3(4096), dim3(256), 0, stream>>>(x, xb, (long)16384 * 1024);
  k_cvt_w<<<dim3(1024), dim3(256), 0, stream>>>(WQ, WK, WV, WO, wqkv, wo);
  k_gemm8<0><<<dim3(768), dim3(512), gemm_lds, stream>>>(xb, wqkv, Qb, Kb, Vtb, bQ, bK, bV,
                                                         (float*)nullptr, (const float*)nullptr, 12);
  k_attn<<<dim3(512), dim3(256), attn_lds, stream>>>(Qb, Kb, Vtb, Zb);
  k_gemm8<1><<<dim3(256), dim3(512), gemm_lds, stream>>>(Zb, wo,
                                                         (u16*)nullptr, (u16*)nullptr, (u16*)nullptr,
                                                         (const float*)nullptr, (const float*)nullptr, (const float*)nullptr,
                                                         out, bO, 4);
}

// Round 8
// 325.319 us; speedup vs baseline: 2.3965x; 1.1068x over previous
//
#include <hip/hip_runtime.h>

typedef __attribute__((ext_vector_type(8))) short short8;
typedef __attribute__((ext_vector_type(4))) float floatx4;
typedef __attribute__((ext_vector_type(16))) float floatx16;
typedef __attribute__((ext_vector_type(4))) unsigned short ushort4v;
typedef __attribute__((ext_vector_type(2))) unsigned int uint2v;
typedef unsigned short u16;

__device__ __forceinline__ u16 f2bf(float f) {
  unsigned u = __float_as_uint(f);
  u += 0x7fffu + ((u >> 16) & 1u);
  return (u16)(u >> 16);
}

__device__ __forceinline__ void gl_lds16(const void* g, void* l) {
  __builtin_amdgcn_global_load_lds((const __attribute__((address_space(1))) void*)g,
                                   (__attribute__((address_space(3))) void*)l, 16, 0, 0);
}

__device__ __forceinline__ float bpermf(float v, int srclane) {
  return __int_as_float(__builtin_amdgcn_ds_bpermute(srclane << 2, __float_as_int(v)));
}

#define BARRIER() do { asm volatile("" ::: "memory"); __builtin_amdgcn_s_barrier(); asm volatile("" ::: "memory"); } while (0)

// ---------------- converts ----------------

__global__ void k_cvt_x(const float* __restrict__ x, u16* __restrict__ o, long n) {
  long i = ((long)blockIdx.x * blockDim.x + threadIdx.x) * 8;
  long stride = (long)gridDim.x * blockDim.x * 8;
  for (; i < n; i += stride) {
    float4 a = *(const float4*)(x + i);
    float4 b = *(const float4*)(x + i + 4);
    ushort4v r0 = { f2bf(a.x), f2bf(a.y), f2bf(a.z), f2bf(a.w) };
    ushort4v r1 = { f2bf(b.x), f2bf(b.y), f2bf(b.z), f2bf(b.w) };
    *(ushort4v*)(o + i) = r0;
    *(ushort4v*)(o + i + 4) = r1;
  }
}

// Tiled transpose (coalesced read + write)
__global__ __launch_bounds__(256) void k_cvt_w(
    const float* __restrict__ WQ, const float* __restrict__ WK,
    const float* __restrict__ WV, const float* __restrict__ WO,
    u16* __restrict__ wqkv, u16* __restrict__ wo) {
  __shared__ float tile[64][65];
  const int bid = blockIdx.x;
  const float* src;
  u16* dst;
  int C, R, r0, c0;
  if (bid < 768) {
    int th = bid >> 6;
    int tid6 = bid & 63;
    int t = th >> 2, h = th & 3;
    src = ((t == 0) ? WQ : (t == 1) ? WK : WV) + h * 1024 * 256;
    dst = wqkv + (size_t)(t * 1024 + h * 256) * 1024;
    R = 1024; C = 256;
    r0 = (tid6 & 15) * 64;
    c0 = (tid6 >> 4) * 64;
  } else {
    int tid6 = bid - 768;
    src = WO; dst = wo;
    R = 1024; C = 1024;
    r0 = (tid6 & 15) * 64;
    c0 = (tid6 >> 4) * 64;
  }
  const int tx = threadIdx.x & 15, ty = threadIdx.x >> 4;
#pragma unroll
  for (int i = 0; i < 4; ++i) {
    int r = ty + 16 * i;
    float4 v = *(const float4*)(src + (long)(r0 + r) * C + c0 + tx * 4);
    tile[r][tx * 4 + 0] = v.x;
    tile[r][tx * 4 + 1] = v.y;
    tile[r][tx * 4 + 2] = v.z;
    tile[r][tx * 4 + 3] = v.w;
  }
  __syncthreads();
#pragma unroll
  for (int i = 0; i < 4; ++i) {
    int c = ty + 16 * i;
    ushort4v o = { f2bf(tile[tx * 4 + 0][c]), f2bf(tile[tx * 4 + 1][c]),
                   f2bf(tile[tx * 4 + 2][c]), f2bf(tile[tx * 4 + 3][c]) };
    *(ushort4v*)(dst + (long)(c0 + c) * R + r0 + tx * 4) = o;
  }
}

// ---------------- 8-phase 256x256 GEMM (unchanged schedule; K/V epilogues
// now write attn's BLOCKED layouts):
//   K_blk[bh][kt=s>>5][c=e>>3][k=s&31][j=e&7]  u16 idx: bh<<19|kt<<13|c<<8|k<<3|j
//   V_blk[bh][kt=s>>5][kc=(s>>3)&3][e][jk=s&7] u16 idx: bh<<19|kt<<13|kc<<11|e<<3|jk
// Each 16KB tile is linear in HBM == the exact LDS image attn stages.
template<int EPI>
__global__ __launch_bounds__(512, 2) void k_gemm8(
    const u16* __restrict__ A, const u16* __restrict__ Bt,
    u16* __restrict__ Qo, u16* __restrict__ Ko, u16* __restrict__ Vt,
    const float* __restrict__ bQ, const float* __restrict__ bK, const float* __restrict__ bV,
    float* __restrict__ out, const float* __restrict__ bO, int gridNx) {
  extern __shared__ char lds[];
  const int tid = threadIdx.x, lane = tid & 63, w = tid >> 6;
  const int wm = w >> 2, wn = w & 3;
  const int cI = lane & 15, rI = lane >> 4;
  const int nwg = gridDim.x;
  const int bid = blockIdx.x;
  const int swz = (bid & 7) * (nwg >> 3) + (bid >> 3);  // XCD-grouped (nwg%8==0)
  const int by = swz / gridNx, bx = swz % gridNx;
  const long am0 = (long)by * 256, bn0 = (long)bx * 256;

  int so_ds[2], so_src[2];
#pragma unroll
  for (int jj = 0; jj < 2; ++jj) {
    int o = jj * 8192 + tid * 16;
    int row = o >> 7;
    so_ds[jj] = o;
    so_src[jj] = row * 1024 + ((((o >> 4) & 7) ^ (row & 7)) << 3);  // u16 units
  }
  const u16* gAlo = A + am0 * 1024;
  const u16* gAhi = gAlo + 128 * 1024;
  const u16* gBlo = Bt + bn0 * 1024;
  const u16* gBhi = gBlo + 128 * 1024;

#define STG(gp, kt, ldsbyte) do { \
    gl_lds16((gp) + (kt) * 64 + so_src[0], lds + (ldsbyte) + so_ds[0]); \
    gl_lds16((gp) + (kt) * 64 + so_src[1], lds + (ldsbyte) + so_ds[1]); \
  } while (0)

  floatx4 acc[8][4] = {};

  STG(gAlo, 0, 0);
  STG(gBlo, 0, 65536);
  STG(gAhi, 0, 16384);
  STG(gBhi, 0, 81920);
  STG(gAlo, 1, 32768);
  STG(gBlo, 1, 98304);
  asm volatile("s_waitcnt vmcnt(4)" ::: "memory");
  BARRIER();

#define PHASE(AB, BB, MH, NH, STAGE_STMT, VMSTMT) do { \
    short8 af[4][2], bf[2][2]; \
    _Pragma("unroll") \
    for (int mi2 = 0; mi2 < 4; ++mi2) { \
      int row = wm * 64 + mi2 * 16 + cI; \
      const char* rp = lds + (AB) + (MH) * 16384 + row * 128; \
      int sw = row & 7; \
      _Pragma("unroll") \
      for (int kk = 0; kk < 2; ++kk) \
        af[mi2][kk] = *(const short8*)(rp + (((kk * 4 + rI) ^ sw) << 4)); \
    } \
    _Pragma("unroll") \
    for (int ni2 = 0; ni2 < 2; ++ni2) { \
      int row = wn * 32 + ni2 * 16 + cI; \
      const char* rp = lds + (BB) + (NH) * 16384 + row * 128; \
      int sw = row & 7; \
      _Pragma("unroll") \
      for (int kk = 0; kk < 2; ++kk) \
        bf[ni2][kk] = *(const short8*)(rp + (((kk * 4 + rI) ^ sw) << 4)); \
    } \
    STAGE_STMT; \
    VMSTMT; \
    BARRIER(); \
    __builtin_amdgcn_s_setprio(1); \
    _Pragma("unroll") \
    for (int mi2 = 0; mi2 < 4; ++mi2) \
      _Pragma("unroll") \
      for (int ni2 = 0; ni2 < 2; ++ni2) \
        _Pragma("unroll") \
        for (int kk = 0; kk < 2; ++kk) \
          acc[(MH) * 4 + mi2][(NH) * 2 + ni2] = __builtin_amdgcn_mfma_f32_16x16x32_bf16( \
              af[mi2][kk], bf[ni2][kk], acc[(MH) * 4 + mi2][(NH) * 2 + ni2], 0, 0, 0); \
    __builtin_amdgcn_s_setprio(0); \
    BARRIER(); \
  } while (0)

  for (int it = 0; it < 8; ++it) {
    const int u = 2 * it;
    const bool s2 = (u + 2 < 16), s3 = (u + 3 < 16);
    PHASE(0, 65536, 0, 0, STG(gAhi, u + 1, 49152), );
    PHASE(0, 65536, 0, 1, STG(gBhi, u + 1, 114688), );
    PHASE(0, 65536, 1, 0, if (s2) STG(gAlo, u + 2, 0), );
    PHASE(0, 65536, 1, 1, if (s2) STG(gBlo, u + 2, 65536),
          if (s2) { asm volatile("s_waitcnt vmcnt(4)" ::: "memory"); }
          else    { asm volatile("s_waitcnt vmcnt(0)" ::: "memory"); });
    PHASE(32768, 98304, 0, 0, if (s2) STG(gAhi, u + 2, 16384), );
    PHASE(32768, 98304, 0, 1, if (s2) STG(gBhi, u + 2, 81920), );
    PHASE(32768, 98304, 1, 0, if (s3) STG(gAlo, u + 3, 32768), );
    PHASE(32768, 98304, 1, 1, if (s3) STG(gBlo, u + 3, 98304),
          asm volatile("s_waitcnt vmcnt(4)" ::: "memory"));
  }

  // ---------------- epilogue ----------------
  if (EPI == 0) {
    const int t = (int)(bn0 >> 10);
    const int h = (int)(bn0 >> 8) & 3;
    const float* bias = (t == 0) ? bQ : (t == 1) ? bK : bV;
    const float sc = (t == 0) ? 0.0625f * 1.44269504088896f : 1.0f;
#pragma unroll
    for (int MH = 0; MH < 2; ++MH)
#pragma unroll
    for (int mi = 0; mi < 4; ++mi) {
      int m = (int)am0 + MH * 128 + wm * 64 + mi * 16 + rI * 4;
      int b = m >> 11, s = m & 2047;
#pragma unroll
      for (int NH = 0; NH < 2; ++NH)
#pragma unroll
      for (int ni = 0; ni < 2; ++ni) {
        int e = NH * 128 + wn * 32 + ni * 16 + cI;
        float bb = bias[h * 256 + e];
        floatx4 c = acc[MH * 4 + mi][NH * 2 + ni];
        if (t == 0) {
          long base = ((long)(b * 4 + h) * 2048 + s) * 256 + e;
          Qo[base]       = f2bf((c[0] + bb) * sc);
          Qo[base + 256] = f2bf((c[1] + bb) * sc);
          Qo[base + 512] = f2bf((c[2] + bb) * sc);
          Qo[base + 768] = f2bf((c[3] + bb) * sc);
        } else if (t == 1) {
          // blocked K: bh<<19 | (s>>5)<<13 | (e>>3)<<8 | (s&31)<<3 | (e&7); rows r at +8r
          long kb = ((long)(b * 4 + h) << 19) + ((long)(s >> 5) << 13) +
                    ((e >> 3) << 8) + ((s & 31) << 3) + (e & 7);
          Ko[kb]      = f2bf(c[0] + bb);
          Ko[kb + 8]  = f2bf(c[1] + bb);
          Ko[kb + 16] = f2bf(c[2] + bb);
          Ko[kb + 24] = f2bf(c[3] + bb);
        } else {
          // blocked V: bh<<19 | (s>>5)<<13 | ((s>>3)&3)<<11 | e<<3 | (s&7); rows r consecutive
          long vb = ((long)(b * 4 + h) << 19) + ((long)(s >> 5) << 13) +
                    (((s >> 3) & 3) << 11) + ((long)e << 3) + (s & 7);
          ushort4v v = { f2bf(c[0] + bb), f2bf(c[1] + bb), f2bf(c[2] + bb), f2bf(c[3] + bb) };
          *(ushort4v*)(Vt + vb) = v;
        }
      }
    }
  } else {
#pragma unroll
    for (int MH = 0; MH < 2; ++MH)
#pragma unroll
    for (int mi = 0; mi < 4; ++mi) {
      int m = (int)am0 + MH * 128 + wm * 64 + mi * 16 + rI * 4;
#pragma unroll
      for (int NH = 0; NH < 2; ++NH)
#pragma unroll
      for (int ni = 0; ni < 2; ++ni) {
        int n = (int)bn0 + NH * 128 + wn * 32 + ni * 16 + cI;
        float bb = bO[n];
        floatx4 c = acc[MH * 4 + mi][NH * 2 + ni];
        out[(long)m * 1024 + n]       = c[0] + bb;
        out[(long)(m + 1) * 1024 + n] = c[1] + bb;
        out[(long)(m + 2) * 1024 + n] = c[2] + bb;
        out[(long)(m + 3) * 1024 + n] = c[3] + bb;
      }
    }
  }
#undef PHASE
#undef STG
}

// ---------------- flash attention v6: blocked K/V, imm-offset LDS reads ------
// K/V arrive in HBM pre-blocked as 16KB LDS-image tiles -> staging is a pure
// linear copy (coalesced), frag reads are one base + immediate offset, and the
// layout is bank-conflict-free by construction (no swizzle math anywhere).
__global__ __launch_bounds__(256, 2) void k_attn(
    const u16* __restrict__ Q, const u16* __restrict__ K,
    const u16* __restrict__ Vt, u16* __restrict__ Z) {
  extern __shared__ u16 smem[];
  char* sKc = (char*)smem;            // 2 x 16KB K tiles
  char* sVc = (char*)smem + 32768;    // 2 x 16KB V tiles
  const int tid = threadIdx.x, lane = tid & 63, w = tid >> 6;
  const int q = lane & 31, hi = lane >> 5;
  const int role = (blockIdx.x & 7) * 64 + (blockIdx.x >> 3);  // XCD-grouped, bijective
  const int bh = role >> 4, qt = role & 15;
  const long base = (long)bh * 2048 * 256;
  const int q0 = qt * 128 + w * 32;

  const u16* Kg0 = K + base;   // blocked tiles: kt*8192 u16 each
  const u16* Vg0 = Vt + base;
  const int stq = tid * 8;     // staging source (u16) within tile
  const int dtq = tid * 16;    // staging dest (bytes) within tile

  // Q fragments (scale*log2e pre-folded): lane holds Q[q0+q][ec*16+hi*8 ..]
  short8 qf[16];
#pragma unroll
  for (int ec = 0; ec < 16; ++ec)
    qf[ec] = *(const short8*)(Q + base + (long)(q0 + q) * 256 + ec * 16 + hi * 8);

#define STAGE_K(kt_, buf_) do { \
    const u16* g_ = Kg0 + (kt_) * 8192 + stq; \
    char* d_ = sKc + (buf_) * 16384 + dtq; \
    _Pragma("unroll") \
    for (int j = 0; j < 4; ++j) gl_lds16(g_ + j * 2048, d_ + j * 4096); \
  } while (0)
#define STAGE_V(kt_, buf_) do { \
    const u16* g_ = Vg0 + (kt_) * 8192 + stq; \
    char* d_ = sVc + (buf_) * 16384 + dtq; \
    _Pragma("unroll") \
    for (int j = 0; j < 4; ++j) gl_lds16(g_ + j * 2048, d_ + j * 4096); \
  } while (0)

  STAGE_K(0, 0);

  floatx16 z[8] = {};  // Z[q'][e=et*32+q], q' = (r&3)+8*(r>>2)+4*hi
  float m_run = -1e30f, l = 0.f;
  const int kb = hi * 512 + q * 16;    // K frag base (bytes in tile)
  const int vb = hi * 4096 + q * 16;   // V frag base (bytes in tile)
  short8 pa0 = {}, pa1 = {};           // packed P of tile t-1

  __syncthreads();

  for (int t = 0; t < 64; ++t) {
    const int cb = t & 1;
    if (t < 63) STAGE_K(t + 1, cb ^ 1);
    STAGE_V(t, cb);
    const char* pK = sKc + cb * 16384 + kb;          // K(t)
    const char* pV = sVc + (cb ^ 1) * 16384 + vb;    // V(t-1)

    // QK(t) serial chain interleaved with PV(t-1); all reads base+imm offset
    floatx16 s = {};
    __builtin_amdgcn_s_setprio(1);
    if (t > 0) {
#pragma unroll
      for (int u = 0; u < 8; ++u) {
        short8 kf0 = *(const short8*)(pK + (2 * u) * 1024);
        s = __builtin_amdgcn_mfma_f32_32x32x16_bf16(kf0, qf[2 * u], s, 0, 0, 0);
        short8 vf0 = *(const short8*)(pV + u * 512);
        z[u] = __builtin_amdgcn_mfma_f32_32x32x16_bf16(pa0, vf0, z[u], 0, 0, 0);
        short8 kf1 = *(const short8*)(pK + (2 * u + 1) * 1024);
        s = __builtin_amdgcn_mfma_f32_32x32x16_bf16(kf1, qf[2 * u + 1], s, 0, 0, 0);
        short8 vf1 = *(const short8*)(pV + 8192 + u * 512);
        z[u] = __builtin_amdgcn_mfma_f32_32x32x16_bf16(pa1, vf1, z[u], 0, 0, 0);
      }
    } else {
#pragma unroll
      for (int ec = 0; ec < 16; ++ec) {
        short8 kf = *(const short8*)(pK + ec * 1024);
        s = __builtin_amdgcn_mfma_f32_32x32x16_bf16(kf, qf[ec], s, 0, 0, 0);
      }
    }
    __builtin_amdgcn_s_setprio(0);

    // softmax(t): tree max + cross-half (permlane, pure VALU)
    float m0 = fmaxf(s[0], s[1]),  m1 = fmaxf(s[2], s[3]);
    float m2 = fmaxf(s[4], s[5]),  m3 = fmaxf(s[6], s[7]);
    float m4 = fmaxf(s[8], s[9]),  m5 = fmaxf(s[10], s[11]);
    float m6 = fmaxf(s[12], s[13]), m7 = fmaxf(s[14], s[15]);
    m0 = fmaxf(m0, m1); m2 = fmaxf(m2, m3); m4 = fmaxf(m4, m5); m6 = fmaxf(m6, m7);
    m0 = fmaxf(m0, m2); m4 = fmaxf(m4, m6);
    float pm = fmaxf(m0, m4);
    {
      uint2v sw = __builtin_amdgcn_permlane32_swap(__float_as_uint(pm), __float_as_uint(pm), false, false);
      pm = fmaxf(__uint_as_float(sw[0]), __uint_as_float(sw[1]));
    }

    if (!__all(pm <= m_run + 8.f)) {  // defer-max
      float mn = fmaxf(m_run, pm);
      float esc = exp2f(m_run - mn);
      l *= esc;
      m_run = mn;
      float escv[16];
#pragma unroll
      for (int r = 0; r < 16; ++r)
        escv[r] = bpermf(esc, ((r & 3) + 8 * (r >> 2) + 4 * hi) + 32 * hi);
#pragma unroll
      for (int et = 0; et < 8; ++et)
#pragma unroll
        for (int r = 0; r < 16; ++r) z[et][r] *= escv[r];
    }

    float p[16], rs = 0.f;
#pragma unroll
    for (int r = 0; r < 16; ++r) { p[r] = exp2f(s[r] - m_run); rs += p[r]; }
    {
      uint2v sw = __builtin_amdgcn_permlane32_swap(__float_as_uint(rs), __float_as_uint(rs), false, false);
      l += __uint_as_float(sw[0]) + __uint_as_float(sw[1]);
    }

    // pack P(t) -> pa0/pa1 (consumed next iter / epilogue)
    unsigned w0, w1, w2, w3, w4, w5, w6, w7;
    asm("v_cvt_pk_bf16_f32 %0, %1, %2" : "=v"(w0) : "v"(p[0]), "v"(p[1]));
    asm("v_cvt_pk_bf16_f32 %0, %1, %2" : "=v"(w1) : "v"(p[2]), "v"(p[3]));
    asm("v_cvt_pk_bf16_f32 %0, %1, %2" : "=v"(w2) : "v"(p[4]), "v"(p[5]));
    asm("v_cvt_pk_bf16_f32 %0, %1, %2" : "=v"(w3) : "v"(p[6]), "v"(p[7]));
    asm("v_cvt_pk_bf16_f32 %0, %1, %2" : "=v"(w4) : "v"(p[8]), "v"(p[9]));
    asm("v_cvt_pk_bf16_f32 %0, %1, %2" : "=v"(w5) : "v"(p[10]), "v"(p[11]));
    asm("v_cvt_pk_bf16_f32 %0, %1, %2" : "=v"(w6) : "v"(p[12]), "v"(p[13]));
    asm("v_cvt_pk_bf16_f32 %0, %1, %2" : "=v"(w7) : "v"(p[14]), "v"(p[15]));
    uint2v e02 = __builtin_amdgcn_permlane32_swap(w0, w2, false, false);
    uint2v e13 = __builtin_amdgcn_permlane32_swap(w1, w3, false, false);
    uint2v e46 = __builtin_amdgcn_permlane32_swap(w4, w6, false, false);
    uint2v e57 = __builtin_amdgcn_permlane32_swap(w5, w7, false, false);
    int4 t0i = { (int)e02[0], (int)e13[0], (int)e02[1], (int)e13[1] };
    int4 t1i = { (int)e46[0], (int)e57[0], (int)e46[1], (int)e57[1] };
    pa0 = *(short8*)&t0i;
    pa1 = *(short8*)&t1i;

    __syncthreads();  // drains staged loads (all waves) + guards buffer swap
  }

  // epilogue: PV(63) from V buf1 (t=63 staged into cb=1)
  {
    const char* pV = sVc + 16384 + vb;
#pragma unroll
    for (int u = 0; u < 8; ++u) {
      short8 vf0 = *(const short8*)(pV + u * 512);
      z[u] = __builtin_amdgcn_mfma_f32_32x32x16_bf16(pa0, vf0, z[u], 0, 0, 0);
      short8 vf1 = *(const short8*)(pV + 8192 + u * 512);
      z[u] = __builtin_amdgcn_mfma_f32_32x32x16_bf16(pa1, vf1, z[u], 0, 0, 0);
    }
  }

  float linv = 1.f / l;
  float invv[16];
#pragma unroll
  for (int r = 0; r < 16; ++r)
    invv[r] = bpermf(linv, ((r & 3) + 8 * (r >> 2) + 4 * hi) + 32 * hi);

  const int b = bh >> 2, hh = bh & 3;
  const long zb = (long)b * 2048 * 1024 + hh * 256;
#pragma unroll
  for (int r = 0; r < 16; ++r) {
    const int qr = (r & 3) + 8 * (r >> 2) + 4 * hi;
    long rb = zb + (long)(q0 + qr) * 1024;
#pragma unroll
    for (int et = 0; et < 8; ++et)
      Z[rb + et * 32 + q] = f2bf(z[et][r] * invv[r]);
  }
#undef STAGE_K
#undef STAGE_V
}

// ---------------- launch ----------------

extern "C" void kernel_launch(void* const* d_in, const int* in_sizes, int n_in,
                              void* d_out, int out_size, void* d_ws, size_t ws_size,
                              hipStream_t stream) {
  const float* x  = (const float*)d_in[0];
  const float* WQ = (const float*)d_in[1];
  const float* bQ = (const float*)d_in[2];
  const float* WK = (const float*)d_in[3];
  const float* bK = (const float*)d_in[4];
  const float* WV = (const float*)d_in[5];
  const float* bV = (const float*)d_in[6];
  const float* WO = (const float*)d_in[7];
  const float* bO = (const float*)d_in[8];
  float* out = (float*)d_out;

  char* p = (char*)d_ws;
  u16* xb   = (u16*)p; p += (size_t)16384 * 1024 * 2;  // x bf16; reused later as Z
  u16* wqkv = (u16*)p; p += (size_t)3072 * 1024 * 2;
  u16* wo   = (u16*)p; p += (size_t)1024 * 1024 * 2;
  u16* Qb   = (u16*)p; p += (size_t)32 * 2048 * 256 * 2;
  u16* Kb   = (u16*)p; p += (size_t)32 * 2048 * 256 * 2;  // blocked K
  u16* Vtb  = (u16*)p; p += (size_t)32 * 256 * 2048 * 2;  // blocked V
  u16* Zb   = xb;  // alias: xb dead after k_gemm8<0>

  const int attn_lds = 65536;
  (void)hipFuncSetAttribute((const void*)k_attn,
                            hipFuncAttributeMaxDynamicSharedMemorySize, attn_lds);
  const int gemm_lds = 131072;
  (void)hipFuncSetAttribute((const void*)k_gemm8<0>,
                            hipFuncAttributeMaxDynamicSharedMemorySize, gemm_lds);
  (void)hipFuncSetAttribute((const void*)k_gemm8<1>,
                            hipFuncAttributeMaxDynamicSharedMemorySize, gemm_lds);

  k_cvt_x<<<dim3(4096), dim3(256), 0, stream>>>(x, xb, (long)16384 * 1024);
  k_cvt_w<<<dim3(1024), dim3(256), 0, stream>>>(WQ, WK, WV, WO, wqkv, wo);
  k_gemm8<0><<<dim3(768), dim3(512), gemm_lds, stream>>>(xb, wqkv, Qb, Kb, Vtb, bQ, bK, bV,
                                                         (float*)nullptr, (const float*)nullptr, 12);
  k_attn<<<dim3(512), dim3(256), attn_lds, stream>>>(Qb, Kb, Vtb, Zb);
  k_gemm8<1><<<dim3(256), dim3(512), gemm_lds, stream>>>(Zb, wo,
                                                         (u16*)nullptr, (u16*)nullptr, (u16*)nullptr,
                                                         (const float*)nullptr, (const float*)nullptr, (const float*)nullptr,
                                                         out, bO, 4);
}

// Round 9
// 324.605 us; speedup vs baseline: 2.4017x; 1.0022x over previous
//
#include <hip/hip_runtime.h>

typedef __attribute__((ext_vector_type(8))) short short8;
typedef __attribute__((ext_vector_type(4))) float floatx4;
typedef __attribute__((ext_vector_type(16))) float floatx16;
typedef __attribute__((ext_vector_type(4))) unsigned short ushort4v;
typedef __attribute__((ext_vector_type(2))) unsigned int uint2v;
typedef unsigned short u16;

__device__ __forceinline__ u16 f2bf(float f) {
  unsigned u = __float_as_uint(f);
  u += 0x7fffu + ((u >> 16) & 1u);
  return (u16)(u >> 16);
}

__device__ __forceinline__ void gl_lds16(const void* g, void* l) {
  __builtin_amdgcn_global_load_lds((const __attribute__((address_space(1))) void*)g,
                                   (__attribute__((address_space(3))) void*)l, 16, 0, 0);
}

__device__ __forceinline__ float bpermf(float v, int srclane) {
  return __int_as_float(__builtin_amdgcn_ds_bpermute(srclane << 2, __float_as_int(v)));
}

#define BARRIER() do { asm volatile("" ::: "memory"); __builtin_amdgcn_s_barrier(); asm volatile("" ::: "memory"); } while (0)

// ---------------- converts ----------------

__global__ void k_cvt_x(const float* __restrict__ x, u16* __restrict__ o, long n) {
  long i = ((long)blockIdx.x * blockDim.x + threadIdx.x) * 8;
  long stride = (long)gridDim.x * blockDim.x * 8;
  for (; i < n; i += stride) {
    float4 a = *(const float4*)(x + i);
    float4 b = *(const float4*)(x + i + 4);
    ushort4v r0 = { f2bf(a.x), f2bf(a.y), f2bf(a.z), f2bf(a.w) };
    ushort4v r1 = { f2bf(b.x), f2bf(b.y), f2bf(b.z), f2bf(b.w) };
    *(ushort4v*)(o + i) = r0;
    *(ushort4v*)(o + i + 4) = r1;
  }
}

// Tiled transpose (coalesced read + write)
__global__ __launch_bounds__(256) void k_cvt_w(
    const float* __restrict__ WQ, const float* __restrict__ WK,
    const float* __restrict__ WV, const float* __restrict__ WO,
    u16* __restrict__ wqkv, u16* __restrict__ wo) {
  __shared__ float tile[64][65];
  const int bid = blockIdx.x;
  const float* src;
  u16* dst;
  int C, R, r0, c0;
  if (bid < 768) {
    int th = bid >> 6;
    int tid6 = bid & 63;
    int t = th >> 2, h = th & 3;
    src = ((t == 0) ? WQ : (t == 1) ? WK : WV) + h * 1024 * 256;
    dst = wqkv + (size_t)(t * 1024 + h * 256) * 1024;
    R = 1024; C = 256;
    r0 = (tid6 & 15) * 64;
    c0 = (tid6 >> 4) * 64;
  } else {
    int tid6 = bid - 768;
    src = WO; dst = wo;
    R = 1024; C = 1024;
    r0 = (tid6 & 15) * 64;
    c0 = (tid6 >> 4) * 64;
  }
  const int tx = threadIdx.x & 15, ty = threadIdx.x >> 4;
#pragma unroll
  for (int i = 0; i < 4; ++i) {
    int r = ty + 16 * i;
    float4 v = *(const float4*)(src + (long)(r0 + r) * C + c0 + tx * 4);
    tile[r][tx * 4 + 0] = v.x;
    tile[r][tx * 4 + 1] = v.y;
    tile[r][tx * 4 + 2] = v.z;
    tile[r][tx * 4 + 3] = v.w;
  }
  __syncthreads();
#pragma unroll
  for (int i = 0; i < 4; ++i) {
    int c = ty + 16 * i;
    ushort4v o = { f2bf(tile[tx * 4 + 0][c]), f2bf(tile[tx * 4 + 1][c]),
                   f2bf(tile[tx * 4 + 2][c]), f2bf(tile[tx * 4 + 3][c]) };
    *(ushort4v*)(dst + (long)(c0 + c) * R + r0 + tx * 4) = o;
  }
}

// ---------------- 8-phase 256x256 GEMM ----------------
// Within-XCD by-fastest grouping: resident set = 8 A-panels (4MB, L2-resident)
// x 4 B-panels (streamed once) -> less L3->L2 refetch than bx-fast order.
template<int EPI>
__global__ __launch_bounds__(512, 2) void k_gemm8(
    const u16* __restrict__ A, const u16* __restrict__ Bt,
    u16* __restrict__ Qo, u16* __restrict__ Ko, u16* __restrict__ Vt,
    const float* __restrict__ bQ, const float* __restrict__ bK, const float* __restrict__ bV,
    float* __restrict__ out, const float* __restrict__ bO, int gridNx) {
  extern __shared__ char lds[];
  const int tid = threadIdx.x, lane = tid & 63, w = tid >> 6;
  const int wm = w >> 2, wn = w & 3;
  const int cI = lane & 15, rI = lane >> 4;
  const int bid = blockIdx.x;
  const int xcd = bid & 7, ii = bid >> 3;
  const int by = xcd * 8 + (ii & 7);   // M/256 = 64 = 8 XCD x 8
  const int bx = ii >> 3;              // 0..gridNx-1
  (void)gridNx;
  const long am0 = (long)by * 256, bn0 = (long)bx * 256;

  int so_ds[2], so_src[2];
#pragma unroll
  for (int jj = 0; jj < 2; ++jj) {
    int o = jj * 8192 + tid * 16;
    int row = o >> 7;
    so_ds[jj] = o;
    so_src[jj] = row * 1024 + ((((o >> 4) & 7) ^ (row & 7)) << 3);  // u16 units
  }
  const u16* gAlo = A + am0 * 1024;
  const u16* gAhi = gAlo + 128 * 1024;
  const u16* gBlo = Bt + bn0 * 1024;
  const u16* gBhi = gBlo + 128 * 1024;

#define STG(gp, kt, ldsbyte) do { \
    gl_lds16((gp) + (kt) * 64 + so_src[0], lds + (ldsbyte) + so_ds[0]); \
    gl_lds16((gp) + (kt) * 64 + so_src[1], lds + (ldsbyte) + so_ds[1]); \
  } while (0)

  floatx4 acc[8][4] = {};

  STG(gAlo, 0, 0);
  STG(gBlo, 0, 65536);
  STG(gAhi, 0, 16384);
  STG(gBhi, 0, 81920);
  STG(gAlo, 1, 32768);
  STG(gBlo, 1, 98304);
  asm volatile("s_waitcnt vmcnt(4)" ::: "memory");
  BARRIER();

#define PHASE(AB, BB, MH, NH, STAGE_STMT, VMSTMT) do { \
    short8 af[4][2], bf[2][2]; \
    _Pragma("unroll") \
    for (int mi2 = 0; mi2 < 4; ++mi2) { \
      int row = wm * 64 + mi2 * 16 + cI; \
      const char* rp = lds + (AB) + (MH) * 16384 + row * 128; \
      int sw = row & 7; \
      _Pragma("unroll") \
      for (int kk = 0; kk < 2; ++kk) \
        af[mi2][kk] = *(const short8*)(rp + (((kk * 4 + rI) ^ sw) << 4)); \
    } \
    _Pragma("unroll") \
    for (int ni2 = 0; ni2 < 2; ++ni2) { \
      int row = wn * 32 + ni2 * 16 + cI; \
      const char* rp = lds + (BB) + (NH) * 16384 + row * 128; \
      int sw = row & 7; \
      _Pragma("unroll") \
      for (int kk = 0; kk < 2; ++kk) \
        bf[ni2][kk] = *(const short8*)(rp + (((kk * 4 + rI) ^ sw) << 4)); \
    } \
    STAGE_STMT; \
    VMSTMT; \
    BARRIER(); \
    __builtin_amdgcn_s_setprio(1); \
    _Pragma("unroll") \
    for (int mi2 = 0; mi2 < 4; ++mi2) \
      _Pragma("unroll") \
      for (int ni2 = 0; ni2 < 2; ++ni2) \
        _Pragma("unroll") \
        for (int kk = 0; kk < 2; ++kk) \
          acc[(MH) * 4 + mi2][(NH) * 2 + ni2] = __builtin_amdgcn_mfma_f32_16x16x32_bf16( \
              af[mi2][kk], bf[ni2][kk], acc[(MH) * 4 + mi2][(NH) * 2 + ni2], 0, 0, 0); \
    __builtin_amdgcn_s_setprio(0); \
    BARRIER(); \
  } while (0)

  for (int it = 0; it < 8; ++it) {
    const int u = 2 * it;
    const bool s2 = (u + 2 < 16), s3 = (u + 3 < 16);
    PHASE(0, 65536, 0, 0, STG(gAhi, u + 1, 49152), );
    PHASE(0, 65536, 0, 1, STG(gBhi, u + 1, 114688), );
    PHASE(0, 65536, 1, 0, if (s2) STG(gAlo, u + 2, 0), );
    PHASE(0, 65536, 1, 1, if (s2) STG(gBlo, u + 2, 65536),
          if (s2) { asm volatile("s_waitcnt vmcnt(4)" ::: "memory"); }
          else    { asm volatile("s_waitcnt vmcnt(0)" ::: "memory"); });
    PHASE(32768, 98304, 0, 0, if (s2) STG(gAhi, u + 2, 16384), );
    PHASE(32768, 98304, 0, 1, if (s2) STG(gBhi, u + 2, 81920), );
    PHASE(32768, 98304, 1, 0, if (s3) STG(gAlo, u + 3, 32768), );
    PHASE(32768, 98304, 1, 1, if (s3) STG(gBlo, u + 3, 98304),
          asm volatile("s_waitcnt vmcnt(4)" ::: "memory"));
  }

  // ---------------- epilogue ----------------
  if (EPI == 0) {
    const int t = (int)(bn0 >> 10);
    const int h = (int)(bn0 >> 8) & 3;
    const float* bias = (t == 0) ? bQ : (t == 1) ? bK : bV;
    const float sc = (t == 0) ? 0.0625f * 1.44269504088896f : 1.0f;
#pragma unroll
    for (int MH = 0; MH < 2; ++MH)
#pragma unroll
    for (int mi = 0; mi < 4; ++mi) {
      int m = (int)am0 + MH * 128 + wm * 64 + mi * 16 + rI * 4;
      int b = m >> 11, s = m & 2047;
#pragma unroll
      for (int NH = 0; NH < 2; ++NH)
#pragma unroll
      for (int ni = 0; ni < 2; ++ni) {
        int e = NH * 128 + wn * 32 + ni * 16 + cI;
        float bb = bias[h * 256 + e];
        floatx4 c = acc[MH * 4 + mi][NH * 2 + ni];
        if (t == 0) {
          long base = ((long)(b * 4 + h) * 2048 + s) * 256 + e;
          Qo[base]       = f2bf((c[0] + bb) * sc);
          Qo[base + 256] = f2bf((c[1] + bb) * sc);
          Qo[base + 512] = f2bf((c[2] + bb) * sc);
          Qo[base + 768] = f2bf((c[3] + bb) * sc);
        } else if (t == 1) {
          long kb = ((long)(b * 4 + h) << 19) + ((long)(s >> 5) << 13) +
                    ((e >> 3) << 8) + ((s & 31) << 3) + (e & 7);
          Ko[kb]      = f2bf(c[0] + bb);
          Ko[kb + 8]  = f2bf(c[1] + bb);
          Ko[kb + 16] = f2bf(c[2] + bb);
          Ko[kb + 24] = f2bf(c[3] + bb);
        } else {
          long vb = ((long)(b * 4 + h) << 19) + ((long)(s >> 5) << 13) +
                    (((s >> 3) & 3) << 11) + ((long)e << 3) + (s & 7);
          ushort4v v = { f2bf(c[0] + bb), f2bf(c[1] + bb), f2bf(c[2] + bb), f2bf(c[3] + bb) };
          *(ushort4v*)(Vt + vb) = v;
        }
      }
    }
  } else {
#pragma unroll
    for (int MH = 0; MH < 2; ++MH)
#pragma unroll
    for (int mi = 0; mi < 4; ++mi) {
      int m = (int)am0 + MH * 128 + wm * 64 + mi * 16 + rI * 4;
#pragma unroll
      for (int NH = 0; NH < 2; ++NH)
#pragma unroll
      for (int ni = 0; ni < 2; ++ni) {
        int n = (int)bn0 + NH * 128 + wn * 32 + ni * 16 + cI;
        float bb = bO[n];
        floatx4 c = acc[MH * 4 + mi][NH * 2 + ni];
        out[(long)m * 1024 + n]       = c[0] + bb;
        out[(long)(m + 1) * 1024 + n] = c[1] + bb;
        out[(long)(m + 2) * 1024 + n] = c[2] + bb;
        out[(long)(m + 3) * 1024 + n] = c[3] + bb;
      }
    }
  }
#undef PHASE
#undef STG
}

// ---------------- flash attention v7: merged 8-wave block ----------------
// One 512-thr block per CU owns 256 q-rows and ONE shared K/V staging
// (halves LDS writes + K/V fetch vs two 4-wave blocks). Split QK s-chain
// into two 8-deep accumulators; tree reductions.
__global__ __launch_bounds__(512, 1) void k_attn(
    const u16* __restrict__ Q, const u16* __restrict__ K,
    const u16* __restrict__ Vt, u16* __restrict__ Z) {
  extern __shared__ u16 smem[];
  char* sKc = (char*)smem;            // 2 x 16KB K tiles
  char* sVc = (char*)smem + 32768;    // 2 x 16KB V tiles
  const int tid = threadIdx.x, lane = tid & 63, w = tid >> 6;
  const int q = lane & 31, hi = lane >> 5;
  const int xcd = blockIdx.x & 7, bi = blockIdx.x >> 3;   // 256 blocks = 8 x 32
  const int bh = xcd * 4 + (bi & 3);                      // 4 bh per XCD
  const int qt = bi >> 2;                                 // 0..7
  const long base = (long)bh * 2048 * 256;
  const int q0 = qt * 256 + w * 32;

  const u16* Kg0 = K + base;   // blocked tiles: kt*8192 u16 each
  const u16* Vg0 = Vt + base;
  const int stq = tid * 8;     // staging src (u16) within 8KB half
  const int dtq = tid * 16;    // staging dst (bytes)

  short8 qf[16];
#pragma unroll
  for (int ec = 0; ec < 16; ++ec)
    qf[ec] = *(const short8*)(Q + base + (long)(q0 + q) * 256 + ec * 16 + hi * 8);

#define STAGE_K(kt_, buf_) do { \
    const u16* g_ = Kg0 + (kt_) * 8192 + stq; \
    char* d_ = sKc + (buf_) * 16384 + dtq; \
    gl_lds16(g_, d_); \
    gl_lds16(g_ + 4096, d_ + 8192); \
  } while (0)
#define STAGE_V(kt_, buf_) do { \
    const u16* g_ = Vg0 + (kt_) * 8192 + stq; \
    char* d_ = sVc + (buf_) * 16384 + dtq; \
    gl_lds16(g_, d_); \
    gl_lds16(g_ + 4096, d_ + 8192); \
  } while (0)

  STAGE_K(0, 0);

  floatx16 z[8] = {};  // Z[q'][e=et*32+q], q' = (r&3)+8*(r>>2)+4*hi
  float m_run = -1e30f, l = 0.f;
  const int kb = hi * 512 + q * 16;    // K frag base (bytes in tile)
  const int vb = hi * 4096 + q * 16;   // V frag base (bytes in tile)
  short8 pa0 = {}, pa1 = {};           // packed P of tile t-1

  __syncthreads();

  for (int t = 0; t < 64; ++t) {
    const int cb = t & 1;
    if (t < 63) STAGE_K(t + 1, cb ^ 1);
    STAGE_V(t, cb);
    const char* pK = sKc + cb * 16384 + kb;          // K(t)
    const char* pV = sVc + (cb ^ 1) * 16384 + vb;    // V(t-1)

    // QK(t) as two independent 8-deep chains, interleaved with PV(t-1)
    floatx16 s0 = {}, s1 = {};
    __builtin_amdgcn_s_setprio(1);
    if (t > 0) {
#pragma unroll
      for (int u = 0; u < 8; ++u) {
        short8 kf0 = *(const short8*)(pK + (2 * u) * 1024);
        s0 = __builtin_amdgcn_mfma_f32_32x32x16_bf16(kf0, qf[2 * u], s0, 0, 0, 0);
        short8 vf0 = *(const short8*)(pV + u * 512);
        z[u] = __builtin_amdgcn_mfma_f32_32x32x16_bf16(pa0, vf0, z[u], 0, 0, 0);
        short8 kf1 = *(const short8*)(pK + (2 * u + 1) * 1024);
        s1 = __builtin_amdgcn_mfma_f32_32x32x16_bf16(kf1, qf[2 * u + 1], s1, 0, 0, 0);
        short8 vf1 = *(const short8*)(pV + 8192 + u * 512);
        z[u] = __builtin_amdgcn_mfma_f32_32x32x16_bf16(pa1, vf1, z[u], 0, 0, 0);
      }
    } else {
#pragma unroll
      for (int u = 0; u < 8; ++u) {
        short8 kf0 = *(const short8*)(pK + (2 * u) * 1024);
        s0 = __builtin_amdgcn_mfma_f32_32x32x16_bf16(kf0, qf[2 * u], s0, 0, 0, 0);
        short8 kf1 = *(const short8*)(pK + (2 * u + 1) * 1024);
        s1 = __builtin_amdgcn_mfma_f32_32x32x16_bf16(kf1, qf[2 * u + 1], s1, 0, 0, 0);
      }
    }
    __builtin_amdgcn_s_setprio(0);
    floatx16 s = s0 + s1;

    // softmax(t): tree max + cross-half (permlane, pure VALU)
    float m0 = fmaxf(s[0], s[1]),  m1 = fmaxf(s[2], s[3]);
    float m2 = fmaxf(s[4], s[5]),  m3 = fmaxf(s[6], s[7]);
    float m4 = fmaxf(s[8], s[9]),  m5 = fmaxf(s[10], s[11]);
    float m6 = fmaxf(s[12], s[13]), m7 = fmaxf(s[14], s[15]);
    m0 = fmaxf(m0, m1); m2 = fmaxf(m2, m3); m4 = fmaxf(m4, m5); m6 = fmaxf(m6, m7);
    m0 = fmaxf(m0, m2); m4 = fmaxf(m4, m6);
    float pm = fmaxf(m0, m4);
    {
      uint2v sw = __builtin_amdgcn_permlane32_swap(__float_as_uint(pm), __float_as_uint(pm), false, false);
      pm = fmaxf(__uint_as_float(sw[0]), __uint_as_float(sw[1]));
    }

    if (!__all(pm <= m_run + 8.f)) {  // defer-max
      float mn = fmaxf(m_run, pm);
      float esc = exp2f(m_run - mn);
      l *= esc;
      m_run = mn;
      float escv[16];
#pragma unroll
      for (int r = 0; r < 16; ++r)
        escv[r] = bpermf(esc, ((r & 3) + 8 * (r >> 2) + 4 * hi) + 32 * hi);
#pragma unroll
      for (int et = 0; et < 8; ++et)
#pragma unroll
        for (int r = 0; r < 16; ++r) z[et][r] *= escv[r];
    }

    float p[16];
#pragma unroll
    for (int r = 0; r < 16; ++r) p[r] = exp2f(s[r] - m_run);
    float a0 = p[0] + p[1], a1 = p[2] + p[3], a2 = p[4] + p[5], a3 = p[6] + p[7];
    float a4 = p[8] + p[9], a5 = p[10] + p[11], a6 = p[12] + p[13], a7 = p[14] + p[15];
    a0 += a1; a2 += a3; a4 += a5; a6 += a7;
    a0 += a2; a4 += a6;
    float rs = a0 + a4;
    {
      uint2v sw = __builtin_amdgcn_permlane32_swap(__float_as_uint(rs), __float_as_uint(rs), false, false);
      l += __uint_as_float(sw[0]) + __uint_as_float(sw[1]);
    }

    // pack P(t) -> pa0/pa1 (consumed next iter / epilogue)
    unsigned w0, w1, w2, w3, w4, w5, w6, w7;
    asm("v_cvt_pk_bf16_f32 %0, %1, %2" : "=v"(w0) : "v"(p[0]), "v"(p[1]));
    asm("v_cvt_pk_bf16_f32 %0, %1, %2" : "=v"(w1) : "v"(p[2]), "v"(p[3]));
    asm("v_cvt_pk_bf16_f32 %0, %1, %2" : "=v"(w2) : "v"(p[4]), "v"(p[5]));
    asm("v_cvt_pk_bf16_f32 %0, %1, %2" : "=v"(w3) : "v"(p[6]), "v"(p[7]));
    asm("v_cvt_pk_bf16_f32 %0, %1, %2" : "=v"(w4) : "v"(p[8]), "v"(p[9]));
    asm("v_cvt_pk_bf16_f32 %0, %1, %2" : "=v"(w5) : "v"(p[10]), "v"(p[11]));
    asm("v_cvt_pk_bf16_f32 %0, %1, %2" : "=v"(w6) : "v"(p[12]), "v"(p[13]));
    asm("v_cvt_pk_bf16_f32 %0, %1, %2" : "=v"(w7) : "v"(p[14]), "v"(p[15]));
    uint2v e02 = __builtin_amdgcn_permlane32_swap(w0, w2, false, false);
    uint2v e13 = __builtin_amdgcn_permlane32_swap(w1, w3, false, false);
    uint2v e46 = __builtin_amdgcn_permlane32_swap(w4, w6, false, false);
    uint2v e57 = __builtin_amdgcn_permlane32_swap(w5, w7, false, false);
    int4 t0i = { (int)e02[0], (int)e13[0], (int)e02[1], (int)e13[1] };
    int4 t1i = { (int)e46[0], (int)e57[0], (int)e46[1], (int)e57[1] };
    pa0 = *(short8*)&t0i;
    pa1 = *(short8*)&t1i;

    __syncthreads();  // drains staged loads (all waves) + guards buffer swap
  }

  // epilogue: PV(63) from V buf1 (t=63 staged into cb=1)
  {
    const char* pV = sVc + 16384 + vb;
#pragma unroll
    for (int u = 0; u < 8; ++u) {
      short8 vf0 = *(const short8*)(pV + u * 512);
      z[u] = __builtin_amdgcn_mfma_f32_32x32x16_bf16(pa0, vf0, z[u], 0, 0, 0);
      short8 vf1 = *(const short8*)(pV + 8192 + u * 512);
      z[u] = __builtin_amdgcn_mfma_f32_32x32x16_bf16(pa1, vf1, z[u], 0, 0, 0);
    }
  }

  float linv = 1.f / l;
  float invv[16];
#pragma unroll
  for (int r = 0; r < 16; ++r)
    invv[r] = bpermf(linv, ((r & 3) + 8 * (r >> 2) + 4 * hi) + 32 * hi);

  const int b = bh >> 2, hh = bh & 3;
  const long zb = (long)b * 2048 * 1024 + hh * 256;
#pragma unroll
  for (int r = 0; r < 16; ++r) {
    const int qr = (r & 3) + 8 * (r >> 2) + 4 * hi;
    long rb = zb + (long)(q0 + qr) * 1024;
#pragma unroll
    for (int et = 0; et < 8; ++et)
      Z[rb + et * 32 + q] = f2bf(z[et][r] * invv[r]);
  }
#undef STAGE_K
#undef STAGE_V
}

// ---------------- launch ----------------

extern "C" void kernel_launch(void* const* d_in, const int* in_sizes, int n_in,
                              void* d_out, int out_size, void* d_ws, size_t ws_size,
                              hipStream_t stream) {
  const float* x  = (const float*)d_in[0];
  const float* WQ = (const float*)d_in[1];
  const float* bQ = (const float*)d_in[2];
  const float* WK = (const float*)d_in[3];
  const float* bK = (const float*)d_in[4];
  const float* WV = (const float*)d_in[5];
  const float* bV = (const float*)d_in[6];
  const float* WO = (const float*)d_in[7];
  const float* bO = (const float*)d_in[8];
  float* out = (float*)d_out;

  char* p = (char*)d_ws;
  u16* xb   = (u16*)p; p += (size_t)16384 * 1024 * 2;  // x bf16; reused later as Z
  u16* wqkv = (u16*)p; p += (size_t)3072 * 1024 * 2;
  u16* wo   = (u16*)p; p += (size_t)1024 * 1024 * 2;
  u16* Qb   = (u16*)p; p += (size_t)32 * 2048 * 256 * 2;
  u16* Kb   = (u16*)p; p += (size_t)32 * 2048 * 256 * 2;  // blocked K
  u16* Vtb  = (u16*)p; p += (size_t)32 * 256 * 2048 * 2;  // blocked V
  u16* Zb   = xb;  // alias: xb dead after k_gemm8<0>

  const int attn_lds = 65536;
  (void)hipFuncSetAttribute((const void*)k_attn,
                            hipFuncAttributeMaxDynamicSharedMemorySize, attn_lds);
  const int gemm_lds = 131072;
  (void)hipFuncSetAttribute((const void*)k_gemm8<0>,
                            hipFuncAttributeMaxDynamicSharedMemorySize, gemm_lds);
  (void)hipFuncSetAttribute((const void*)k_gemm8<1>,
                            hipFuncAttributeMaxDynamicSharedMemorySize, gemm_lds);

  k_cvt_x<<<dim3(4096), dim3(256), 0, stream>>>(x, xb, (long)16384 * 1024);
  k_cvt_w<<<dim3(1024), dim3(256), 0, stream>>>(WQ, WK, WV, WO, wqkv, wo);
  k_gemm8<0><<<dim3(768), dim3(512), gemm_lds, stream>>>(xb, wqkv, Qb, Kb, Vtb, bQ, bK, bV,
                                                         (float*)nullptr, (const float*)nullptr, 12);
  k_attn<<<dim3(256), dim3(512), attn_lds, stream>>>(Qb, Kb, Vtb, Zb);
  k_gemm8<1><<<dim3(256), dim3(512), gemm_lds, stream>>>(Zb, wo,
                                                         (u16*)nullptr, (u16*)nullptr, (u16*)nullptr,
                                                         (const float*)nullptr, (const float*)nullptr, (const float*)nullptr,
                                                         out, bO, 4);
}

// Round 10
// 324.431 us; speedup vs baseline: 2.4030x; 1.0005x over previous
//
#include <hip/hip_runtime.h>

typedef __attribute__((ext_vector_type(8))) short short8;
typedef __attribute__((ext_vector_type(4))) float floatx4;
typedef __attribute__((ext_vector_type(16))) float floatx16;
typedef __attribute__((ext_vector_type(4))) unsigned short ushort4v;
typedef __attribute__((ext_vector_type(2))) unsigned int uint2v;
typedef unsigned short u16;

__device__ __forceinline__ u16 f2bf(float f) {
  unsigned u = __float_as_uint(f);
  u += 0x7fffu + ((u >> 16) & 1u);
  return (u16)(u >> 16);
}

__device__ __forceinline__ void gl_lds16(const void* g, void* l) {
  __builtin_amdgcn_global_load_lds((const __attribute__((address_space(1))) void*)g,
                                   (__attribute__((address_space(3))) void*)l, 16, 0, 0);
}

__device__ __forceinline__ float bpermf(float v, int srclane) {
  return __int_as_float(__builtin_amdgcn_ds_bpermute(srclane << 2, __float_as_int(v)));
}

#define BARRIER() do { asm volatile("" ::: "memory"); __builtin_amdgcn_s_barrier(); asm volatile("" ::: "memory"); } while (0)

// ---------------- converts ----------------

__global__ void k_cvt_x(const float* __restrict__ x, u16* __restrict__ o, long n) {
  long i = ((long)blockIdx.x * blockDim.x + threadIdx.x) * 8;
  long stride = (long)gridDim.x * blockDim.x * 8;
  for (; i < n; i += stride) {
    float4 a = *(const float4*)(x + i);
    float4 b = *(const float4*)(x + i + 4);
    ushort4v r0 = { f2bf(a.x), f2bf(a.y), f2bf(a.z), f2bf(a.w) };
    ushort4v r1 = { f2bf(b.x), f2bf(b.y), f2bf(b.z), f2bf(b.w) };
    *(ushort4v*)(o + i) = r0;
    *(ushort4v*)(o + i + 4) = r1;
  }
}

// Tiled transpose (coalesced read + write)
__global__ __launch_bounds__(256) void k_cvt_w(
    const float* __restrict__ WQ, const float* __restrict__ WK,
    const float* __restrict__ WV, const float* __restrict__ WO,
    u16* __restrict__ wqkv, u16* __restrict__ wo) {
  __shared__ float tile[64][65];
  const int bid = blockIdx.x;
  const float* src;
  u16* dst;
  int C, R, r0, c0;
  if (bid < 768) {
    int th = bid >> 6;
    int tid6 = bid & 63;
    int t = th >> 2, h = th & 3;
    src = ((t == 0) ? WQ : (t == 1) ? WK : WV) + h * 1024 * 256;
    dst = wqkv + (size_t)(t * 1024 + h * 256) * 1024;
    R = 1024; C = 256;
    r0 = (tid6 & 15) * 64;
    c0 = (tid6 >> 4) * 64;
  } else {
    int tid6 = bid - 768;
    src = WO; dst = wo;
    R = 1024; C = 1024;
    r0 = (tid6 & 15) * 64;
    c0 = (tid6 >> 4) * 64;
  }
  const int tx = threadIdx.x & 15, ty = threadIdx.x >> 4;
#pragma unroll
  for (int i = 0; i < 4; ++i) {
    int r = ty + 16 * i;
    float4 v = *(const float4*)(src + (long)(r0 + r) * C + c0 + tx * 4);
    tile[r][tx * 4 + 0] = v.x;
    tile[r][tx * 4 + 1] = v.y;
    tile[r][tx * 4 + 2] = v.z;
    tile[r][tx * 4 + 3] = v.w;
  }
  __syncthreads();
#pragma unroll
  for (int i = 0; i < 4; ++i) {
    int c = ty + 16 * i;
    ushort4v o = { f2bf(tile[tx * 4 + 0][c]), f2bf(tile[tx * 4 + 1][c]),
                   f2bf(tile[tx * 4 + 2][c]), f2bf(tile[tx * 4 + 3][c]) };
    *(ushort4v*)(dst + (long)(c0 + c) * R + r0 + tx * 4) = o;
  }
}

// ---------------- 8-phase 256x256 GEMM ----------------
// Within-XCD by-fastest grouping: resident set = 8 A-panels (4MB, L2-resident)
// x B-panels streamed once.
template<int EPI>
__global__ __launch_bounds__(512, 2) void k_gemm8(
    const u16* __restrict__ A, const u16* __restrict__ Bt,
    u16* __restrict__ Qo, u16* __restrict__ Ko, u16* __restrict__ Vt,
    const float* __restrict__ bQ, const float* __restrict__ bK, const float* __restrict__ bV,
    float* __restrict__ out, const float* __restrict__ bO, int gridNx) {
  extern __shared__ char lds[];
  const int tid = threadIdx.x, lane = tid & 63, w = tid >> 6;
  const int wm = w >> 2, wn = w & 3;
  const int cI = lane & 15, rI = lane >> 4;
  const int bid = blockIdx.x;
  const int xcd = bid & 7, ii = bid >> 3;
  const int by = xcd * 8 + (ii & 7);   // M/256 = 64 = 8 XCD x 8
  const int bx = ii >> 3;
  (void)gridNx;
  const long am0 = (long)by * 256, bn0 = (long)bx * 256;

  int so_ds[2], so_src[2];
#pragma unroll
  for (int jj = 0; jj < 2; ++jj) {
    int o = jj * 8192 + tid * 16;
    int row = o >> 7;
    so_ds[jj] = o;
    so_src[jj] = row * 1024 + ((((o >> 4) & 7) ^ (row & 7)) << 3);  // u16 units
  }
  const u16* gAlo = A + am0 * 1024;
  const u16* gAhi = gAlo + 128 * 1024;
  const u16* gBlo = Bt + bn0 * 1024;
  const u16* gBhi = gBlo + 128 * 1024;

#define STG(gp, kt, ldsbyte) do { \
    gl_lds16((gp) + (kt) * 64 + so_src[0], lds + (ldsbyte) + so_ds[0]); \
    gl_lds16((gp) + (kt) * 64 + so_src[1], lds + (ldsbyte) + so_ds[1]); \
  } while (0)

  floatx4 acc[8][4] = {};

  STG(gAlo, 0, 0);
  STG(gBlo, 0, 65536);
  STG(gAhi, 0, 16384);
  STG(gBhi, 0, 81920);
  STG(gAlo, 1, 32768);
  STG(gBlo, 1, 98304);
  asm volatile("s_waitcnt vmcnt(4)" ::: "memory");
  BARRIER();

#define PHASE(AB, BB, MH, NH, STAGE_STMT, VMSTMT) do { \
    short8 af[4][2], bf[2][2]; \
    _Pragma("unroll") \
    for (int mi2 = 0; mi2 < 4; ++mi2) { \
      int row = wm * 64 + mi2 * 16 + cI; \
      const char* rp = lds + (AB) + (MH) * 16384 + row * 128; \
      int sw = row & 7; \
      _Pragma("unroll") \
      for (int kk = 0; kk < 2; ++kk) \
        af[mi2][kk] = *(const short8*)(rp + (((kk * 4 + rI) ^ sw) << 4)); \
    } \
    _Pragma("unroll") \
    for (int ni2 = 0; ni2 < 2; ++ni2) { \
      int row = wn * 32 + ni2 * 16 + cI; \
      const char* rp = lds + (BB) + (NH) * 16384 + row * 128; \
      int sw = row & 7; \
      _Pragma("unroll") \
      for (int kk = 0; kk < 2; ++kk) \
        bf[ni2][kk] = *(const short8*)(rp + (((kk * 4 + rI) ^ sw) << 4)); \
    } \
    STAGE_STMT; \
    VMSTMT; \
    BARRIER(); \
    __builtin_amdgcn_s_setprio(1); \
    _Pragma("unroll") \
    for (int mi2 = 0; mi2 < 4; ++mi2) \
      _Pragma("unroll") \
      for (int ni2 = 0; ni2 < 2; ++ni2) \
        _Pragma("unroll") \
        for (int kk = 0; kk < 2; ++kk) \
          acc[(MH) * 4 + mi2][(NH) * 2 + ni2] = __builtin_amdgcn_mfma_f32_16x16x32_bf16( \
              af[mi2][kk], bf[ni2][kk], acc[(MH) * 4 + mi2][(NH) * 2 + ni2], 0, 0, 0); \
    __builtin_amdgcn_s_setprio(0); \
    BARRIER(); \
  } while (0)

  for (int it = 0; it < 8; ++it) {
    const int u = 2 * it;
    const bool s2 = (u + 2 < 16), s3 = (u + 3 < 16);
    PHASE(0, 65536, 0, 0, STG(gAhi, u + 1, 49152), );
    PHASE(0, 65536, 0, 1, STG(gBhi, u + 1, 114688), );
    PHASE(0, 65536, 1, 0, if (s2) STG(gAlo, u + 2, 0), );
    PHASE(0, 65536, 1, 1, if (s2) STG(gBlo, u + 2, 65536),
          if (s2) { asm volatile("s_waitcnt vmcnt(4)" ::: "memory"); }
          else    { asm volatile("s_waitcnt vmcnt(0)" ::: "memory"); });
    PHASE(32768, 98304, 0, 0, if (s2) STG(gAhi, u + 2, 16384), );
    PHASE(32768, 98304, 0, 1, if (s2) STG(gBhi, u + 2, 81920), );
    PHASE(32768, 98304, 1, 0, if (s3) STG(gAlo, u + 3, 32768), );
    PHASE(32768, 98304, 1, 1, if (s3) STG(gBlo, u + 3, 98304),
          asm volatile("s_waitcnt vmcnt(4)" ::: "memory"));
  }

  // ---------------- epilogue ----------------
  if (EPI == 0) {
    const int t = (int)(bn0 >> 10);
    const int h = (int)(bn0 >> 8) & 3;
    const float* bias = (t == 0) ? bQ : (t == 1) ? bK : bV;
    const float sc = (t == 0) ? 0.0625f * 1.44269504088896f : 1.0f;
#pragma unroll
    for (int MH = 0; MH < 2; ++MH)
#pragma unroll
    for (int mi = 0; mi < 4; ++mi) {
      int m = (int)am0 + MH * 128 + wm * 64 + mi * 16 + rI * 4;
      int b = m >> 11, s = m & 2047;
#pragma unroll
      for (int NH = 0; NH < 2; ++NH)
#pragma unroll
      for (int ni = 0; ni < 2; ++ni) {
        int e = NH * 128 + wn * 32 + ni * 16 + cI;
        float bb = bias[h * 256 + e];
        floatx4 c = acc[MH * 4 + mi][NH * 2 + ni];
        if (t == 0) {
          long base = ((long)(b * 4 + h) * 2048 + s) * 256 + e;
          Qo[base]       = f2bf((c[0] + bb) * sc);
          Qo[base + 256] = f2bf((c[1] + bb) * sc);
          Qo[base + 512] = f2bf((c[2] + bb) * sc);
          Qo[base + 768] = f2bf((c[3] + bb) * sc);
        } else if (t == 1) {
          long kb = ((long)(b * 4 + h) << 19) + ((long)(s >> 5) << 13) +
                    ((e >> 3) << 8) + ((s & 31) << 3) + (e & 7);
          Ko[kb]      = f2bf(c[0] + bb);
          Ko[kb + 8]  = f2bf(c[1] + bb);
          Ko[kb + 16] = f2bf(c[2] + bb);
          Ko[kb + 24] = f2bf(c[3] + bb);
        } else {
          long vb = ((long)(b * 4 + h) << 19) + ((long)(s >> 5) << 13) +
                    (((s >> 3) & 3) << 11) + ((long)e << 3) + (s & 7);
          ushort4v v = { f2bf(c[0] + bb), f2bf(c[1] + bb), f2bf(c[2] + bb), f2bf(c[3] + bb) };
          *(ushort4v*)(Vt + vb) = v;
        }
      }
    }
  } else {
#pragma unroll
    for (int MH = 0; MH < 2; ++MH)
#pragma unroll
    for (int mi = 0; mi < 4; ++mi) {
      int m = (int)am0 + MH * 128 + wm * 64 + mi * 16 + rI * 4;
#pragma unroll
      for (int NH = 0; NH < 2; ++NH)
#pragma unroll
      for (int ni = 0; ni < 2; ++ni) {
        int n = (int)bn0 + NH * 128 + wn * 32 + ni * 16 + cI;
        float bb = bO[n];
        floatx4 c = acc[MH * 4 + mi][NH * 2 + ni];
        out[(long)m * 1024 + n]       = c[0] + bb;
        out[(long)(m + 1) * 1024 + n] = c[1] + bb;
        out[(long)(m + 2) * 1024 + n] = c[2] + bb;
        out[(long)(m + 3) * 1024 + n] = c[3] + bb;
      }
    }
  }
#undef PHASE
#undef STG
}

// ---------------- flash attention v6 (round-8 exact): blocked K/V ----------
__global__ __launch_bounds__(256, 2) void k_attn(
    const u16* __restrict__ Q, const u16* __restrict__ K,
    const u16* __restrict__ Vt, u16* __restrict__ Z) {
  extern __shared__ u16 smem[];
  char* sKc = (char*)smem;            // 2 x 16KB K tiles
  char* sVc = (char*)smem + 32768;    // 2 x 16KB V tiles
  const int tid = threadIdx.x, lane = tid & 63, w = tid >> 6;
  const int q = lane & 31, hi = lane >> 5;
  const int role = (blockIdx.x & 7) * 64 + (blockIdx.x >> 3);  // XCD-grouped, bijective
  const int bh = role >> 4, qt = role & 15;
  const long base = (long)bh * 2048 * 256;
  const int q0 = qt * 128 + w * 32;

  const u16* Kg0 = K + base;   // blocked tiles: kt*8192 u16 each
  const u16* Vg0 = Vt + base;
  const int stq = tid * 8;     // staging source (u16) within tile
  const int dtq = tid * 16;    // staging dest (bytes) within tile

  short8 qf[16];
#pragma unroll
  for (int ec = 0; ec < 16; ++ec)
    qf[ec] = *(const short8*)(Q + base + (long)(q0 + q) * 256 + ec * 16 + hi * 8);

#define STAGE_K(kt_, buf_) do { \
    const u16* g_ = Kg0 + (kt_) * 8192 + stq; \
    char* d_ = sKc + (buf_) * 16384 + dtq; \
    _Pragma("unroll") \
    for (int j = 0; j < 4; ++j) gl_lds16(g_ + j * 2048, d_ + j * 4096); \
  } while (0)
#define STAGE_V(kt_, buf_) do { \
    const u16* g_ = Vg0 + (kt_) * 8192 + stq; \
    char* d_ = sVc + (buf_) * 16384 + dtq; \
    _Pragma("unroll") \
    for (int j = 0; j < 4; ++j) gl_lds16(g_ + j * 2048, d_ + j * 4096); \
  } while (0)

  STAGE_K(0, 0);

  floatx16 z[8] = {};  // Z[q'][e=et*32+q], q' = (r&3)+8*(r>>2)+4*hi
  float m_run = -1e30f, l = 0.f;
  const int kb = hi * 512 + q * 16;    // K frag base (bytes in tile)
  const int vb = hi * 4096 + q * 16;   // V frag base (bytes in tile)
  short8 pa0 = {}, pa1 = {};           // packed P of tile t-1

  __syncthreads();

  for (int t = 0; t < 64; ++t) {
    const int cb = t & 1;
    if (t < 63) STAGE_K(t + 1, cb ^ 1);
    STAGE_V(t, cb);
    const char* pK = sKc + cb * 16384 + kb;          // K(t)
    const char* pV = sVc + (cb ^ 1) * 16384 + vb;    // V(t-1)

    floatx16 s = {};
    __builtin_amdgcn_s_setprio(1);
    if (t > 0) {
#pragma unroll
      for (int u = 0; u < 8; ++u) {
        short8 kf0 = *(const short8*)(pK + (2 * u) * 1024);
        s = __builtin_amdgcn_mfma_f32_32x32x16_bf16(kf0, qf[2 * u], s, 0, 0, 0);
        short8 vf0 = *(const short8*)(pV + u * 512);
        z[u] = __builtin_amdgcn_mfma_f32_32x32x16_bf16(pa0, vf0, z[u], 0, 0, 0);
        short8 kf1 = *(const short8*)(pK + (2 * u + 1) * 1024);
        s = __builtin_amdgcn_mfma_f32_32x32x16_bf16(kf1, qf[2 * u + 1], s, 0, 0, 0);
        short8 vf1 = *(const short8*)(pV + 8192 + u * 512);
        z[u] = __builtin_amdgcn_mfma_f32_32x32x16_bf16(pa1, vf1, z[u], 0, 0, 0);
      }
    } else {
#pragma unroll
      for (int ec = 0; ec < 16; ++ec) {
        short8 kf = *(const short8*)(pK + ec * 1024);
        s = __builtin_amdgcn_mfma_f32_32x32x16_bf16(kf, qf[ec], s, 0, 0, 0);
      }
    }
    __builtin_amdgcn_s_setprio(0);

    float m0 = fmaxf(s[0], s[1]),  m1 = fmaxf(s[2], s[3]);
    float m2 = fmaxf(s[4], s[5]),  m3 = fmaxf(s[6], s[7]);
    float m4 = fmaxf(s[8], s[9]),  m5 = fmaxf(s[10], s[11]);
    float m6 = fmaxf(s[12], s[13]), m7 = fmaxf(s[14], s[15]);
    m0 = fmaxf(m0, m1); m2 = fmaxf(m2, m3); m4 = fmaxf(m4, m5); m6 = fmaxf(m6, m7);
    m0 = fmaxf(m0, m2); m4 = fmaxf(m4, m6);
    float pm = fmaxf(m0, m4);
    {
      uint2v sw = __builtin_amdgcn_permlane32_swap(__float_as_uint(pm), __float_as_uint(pm), false, false);
      pm = fmaxf(__uint_as_float(sw[0]), __uint_as_float(sw[1]));
    }

    if (!__all(pm <= m_run + 8.f)) {  // defer-max
      float mn = fmaxf(m_run, pm);
      float esc = exp2f(m_run - mn);
      l *= esc;
      m_run = mn;
      float escv[16];
#pragma unroll
      for (int r = 0; r < 16; ++r)
        escv[r] = bpermf(esc, ((r & 3) + 8 * (r >> 2) + 4 * hi) + 32 * hi);
#pragma unroll
      for (int et = 0; et < 8; ++et)
#pragma unroll
        for (int r = 0; r < 16; ++r) z[et][r] *= escv[r];
    }

    float p[16], rs = 0.f;
#pragma unroll
    for (int r = 0; r < 16; ++r) { p[r] = exp2f(s[r] - m_run); rs += p[r]; }
    {
      uint2v sw = __builtin_amdgcn_permlane32_swap(__float_as_uint(rs), __float_as_uint(rs), false, false);
      l += __uint_as_float(sw[0]) + __uint_as_float(sw[1]);
    }

    unsigned w0, w1, w2, w3, w4, w5, w6, w7;
    asm("v_cvt_pk_bf16_f32 %0, %1, %2" : "=v"(w0) : "v"(p[0]), "v"(p[1]));
    asm("v_cvt_pk_bf16_f32 %0, %1, %2" : "=v"(w1) : "v"(p[2]), "v"(p[3]));
    asm("v_cvt_pk_bf16_f32 %0, %1, %2" : "=v"(w2) : "v"(p[4]), "v"(p[5]));
    asm("v_cvt_pk_bf16_f32 %0, %1, %2" : "=v"(w3) : "v"(p[6]), "v"(p[7]));
    asm("v_cvt_pk_bf16_f32 %0, %1, %2" : "=v"(w4) : "v"(p[8]), "v"(p[9]));
    asm("v_cvt_pk_bf16_f32 %0, %1, %2" : "=v"(w5) : "v"(p[10]), "v"(p[11]));
    asm("v_cvt_pk_bf16_f32 %0, %1, %2" : "=v"(w6) : "v"(p[12]), "v"(p[13]));
    asm("v_cvt_pk_bf16_f32 %0, %1, %2" : "=v"(w7) : "v"(p[14]), "v"(p[15]));
    uint2v e02 = __builtin_amdgcn_permlane32_swap(w0, w2, false, false);
    uint2v e13 = __builtin_amdgcn_permlane32_swap(w1, w3, false, false);
    uint2v e46 = __builtin_amdgcn_permlane32_swap(w4, w6, false, false);
    uint2v e57 = __builtin_amdgcn_permlane32_swap(w5, w7, false, false);
    int4 t0i = { (int)e02[0], (int)e13[0], (int)e02[1], (int)e13[1] };
    int4 t1i = { (int)e46[0], (int)e57[0], (int)e46[1], (int)e57[1] };
    pa0 = *(short8*)&t0i;
    pa1 = *(short8*)&t1i;

    __syncthreads();  // drains staged loads (all waves) + guards buffer swap
  }

  // epilogue: PV(63) from V buf1 (t=63 staged into cb=1)
  {
    const char* pV = sVc + 16384 + vb;
#pragma unroll
    for (int u = 0; u < 8; ++u) {
      short8 vf0 = *(const short8*)(pV + u * 512);
      z[u] = __builtin_amdgcn_mfma_f32_32x32x16_bf16(pa0, vf0, z[u], 0, 0, 0);
      short8 vf1 = *(const short8*)(pV + 8192 + u * 512);
      z[u] = __builtin_amdgcn_mfma_f32_32x32x16_bf16(pa1, vf1, z[u], 0, 0, 0);
    }
  }

  float linv = 1.f / l;
  float invv[16];
#pragma unroll
  for (int r = 0; r < 16; ++r)
    invv[r] = bpermf(linv, ((r & 3) + 8 * (r >> 2) + 4 * hi) + 32 * hi);

  const int b = bh >> 2, hh = bh & 3;
  const long zb = (long)b * 2048 * 1024 + hh * 256;
#pragma unroll
  for (int r = 0; r < 16; ++r) {
    const int qr = (r & 3) + 8 * (r >> 2) + 4 * hi;
    long rb = zb + (long)(q0 + qr) * 1024;
#pragma unroll
    for (int et = 0; et < 8; ++et)
      Z[rb + et * 32 + q] = f2bf(z[et][r] * invv[r]);
  }
#undef STAGE_K
#undef STAGE_V
}

// ---------------- launch ----------------

extern "C" void kernel_launch(void* const* d_in, const int* in_sizes, int n_in,
                              void* d_out, int out_size, void* d_ws, size_t ws_size,
                              hipStream_t stream) {
  const float* x  = (const float*)d_in[0];
  const float* WQ = (const float*)d_in[1];
  const float* bQ = (const float*)d_in[2];
  const float* WK = (const float*)d_in[3];
  const float* bK = (const float*)d_in[4];
  const float* WV = (const float*)d_in[5];
  const float* bV = (const float*)d_in[6];
  const float* WO = (const float*)d_in[7];
  const float* bO = (const float*)d_in[8];
  float* out = (float*)d_out;

  char* p = (char*)d_ws;
  u16* xb   = (u16*)p; p += (size_t)16384 * 1024 * 2;  // x bf16; reused later as Z
  u16* wqkv = (u16*)p; p += (size_t)3072 * 1024 * 2;
  u16* wo   = (u16*)p; p += (size_t)1024 * 1024 * 2;
  u16* Qb   = (u16*)p; p += (size_t)32 * 2048 * 256 * 2;
  u16* Kb   = (u16*)p; p += (size_t)32 * 2048 * 256 * 2;  // blocked K
  u16* Vtb  = (u16*)p; p += (size_t)32 * 256 * 2048 * 2;  // blocked V
  u16* Zb   = xb;  // alias: xb dead after k_gemm8<0>

  const int attn_lds = 65536;
  (void)hipFuncSetAttribute((const void*)k_attn,
                            hipFuncAttributeMaxDynamicSharedMemorySize, attn_lds);
  const int gemm_lds = 131072;
  (void)hipFuncSetAttribute((const void*)k_gemm8<0>,
                            hipFuncAttributeMaxDynamicSharedMemorySize, gemm_lds);
  (void)hipFuncSetAttribute((const void*)k_gemm8<1>,
                            hipFuncAttributeMaxDynamicSharedMemorySize, gemm_lds);

  k_cvt_x<<<dim3(4096), dim3(256), 0, stream>>>(x, xb, (long)16384 * 1024);
  k_cvt_w<<<dim3(1024), dim3(256), 0, stream>>>(WQ, WK, WV, WO, wqkv, wo);
  k_gemm8<0><<<dim3(768), dim3(512), gemm_lds, stream>>>(xb, wqkv, Qb, Kb, Vtb, bQ, bK, bV,
                                                         (float*)nullptr, (const float*)nullptr, 12);
  k_attn<<<dim3(512), dim3(256), attn_lds, stream>>>(Qb, Kb, Vtb, Zb);
  k_gemm8<1><<<dim3(256), dim3(512), gemm_lds, stream>>>(Zb, wo,
                                                         (u16*)nullptr, (u16*)nullptr, (u16*)nullptr,
                                                         (const float*)nullptr, (const float*)nullptr, (const float*)nullptr,
                                                         out, bO, 4);
}

// Round 11
// 324.208 us; speedup vs baseline: 2.4047x; 1.0007x over previous
//
#include <hip/hip_runtime.h>

typedef __attribute__((ext_vector_type(8))) short short8;
typedef __attribute__((ext_vector_type(4))) float floatx4;
typedef __attribute__((ext_vector_type(16))) float floatx16;
typedef __attribute__((ext_vector_type(4))) unsigned short ushort4v;
typedef __attribute__((ext_vector_type(2))) unsigned int uint2v;
typedef unsigned short u16;

__device__ __forceinline__ u16 f2bf(float f) {
  unsigned u = __float_as_uint(f);
  u += 0x7fffu + ((u >> 16) & 1u);
  return (u16)(u >> 16);
}

__device__ __forceinline__ void gl_lds16(const void* g, void* l) {
  __builtin_amdgcn_global_load_lds((const __attribute__((address_space(1))) void*)g,
                                   (__attribute__((address_space(3))) void*)l, 16, 0, 0);
}

__device__ __forceinline__ float bpermf(float v, int srclane) {
  return __int_as_float(__builtin_amdgcn_ds_bpermute(srclane << 2, __float_as_int(v)));
}

#define BARRIER() do { asm volatile("" ::: "memory"); __builtin_amdgcn_s_barrier(); asm volatile("" ::: "memory"); } while (0)

// ---------------- merged converts ----------------
// blocks 0..4095: x fp32 -> bf16 (vectorized). blocks 4096..5119: W transposes.
__global__ __launch_bounds__(256) void k_cvt(
    const float* __restrict__ x, u16* __restrict__ xb,
    const float* __restrict__ WQ, const float* __restrict__ WK,
    const float* __restrict__ WV, const float* __restrict__ WO,
    u16* __restrict__ wqkv, u16* __restrict__ wo) {
  __shared__ float tile[64][65];
  const int bid = blockIdx.x;
  if (bid < 4096) {
    const long n = (long)16384 * 1024;
    long i = ((long)bid * blockDim.x + threadIdx.x) * 8;
    long stride = (long)4096 * blockDim.x * 8;
    for (; i < n; i += stride) {
      float4 a = *(const float4*)(x + i);
      float4 b = *(const float4*)(x + i + 4);
      ushort4v r0 = { f2bf(a.x), f2bf(a.y), f2bf(a.z), f2bf(a.w) };
      ushort4v r1 = { f2bf(b.x), f2bf(b.y), f2bf(b.z), f2bf(b.w) };
      *(ushort4v*)(xb + i) = r0;
      *(ushort4v*)(xb + i + 4) = r1;
    }
    return;
  }
  const int wb = bid - 4096;
  const float* src;
  u16* dst;
  int C, R, r0, c0;
  if (wb < 768) {
    int th = wb >> 6;
    int tid6 = wb & 63;
    int t = th >> 2, h = th & 3;
    src = ((t == 0) ? WQ : (t == 1) ? WK : WV) + h * 1024 * 256;
    dst = wqkv + (size_t)(t * 1024 + h * 256) * 1024;
    R = 1024; C = 256;
    r0 = (tid6 & 15) * 64;
    c0 = (tid6 >> 4) * 64;
  } else {
    int tid6 = wb - 768;
    src = WO; dst = wo;
    R = 1024; C = 1024;
    r0 = (tid6 & 15) * 64;
    c0 = (tid6 >> 4) * 64;
  }
  const int tx = threadIdx.x & 15, ty = threadIdx.x >> 4;
#pragma unroll
  for (int i = 0; i < 4; ++i) {
    int r = ty + 16 * i;
    float4 v = *(const float4*)(src + (long)(r0 + r) * C + c0 + tx * 4);
    tile[r][tx * 4 + 0] = v.x;
    tile[r][tx * 4 + 1] = v.y;
    tile[r][tx * 4 + 2] = v.z;
    tile[r][tx * 4 + 3] = v.w;
  }
  __syncthreads();
#pragma unroll
  for (int i = 0; i < 4; ++i) {
    int c = ty + 16 * i;
    ushort4v o = { f2bf(tile[tx * 4 + 0][c]), f2bf(tile[tx * 4 + 1][c]),
                   f2bf(tile[tx * 4 + 2][c]), f2bf(tile[tx * 4 + 3][c]) };
    *(ushort4v*)(dst + (long)(c0 + c) * R + r0 + tx * 4) = o;
  }
}

// ---------------- 8-phase 256x256 GEMM (unchanged) ----------------
template<int EPI>
__global__ __launch_bounds__(512, 2) void k_gemm8(
    const u16* __restrict__ A, const u16* __restrict__ Bt,
    u16* __restrict__ Qo, u16* __restrict__ Ko, u16* __restrict__ Vt,
    const float* __restrict__ bQ, const float* __restrict__ bK, const float* __restrict__ bV,
    float* __restrict__ out, const float* __restrict__ bO, int gridNx) {
  extern __shared__ char lds[];
  const int tid = threadIdx.x, lane = tid & 63, w = tid >> 6;
  const int wm = w >> 2, wn = w & 3;
  const int cI = lane & 15, rI = lane >> 4;
  const int bid = blockIdx.x;
  const int xcd = bid & 7, ii = bid >> 3;
  const int by = xcd * 8 + (ii & 7);
  const int bx = ii >> 3;
  (void)gridNx;
  const long am0 = (long)by * 256, bn0 = (long)bx * 256;

  int so_ds[2], so_src[2];
#pragma unroll
  for (int jj = 0; jj < 2; ++jj) {
    int o = jj * 8192 + tid * 16;
    int row = o >> 7;
    so_ds[jj] = o;
    so_src[jj] = row * 1024 + ((((o >> 4) & 7) ^ (row & 7)) << 3);  // u16 units
  }
  const u16* gAlo = A + am0 * 1024;
  const u16* gAhi = gAlo + 128 * 1024;
  const u16* gBlo = Bt + bn0 * 1024;
  const u16* gBhi = gBlo + 128 * 1024;

#define STG(gp, kt, ldsbyte) do { \
    gl_lds16((gp) + (kt) * 64 + so_src[0], lds + (ldsbyte) + so_ds[0]); \
    gl_lds16((gp) + (kt) * 64 + so_src[1], lds + (ldsbyte) + so_ds[1]); \
  } while (0)

  floatx4 acc[8][4] = {};

  STG(gAlo, 0, 0);
  STG(gBlo, 0, 65536);
  STG(gAhi, 0, 16384);
  STG(gBhi, 0, 81920);
  STG(gAlo, 1, 32768);
  STG(gBlo, 1, 98304);
  asm volatile("s_waitcnt vmcnt(4)" ::: "memory");
  BARRIER();

#define PHASE(AB, BB, MH, NH, STAGE_STMT, VMSTMT) do { \
    short8 af[4][2], bf[2][2]; \
    _Pragma("unroll") \
    for (int mi2 = 0; mi2 < 4; ++mi2) { \
      int row = wm * 64 + mi2 * 16 + cI; \
      const char* rp = lds + (AB) + (MH) * 16384 + row * 128; \
      int sw = row & 7; \
      _Pragma("unroll") \
      for (int kk = 0; kk < 2; ++kk) \
        af[mi2][kk] = *(const short8*)(rp + (((kk * 4 + rI) ^ sw) << 4)); \
    } \
    _Pragma("unroll") \
    for (int ni2 = 0; ni2 < 2; ++ni2) { \
      int row = wn * 32 + ni2 * 16 + cI; \
      const char* rp = lds + (BB) + (NH) * 16384 + row * 128; \
      int sw = row & 7; \
      _Pragma("unroll") \
      for (int kk = 0; kk < 2; ++kk) \
        bf[ni2][kk] = *(const short8*)(rp + (((kk * 4 + rI) ^ sw) << 4)); \
    } \
    STAGE_STMT; \
    VMSTMT; \
    BARRIER(); \
    __builtin_amdgcn_s_setprio(1); \
    _Pragma("unroll") \
    for (int mi2 = 0; mi2 < 4; ++mi2) \
      _Pragma("unroll") \
      for (int ni2 = 0; ni2 < 2; ++ni2) \
        _Pragma("unroll") \
        for (int kk = 0; kk < 2; ++kk) \
          acc[(MH) * 4 + mi2][(NH) * 2 + ni2] = __builtin_amdgcn_mfma_f32_16x16x32_bf16( \
              af[mi2][kk], bf[ni2][kk], acc[(MH) * 4 + mi2][(NH) * 2 + ni2], 0, 0, 0); \
    __builtin_amdgcn_s_setprio(0); \
    BARRIER(); \
  } while (0)

  for (int it = 0; it < 8; ++it) {
    const int u = 2 * it;
    const bool s2 = (u + 2 < 16), s3 = (u + 3 < 16);
    PHASE(0, 65536, 0, 0, STG(gAhi, u + 1, 49152), );
    PHASE(0, 65536, 0, 1, STG(gBhi, u + 1, 114688), );
    PHASE(0, 65536, 1, 0, if (s2) STG(gAlo, u + 2, 0), );
    PHASE(0, 65536, 1, 1, if (s2) STG(gBlo, u + 2, 65536),
          if (s2) { asm volatile("s_waitcnt vmcnt(4)" ::: "memory"); }
          else    { asm volatile("s_waitcnt vmcnt(0)" ::: "memory"); });
    PHASE(32768, 98304, 0, 0, if (s2) STG(gAhi, u + 2, 16384), );
    PHASE(32768, 98304, 0, 1, if (s2) STG(gBhi, u + 2, 81920), );
    PHASE(32768, 98304, 1, 0, if (s3) STG(gAlo, u + 3, 32768), );
    PHASE(32768, 98304, 1, 1, if (s3) STG(gBlo, u + 3, 98304),
          asm volatile("s_waitcnt vmcnt(4)" ::: "memory"));
  }

  if (EPI == 0) {
    const int t = (int)(bn0 >> 10);
    const int h = (int)(bn0 >> 8) & 3;
    const float* bias = (t == 0) ? bQ : (t == 1) ? bK : bV;
    const float sc = (t == 0) ? 0.0625f * 1.44269504088896f : 1.0f;
#pragma unroll
    for (int MH = 0; MH < 2; ++MH)
#pragma unroll
    for (int mi = 0; mi < 4; ++mi) {
      int m = (int)am0 + MH * 128 + wm * 64 + mi * 16 + rI * 4;
      int b = m >> 11, s = m & 2047;
#pragma unroll
      for (int NH = 0; NH < 2; ++NH)
#pragma unroll
      for (int ni = 0; ni < 2; ++ni) {
        int e = NH * 128 + wn * 32 + ni * 16 + cI;
        float bb = bias[h * 256 + e];
        floatx4 c = acc[MH * 4 + mi][NH * 2 + ni];
        if (t == 0) {
          long base = ((long)(b * 4 + h) * 2048 + s) * 256 + e;
          Qo[base]       = f2bf((c[0] + bb) * sc);
          Qo[base + 256] = f2bf((c[1] + bb) * sc);
          Qo[base + 512] = f2bf((c[2] + bb) * sc);
          Qo[base + 768] = f2bf((c[3] + bb) * sc);
        } else if (t == 1) {
          long kb = ((long)(b * 4 + h) << 19) + ((long)(s >> 5) << 13) +
                    ((e >> 3) << 8) + ((s & 31) << 3) + (e & 7);
          Ko[kb]      = f2bf(c[0] + bb);
          Ko[kb + 8]  = f2bf(c[1] + bb);
          Ko[kb + 16] = f2bf(c[2] + bb);
          Ko[kb + 24] = f2bf(c[3] + bb);
        } else {
          long vb = ((long)(b * 4 + h) << 19) + ((long)(s >> 5) << 13) +
                    (((s >> 3) & 3) << 11) + ((long)e << 3) + (s & 7);
          ushort4v v = { f2bf(c[0] + bb), f2bf(c[1] + bb), f2bf(c[2] + bb), f2bf(c[3] + bb) };
          *(ushort4v*)(Vt + vb) = v;
        }
      }
    }
  } else {
#pragma unroll
    for (int MH = 0; MH < 2; ++MH)
#pragma unroll
    for (int mi = 0; mi < 4; ++mi) {
      int m = (int)am0 + MH * 128 + wm * 64 + mi * 16 + rI * 4;
#pragma unroll
      for (int NH = 0; NH < 2; ++NH)
#pragma unroll
      for (int ni = 0; ni < 2; ++ni) {
        int n = (int)bn0 + NH * 128 + wn * 32 + ni * 16 + cI;
        float bb = bO[n];
        floatx4 c = acc[MH * 4 + mi][NH * 2 + ni];
        out[(long)m * 1024 + n]       = c[0] + bb;
        out[(long)(m + 1) * 1024 + n] = c[1] + bb;
        out[(long)(m + 2) * 1024 + n] = c[2] + bb;
        out[(long)(m + 3) * 1024 + n] = c[3] + bb;
      }
    }
  }
#undef PHASE
#undef STG
}

// ---------------- flash attention v8: v6 + split s-chain + tree reductions --
__global__ __launch_bounds__(256, 2) void k_attn(
    const u16* __restrict__ Q, const u16* __restrict__ K,
    const u16* __restrict__ Vt, u16* __restrict__ Z) {
  extern __shared__ u16 smem[];
  char* sKc = (char*)smem;            // 2 x 16KB K tiles
  char* sVc = (char*)smem + 32768;    // 2 x 16KB V tiles
  const int tid = threadIdx.x, lane = tid & 63, w = tid >> 6;
  const int q = lane & 31, hi = lane >> 5;
  const int role = (blockIdx.x & 7) * 64 + (blockIdx.x >> 3);  // XCD-grouped, bijective
  const int bh = role >> 4, qt = role & 15;
  const long base = (long)bh * 2048 * 256;
  const int q0 = qt * 128 + w * 32;

  const u16* Kg0 = K + base;
  const u16* Vg0 = Vt + base;
  const int stq = tid * 8;
  const int dtq = tid * 16;

  short8 qf[16];
#pragma unroll
  for (int ec = 0; ec < 16; ++ec)
    qf[ec] = *(const short8*)(Q + base + (long)(q0 + q) * 256 + ec * 16 + hi * 8);

#define STAGE_K(kt_, buf_) do { \
    const u16* g_ = Kg0 + (kt_) * 8192 + stq; \
    char* d_ = sKc + (buf_) * 16384 + dtq; \
    _Pragma("unroll") \
    for (int j = 0; j < 4; ++j) gl_lds16(g_ + j * 2048, d_ + j * 4096); \
  } while (0)
#define STAGE_V(kt_, buf_) do { \
    const u16* g_ = Vg0 + (kt_) * 8192 + stq; \
    char* d_ = sVc + (buf_) * 16384 + dtq; \
    _Pragma("unroll") \
    for (int j = 0; j < 4; ++j) gl_lds16(g_ + j * 2048, d_ + j * 4096); \
  } while (0)

  STAGE_K(0, 0);

  floatx16 z[8] = {};
  float m_run = -1e30f, l = 0.f;
  const int kb = hi * 512 + q * 16;
  const int vb = hi * 4096 + q * 16;
  short8 pa0 = {}, pa1 = {};

  __syncthreads();

  for (int t = 0; t < 64; ++t) {
    const int cb = t & 1;
    if (t < 63) STAGE_K(t + 1, cb ^ 1);
    STAGE_V(t, cb);
    const char* pK = sKc + cb * 16384 + kb;          // K(t)
    const char* pV = sVc + (cb ^ 1) * 16384 + vb;    // V(t-1)

    // QK(t) as two independent 8-deep chains, interleaved with PV(t-1)
    floatx16 s0 = {}, s1 = {};
    __builtin_amdgcn_s_setprio(1);
    if (t > 0) {
#pragma unroll
      for (int u = 0; u < 8; ++u) {
        short8 kf0 = *(const short8*)(pK + (2 * u) * 1024);
        s0 = __builtin_amdgcn_mfma_f32_32x32x16_bf16(kf0, qf[2 * u], s0, 0, 0, 0);
        short8 vf0 = *(const short8*)(pV + u * 512);
        z[u] = __builtin_amdgcn_mfma_f32_32x32x16_bf16(pa0, vf0, z[u], 0, 0, 0);
        short8 kf1 = *(const short8*)(pK + (2 * u + 1) * 1024);
        s1 = __builtin_amdgcn_mfma_f32_32x32x16_bf16(kf1, qf[2 * u + 1], s1, 0, 0, 0);
        short8 vf1 = *(const short8*)(pV + 8192 + u * 512);
        z[u] = __builtin_amdgcn_mfma_f32_32x32x16_bf16(pa1, vf1, z[u], 0, 0, 0);
      }
    } else {
#pragma unroll
      for (int u = 0; u < 8; ++u) {
        short8 kf0 = *(const short8*)(pK + (2 * u) * 1024);
        s0 = __builtin_amdgcn_mfma_f32_32x32x16_bf16(kf0, qf[2 * u], s0, 0, 0, 0);
        short8 kf1 = *(const short8*)(pK + (2 * u + 1) * 1024);
        s1 = __builtin_amdgcn_mfma_f32_32x32x16_bf16(kf1, qf[2 * u + 1], s1, 0, 0, 0);
      }
    }
    __builtin_amdgcn_s_setprio(0);
    floatx16 s = s0 + s1;

    // tree max (max3-fusable triples) + cross-half
    float t0 = fmaxf(fmaxf(s[0], s[1]), s[2]);
    float t1 = fmaxf(fmaxf(s[3], s[4]), s[5]);
    float t2 = fmaxf(fmaxf(s[6], s[7]), s[8]);
    float t3 = fmaxf(fmaxf(s[9], s[10]), s[11]);
    float t4 = fmaxf(fmaxf(s[12], s[13]), s[14]);
    float pm = fmaxf(fmaxf(t0, t1), fmaxf(fmaxf(t2, t3), fmaxf(t4, s[15])));
    {
      uint2v sw = __builtin_amdgcn_permlane32_swap(__float_as_uint(pm), __float_as_uint(pm), false, false);
      pm = fmaxf(__uint_as_float(sw[0]), __uint_as_float(sw[1]));
    }

    if (!__all(pm <= m_run + 8.f)) {  // defer-max
      float mn = fmaxf(m_run, pm);
      float esc = exp2f(m_run - mn);
      l *= esc;
      m_run = mn;
      float escv[16];
#pragma unroll
      for (int r = 0; r < 16; ++r)
        escv[r] = bpermf(esc, ((r & 3) + 8 * (r >> 2) + 4 * hi) + 32 * hi);
#pragma unroll
      for (int et = 0; et < 8; ++et)
#pragma unroll
        for (int r = 0; r < 16; ++r) z[et][r] *= escv[r];
    }

    float p[16];
#pragma unroll
    for (int r = 0; r < 16; ++r) p[r] = exp2f(s[r] - m_run);
    float a0 = p[0] + p[1], a1 = p[2] + p[3], a2 = p[4] + p[5], a3 = p[6] + p[7];
    float a4 = p[8] + p[9], a5 = p[10] + p[11], a6 = p[12] + p[13], a7 = p[14] + p[15];
    a0 += a1; a2 += a3; a4 += a5; a6 += a7;
    a0 += a2; a4 += a6;
    float rs = a0 + a4;
    {
      uint2v sw = __builtin_amdgcn_permlane32_swap(__float_as_uint(rs), __float_as_uint(rs), false, false);
      l += __uint_as_float(sw[0]) + __uint_as_float(sw[1]);
    }

    unsigned w0, w1, w2, w3, w4, w5, w6, w7;
    asm("v_cvt_pk_bf16_f32 %0, %1, %2" : "=v"(w0) : "v"(p[0]), "v"(p[1]));
    asm("v_cvt_pk_bf16_f32 %0, %1, %2" : "=v"(w1) : "v"(p[2]), "v"(p[3]));
    asm("v_cvt_pk_bf16_f32 %0, %1, %2" : "=v"(w2) : "v"(p[4]), "v"(p[5]));
    asm("v_cvt_pk_bf16_f32 %0, %1, %2" : "=v"(w3) : "v"(p[6]), "v"(p[7]));
    asm("v_cvt_pk_bf16_f32 %0, %1, %2" : "=v"(w4) : "v"(p[8]), "v"(p[9]));
    asm("v_cvt_pk_bf16_f32 %0, %1, %2" : "=v"(w5) : "v"(p[10]), "v"(p[11]));
    asm("v_cvt_pk_bf16_f32 %0, %1, %2" : "=v"(w6) : "v"(p[12]), "v"(p[13]));
    asm("v_cvt_pk_bf16_f32 %0, %1, %2" : "=v"(w7) : "v"(p[14]), "v"(p[15]));
    uint2v e02 = __builtin_amdgcn_permlane32_swap(w0, w2, false, false);
    uint2v e13 = __builtin_amdgcn_permlane32_swap(w1, w3, false, false);
    uint2v e46 = __builtin_amdgcn_permlane32_swap(w4, w6, false, false);
    uint2v e57 = __builtin_amdgcn_permlane32_swap(w5, w7, false, false);
    int4 t0i = { (int)e02[0], (int)e13[0], (int)e02[1], (int)e13[1] };
    int4 t1i = { (int)e46[0], (int)e57[0], (int)e46[1], (int)e57[1] };
    pa0 = *(short8*)&t0i;
    pa1 = *(short8*)&t1i;

    __syncthreads();
  }

  // epilogue: PV(63) from V buf1
  {
    const char* pV = sVc + 16384 + vb;
#pragma unroll
    for (int u = 0; u < 8; ++u) {
      short8 vf0 = *(const short8*)(pV + u * 512);
      z[u] = __builtin_amdgcn_mfma_f32_32x32x16_bf16(pa0, vf0, z[u], 0, 0, 0);
      short8 vf1 = *(const short8*)(pV + 8192 + u * 512);
      z[u] = __builtin_amdgcn_mfma_f32_32x32x16_bf16(pa1, vf1, z[u], 0, 0, 0);
    }
  }

  float linv = 1.f / l;
  float invv[16];
#pragma unroll
  for (int r = 0; r < 16; ++r)
    invv[r] = bpermf(linv, ((r & 3) + 8 * (r >> 2) + 4 * hi) + 32 * hi);

  const int b = bh >> 2, hh = bh & 3;
  const long zb = (long)b * 2048 * 1024 + hh * 256;
#pragma unroll
  for (int r = 0; r < 16; ++r) {
    const int qr = (r & 3) + 8 * (r >> 2) + 4 * hi;
    long rb = zb + (long)(q0 + qr) * 1024;
#pragma unroll
    for (int et = 0; et < 8; ++et)
      Z[rb + et * 32 + q] = f2bf(z[et][r] * invv[r]);
  }
#undef STAGE_K
#undef STAGE_V
}

// ---------------- launch ----------------

extern "C" void kernel_launch(void* const* d_in, const int* in_sizes, int n_in,
                              void* d_out, int out_size, void* d_ws, size_t ws_size,
                              hipStream_t stream) {
  const float* x  = (const float*)d_in[0];
  const float* WQ = (const float*)d_in[1];
  const float* bQ = (const float*)d_in[2];
  const float* WK = (const float*)d_in[3];
  const float* bK = (const float*)d_in[4];
  const float* WV = (const float*)d_in[5];
  const float* bV = (const float*)d_in[6];
  const float* WO = (const float*)d_in[7];
  const float* bO = (const float*)d_in[8];
  float* out = (float*)d_out;

  char* p = (char*)d_ws;
  u16* xb   = (u16*)p; p += (size_t)16384 * 1024 * 2;  // x bf16; reused later as Z
  u16* wqkv = (u16*)p; p += (size_t)3072 * 1024 * 2;
  u16* wo   = (u16*)p; p += (size_t)1024 * 1024 * 2;
  u16* Qb   = (u16*)p; p += (size_t)32 * 2048 * 256 * 2;
  u16* Kb   = (u16*)p; p += (size_t)32 * 2048 * 256 * 2;  // blocked K
  u16* Vtb  = (u16*)p; p += (size_t)32 * 256 * 2048 * 2;  // blocked V
  u16* Zb   = xb;  // alias: xb dead after k_gemm8<0>

  const int attn_lds = 65536;
  (void)hipFuncSetAttribute((const void*)k_attn,
                            hipFuncAttributeMaxDynamicSharedMemorySize, attn_lds);
  const int gemm_lds = 131072;
  (void)hipFuncSetAttribute((const void*)k_gemm8<0>,
                            hipFuncAttributeMaxDynamicSharedMemorySize, gemm_lds);
  (void)hipFuncSetAttribute((const void*)k_gemm8<1>,
                            hipFuncAttributeMaxDynamicSharedMemorySize, gemm_lds);

  k_cvt<<<dim3(5120), dim3(256), 0, stream>>>(x, xb, WQ, WK, WV, WO, wqkv, wo);
  k_gemm8<0><<<dim3(768), dim3(512), gemm_lds, stream>>>(xb, wqkv, Qb, Kb, Vtb, bQ, bK, bV,
                                                         (float*)nullptr, (const float*)nullptr, 12);
  k_attn<<<dim3(512), dim3(256), attn_lds, stream>>>(Qb, Kb, Vtb, Zb);
  k_gemm8<1><<<dim3(256), dim3(512), gemm_lds, stream>>>(Zb, wo,
                                                         (u16*)nullptr, (u16*)nullptr, (u16*)nullptr,
                                                         (const float*)nullptr, (const float*)nullptr, (const float*)nullptr,
                                                         out, bO, 4);
}